// Round 2
// baseline (749.236 us; speedup 1.0000x reference)
//
#include <hip/hip_runtime.h>
#include <math.h>

#define NN 40000
#define FF 256
#define DD 64
#define LHH 200
#define BB 512
#define TDD 16
#define GE_HASH 1024

// freqs[j] = 10^(-0.3125*j)
__constant__ float TFREQ[16] = {
    1.0f,            0.48696753f,    0.23713737f,    0.115478195f,
    0.056234132f,    0.027384196f,   0.013335215f,   0.0064938162f,
    0.0031622776f,   0.0015399265f,  0.00074989421f, 0.00036517414f,
    0.00017782794f,  8.6596433e-05f, 4.2169650e-05f, 2.0535251e-05f
};

// ---------------------------------------------------------------------------
// K1: C[n][0:64] = A[n][:] @ W[64][KDIM]^T + bias
// ---------------------------------------------------------------------------
template<int KDIM>
__global__ void __launch_bounds__(256)
gemm_nt_kernel(const float* __restrict__ A, const float* __restrict__ W,
               const float* __restrict__ bias, float* __restrict__ C, int Nrows)
{
    __shared__ __align__(16) float a_t[128][8];
    __shared__ __align__(16) float wt[8][64];
    const int tid = threadIdx.x;
    const int tx = tid & 15;
    const int ty = tid >> 4;
    const int n0 = blockIdx.x * 128;

    float4 acc[8];
#pragma unroll
    for (int r = 0; r < 8; ++r) acc[r] = make_float4(0.f, 0.f, 0.f, 0.f);

    for (int kc = 0; kc < KDIM; kc += 8) {
        __syncthreads();
        {
            int r = tid >> 1;
            int cc = (tid & 1) * 4;
            int n = n0 + r;
            float4 v = make_float4(0.f, 0.f, 0.f, 0.f);
            if (n < Nrows) v = *(const float4*)(A + (size_t)n * KDIM + kc + cc);
            *(float4*)&a_t[r][cc] = v;
        }
        {
            int m = tid >> 2;
            int f0 = (tid & 3) * 2;
            float2 v = *(const float2*)(W + (size_t)m * KDIM + kc + f0);
            wt[f0][m] = v.x; wt[f0 + 1][m] = v.y;
        }
        __syncthreads();
        float4 w4[8];
#pragma unroll
        for (int f = 0; f < 8; ++f) w4[f] = *(float4*)&wt[f][tx * 4];
#pragma unroll
        for (int rr = 0; rr < 8; ++rr) {
            int row = ty + rr * 16;
            float4 a0 = *(float4*)&a_t[row][0];
            float4 a1 = *(float4*)&a_t[row][4];
            float av[8] = {a0.x, a0.y, a0.z, a0.w, a1.x, a1.y, a1.z, a1.w};
#pragma unroll
            for (int f = 0; f < 8; ++f) {
                acc[rr].x += av[f] * w4[f].x;
                acc[rr].y += av[f] * w4[f].y;
                acc[rr].z += av[f] * w4[f].z;
                acc[rr].w += av[f] * w4[f].w;
            }
        }
    }
    float4 bv = make_float4(0.f, 0.f, 0.f, 0.f);
    if (bias) bv = *(const float4*)(bias + tx * 4);
#pragma unroll
    for (int rr = 0; rr < 8; ++rr) {
        int n = n0 + ty + rr * 16;
        if (n < Nrows) {
            float4 o = acc[rr];
            o.x += bv.x; o.y += bv.y; o.z += bv.z; o.w += bv.w;
            *(float4*)(C + (size_t)n * DD + tx * 4) = o;
        }
    }
}

// ---------------------------------------------------------------------------
// Tn[n][j] = sum_k proj[n][k] * Wih[j][k] * ln_g[k]   (j = 0..191)
// block: 256 thr, tile 64 rows; wgT padded [64][193] to kill bank conflicts.
// ---------------------------------------------------------------------------
__global__ void __launch_bounds__(256)
tn_gemm_kernel(const float* __restrict__ proj, const float* __restrict__ Wih,
               const float* __restrict__ ln_g, float* __restrict__ Tn)
{
    __shared__ float wgT[64][193];
    __shared__ __align__(16) float4 at4[64][16];
    const int tid = threadIdx.x;
    const int n0 = blockIdx.x * 64;
    for (int i = tid; i < 192 * 64; i += 256) {
        int j = i >> 6, k = i & 63;
        wgT[k][j] = Wih[i] * ln_g[k];
    }
    for (int i = tid; i < 1024; i += 256) {
        int r = i >> 4, kc = i & 15;
        at4[r][kc] = ((const float4*)(proj + (size_t)(n0 + r) * DD))[kc];
    }
    __syncthreads();
    const int c = tid & 63, wv = tid >> 6;
    float acc0[16], acc1[16], acc2[16];
#pragma unroll
    for (int r = 0; r < 16; ++r) { acc0[r] = 0.f; acc1[r] = 0.f; acc2[r] = 0.f; }
    for (int kc = 0; kc < 16; ++kc) {
        float w0[4], w1[4], w2[4];
#pragma unroll
        for (int q = 0; q < 4; ++q) {
            w0[q] = wgT[kc * 4 + q][c];
            w1[q] = wgT[kc * 4 + q][64 + c];
            w2[q] = wgT[kc * 4 + q][128 + c];
        }
#pragma unroll
        for (int r = 0; r < 16; ++r) {
            float4 a = at4[wv * 16 + r][kc];
            acc0[r] += a.x * w0[0] + a.y * w0[1] + a.z * w0[2] + a.w * w0[3];
            acc1[r] += a.x * w1[0] + a.y * w1[1] + a.z * w1[2] + a.w * w1[3];
            acc2[r] += a.x * w2[0] + a.y * w2[1] + a.z * w2[2] + a.w * w2[3];
        }
    }
#pragma unroll
    for (int r = 0; r < 16; ++r) {
        size_t row = (size_t)(n0 + wv * 16 + r) * 192;
        Tn[row + c]       = acc0[r];
        Tn[row + 64 + c]  = acc1[r];
        Tn[row + 128 + c] = acc2[r];
    }
}

// ---------------------------------------------------------------------------
// Per-gate-row constants: out[21][192]
//   p=0: Te = Wg@we   p=1: Tw = Wg@ws   p=2: T1 = Wg@1   p=3: Tb0 = Wg@b0
//   p=4: Cc = Wih@ln_b + bih            p=5..20: Tt[t] = Wg@Wtime[:,t]
// ---------------------------------------------------------------------------
__global__ void __launch_bounds__(192)
consts_kernel(const float* __restrict__ Wih, const float* __restrict__ bih,
              const float* __restrict__ ln_g, const float* __restrict__ ln_b,
              const float* __restrict__ Wedge, const float* __restrict__ bedge,
              const float* __restrict__ Wtime, const float* __restrict__ btime,
              const float* __restrict__ Wstruct, const float* __restrict__ bstruct,
              float* __restrict__ out)
{
    const int j = threadIdx.x;
    float te = 0.f, tw = 0.f, t1 = 0.f, tb0 = 0.f, cc = 0.f;
    float tt[16];
#pragma unroll
    for (int t = 0; t < 16; ++t) tt[t] = 0.f;
    for (int k = 0; k < DD; ++k) {
        float wv = Wih[j * DD + k];
        float wg = wv * ln_g[k];
        te  += wg * Wedge[k];
        tw  += wg * Wstruct[k];
        t1  += wg;
        tb0 += wg * (bedge[k] + btime[k] + 2.f * bstruct[k]);
        cc  += wv * ln_b[k];
#pragma unroll
        for (int t = 0; t < 16; ++t) tt[t] += wg * Wtime[k * TDD + t];
    }
    out[0 * 192 + j] = te;
    out[1 * 192 + j] = tw;
    out[2 * 192 + j] = t1;
    out[3 * 192 + j] = tb0;
    out[4 * 192 + j] = cc + bih[j];
    for (int t = 0; t < 16; ++t) out[(5 + t) * 192 + j] = tt[t];
}

// ---------------------------------------------------------------------------
// Stats: per (b,l) compute LN mean + rsqrt(var) of f, and cos table.
// ---------------------------------------------------------------------------
__global__ void __launch_bounds__(192)
stats_kernel(const int* __restrict__ nids, const int* __restrict__ eids,
             const float* __restrict__ times, const int* __restrict__ cur_ids,
             const float* __restrict__ node_raw, const float* __restrict__ edge_raw,
             const float* __restrict__ proj_node,
             const float* __restrict__ Wedge, const float* __restrict__ bedge,
             const float* __restrict__ Wtime, const float* __restrict__ btime,
             const float* __restrict__ Wstruct, const float* __restrict__ bstruct,
             float* __restrict__ ctab_out, float* __restrict__ stats_out)
{
    __shared__ float wtimeT[TDD][DD];
    __shared__ float cbuf[LHH][TDD];
    __shared__ float we_s[DD], ws_s[DD], b0_s[DD];
    const int b = blockIdx.x, tid = threadIdx.x, lane = tid & 63, w = tid >> 6;
    if (tid < DD) {
        we_s[tid] = Wedge[tid];
        ws_s[tid] = Wstruct[tid];
        b0_s[tid] = bedge[tid] + btime[tid] + 2.f * bstruct[tid];
    }
    for (int i = tid; i < DD * TDD; i += 192) wtimeT[i & 15][i >> 4] = Wtime[i];
    for (int i = tid; i < LHH * TDD; i += 192) {
        int l = i >> 4, j = i & 15;
        float t = times[b * LHH + l];
        float cv = cosf(t * TFREQ[j]);
        cbuf[l][j] = cv;
        ctab_out[(size_t)b * LHH * TDD + i] = cv;
    }
    const int cur = cur_ids[b];
    const int csk = (int)node_raw[(size_t)cur * FF];
    __syncthreads();
    for (int l = w; l < LHH; l += 3) {
        int nid = nids[b * LHH + l];
        int eid = eids[b * LHH + l];
        float f = proj_node[(size_t)nid * DD + lane]
                + edge_raw[(size_t)eid * 4] * we_s[lane]
                + b0_s[lane];
        float flg = ((nid == cur) ? 1.f : 0.f)
                  + (((int)node_raw[(size_t)nid * FF] == csk) ? 1.f : 0.f);
        f += flg * ws_s[lane];
        float tf = 0.f;
#pragma unroll
        for (int j = 0; j < TDD; ++j) tf += cbuf[l][j] * wtimeT[j][lane];
        f += tf;
        float m = f;
#pragma unroll
        for (int off = 32; off; off >>= 1) m += __shfl_xor(m, off);
        m *= (1.f / 64.f);
        float dv = f - m, v = dv * dv;
#pragma unroll
        for (int off = 32; off; off >>= 1) v += __shfl_xor(v, off);
        v *= (1.f / 64.f);
        if (lane == 0)
            *(float2*)(stats_out + (size_t)(b * LHH + l) * 2) = make_float2(m, rsqrtf(v + 1e-5f));
    }
}

// ---------------------------------------------------------------------------
// GRU: one wave per sequence, Whh rows in VGPRs, h broadcast via LDS.
// ---------------------------------------------------------------------------
__device__ __forceinline__ float sigm(float x) {
    return __builtin_amdgcn_rcpf(1.f + __expf(-x));
}
__device__ __forceinline__ float tanh_f(float x) {
    float e = __expf(2.f * x);
    return 1.f - 2.f * __builtin_amdgcn_rcpf(e + 1.f);
}

__global__ void __launch_bounds__(64, 1)
gru_wave_kernel(const int* __restrict__ nidsL, const int* __restrict__ eidsL, const int* __restrict__ curL,
                const int* __restrict__ nidsQ, const int* __restrict__ eidsQ, const int* __restrict__ curQ,
                const float* __restrict__ node_raw, const float* __restrict__ edge_raw,
                const float* __restrict__ TnL, const float* __restrict__ TnQ,
                const float* __restrict__ cstL, const float* __restrict__ cstQ,
                const float* __restrict__ ctab, const float* __restrict__ stats,
                const float* __restrict__ WhhL, const float* __restrict__ bhhL,
                const float* __restrict__ WhhQ, const float* __restrict__ bhhQ,
                float* __restrict__ embL, float* __restrict__ embQ)
{
    __shared__ __align__(16) float hsh[DD];
    const int blk = blockIdx.x;
    const int g = blk >> 9, s = blk & 511;
    const int d = threadIdx.x;
    const int*   nids = g ? nidsQ : nidsL;
    const int*   eids = g ? eidsQ : eidsL;
    const int*   curp = g ? curQ : curL;
    const float* Tn   = g ? TnQ : TnL;
    const float* cst  = g ? cstQ : cstL;
    const float* Whh  = g ? WhhQ : WhhL;
    const float* bhh  = g ? bhhQ : bhhL;
    float*       emb  = g ? embQ : embL;

    float wr[DD], wz[DD], wn[DD];
#pragma unroll
    for (int k4 = 0; k4 < 16; ++k4) {
        float4 a = *(const float4*)(Whh + (size_t)d * DD + k4 * 4);
        wr[4*k4] = a.x; wr[4*k4+1] = a.y; wr[4*k4+2] = a.z; wr[4*k4+3] = a.w;
        float4 bq = *(const float4*)(Whh + (size_t)(64 + d) * DD + k4 * 4);
        wz[4*k4] = bq.x; wz[4*k4+1] = bq.y; wz[4*k4+2] = bq.z; wz[4*k4+3] = bq.w;
        float4 cq = *(const float4*)(Whh + (size_t)(128 + d) * DD + k4 * 4);
        wn[4*k4] = cq.x; wn[4*k4+1] = cq.y; wn[4*k4+2] = cq.z; wn[4*k4+3] = cq.w;
    }
    const float TE0 = cst[0*192 + d],       TE1 = cst[0*192 + 64 + d],  TE2 = cst[0*192 + 128 + d];
    const float TW0 = cst[1*192 + d],       TW1 = cst[1*192 + 64 + d],  TW2 = cst[1*192 + 128 + d];
    const float T10 = cst[2*192 + d],       T11 = cst[2*192 + 64 + d],  T12 = cst[2*192 + 128 + d];
    const float TB0 = cst[3*192 + d],       TB1 = cst[3*192 + 64 + d],  TB2 = cst[3*192 + 128 + d];
    const float CC0 = cst[4*192 + d],       CC1 = cst[4*192 + 64 + d],  CC2 = cst[4*192 + 128 + d];
    float tt0[16], tt1[16], tt2[16];
#pragma unroll
    for (int t = 0; t < 16; ++t) {
        tt0[t] = cst[(5 + t) * 192 + d];
        tt1[t] = cst[(5 + t) * 192 + 64 + d];
        tt2[t] = cst[(5 + t) * 192 + 128 + d];
    }
    const float bh0 = bhh[d], bh1 = bhh[64 + d], bh2 = bhh[128 + d];
    const int cur = curp[s];
    const int csk = (int)node_raw[(size_t)cur * FF];
    const float* ct_b = ctab  + (size_t)(g * BB + s) * LHH * TDD;
    const float* st_b = stats + (size_t)(g * BB + s) * LHH * 2;
    const int* nrow = nids + s * LHH;
    const int* erow = eids + s * LHH;

    float h = 0.f;
    int nid_c = nrow[0], eid_c = erow[0];
    float tn0 = Tn[(size_t)nid_c * 192 + d];
    float tn1 = Tn[(size_t)nid_c * 192 + 64 + d];
    float tn2 = Tn[(size_t)nid_c * 192 + 128 + d];
    float e0c = edge_raw[(size_t)eid_c * 4];
    float skc = node_raw[(size_t)nid_c * FF];
    float2 stc = *(const float2*)(st_b);
    int nid_n = nrow[1], eid_n = erow[1];

    for (int l = 0; l < LHH; ++l) {
        // prefetch rows for l+1
        float tn0n = Tn[(size_t)nid_n * 192 + d];
        float tn1n = Tn[(size_t)nid_n * 192 + 64 + d];
        float tn2n = Tn[(size_t)nid_n * 192 + 128 + d];
        float e0n  = edge_raw[(size_t)eid_n * 4];
        float skn  = node_raw[(size_t)nid_n * FF];
        int lp = (l + 1 < LHH) ? l + 1 : LHH - 1;
        float2 stn = *(const float2*)(st_b + 2 * lp);
        int l2 = (l + 2 < LHH) ? l + 2 : LHH - 1;
        int nid_2 = nrow[l2], eid_2 = erow[l2];

        hsh[d] = h;
        __syncthreads();

        // gi (independent of h -> covers LDS latency)
        float flg = ((nid_c == cur) ? 1.f : 0.f) + (((int)skc == csk) ? 1.f : 0.f);
        float mu = stc.x, rs = stc.y;
        float gi0 = tn0 + e0c * TE0 + flg * TW0 + TB0 - mu * T10;
        float gi1 = tn1 + e0c * TE1 + flg * TW1 + TB1 - mu * T11;
        float gi2 = tn2 + e0c * TE2 + flg * TW2 + TB2 - mu * T12;
        const float* ct = ct_b + l * TDD;
#pragma unroll
        for (int t4 = 0; t4 < 4; ++t4) {
            float4 cv = *(const float4*)(ct + 4 * t4);
            gi0 += tt0[4*t4] * cv.x + tt0[4*t4+1] * cv.y + tt0[4*t4+2] * cv.z + tt0[4*t4+3] * cv.w;
            gi1 += tt1[4*t4] * cv.x + tt1[4*t4+1] * cv.y + tt1[4*t4+2] * cv.z + tt1[4*t4+3] * cv.w;
            gi2 += tt2[4*t4] * cv.x + tt2[4*t4+1] * cv.y + tt2[4*t4+2] * cv.z + tt2[4*t4+3] * cv.w;
        }
        gi0 = gi0 * rs + CC0;
        gi1 = gi1 * rs + CC1;
        gi2 = gi2 * rs + CC2;

        // gh matvec: h broadcast via uniform LDS reads
        float a0 = 0.f, a1 = 0.f, a2 = 0.f;
#pragma unroll
        for (int k4 = 0; k4 < 16; ++k4) {
            float4 hv = *(const float4*)&hsh[4 * k4];
            a0 += wr[4*k4] * hv.x + wr[4*k4+1] * hv.y + wr[4*k4+2] * hv.z + wr[4*k4+3] * hv.w;
            a1 += wz[4*k4] * hv.x + wz[4*k4+1] * hv.y + wz[4*k4+2] * hv.z + wz[4*k4+3] * hv.w;
            a2 += wn[4*k4] * hv.x + wn[4*k4+1] * hv.y + wn[4*k4+2] * hv.z + wn[4*k4+3] * hv.w;
        }
        float r = sigm(gi0 + a0 + bh0);
        float z = sigm(gi1 + a1 + bh1);
        float n = tanh_f(gi2 + r * (a2 + bh2));
        h = (1.f - z) * n + z * h;

        // rotate prefetch
        nid_c = nid_n;
        tn0 = tn0n; tn1 = tn1n; tn2 = tn2n;
        e0c = e0n; skc = skn; stc = stn;
        nid_n = nid_2; eid_n = eid_2;
    }
    emb[(size_t)s * DD + d] = h;
}

// ---------------------------------------------------------------------------
// K3: graph_emb — hash-dedup'd GCNConv + mean pool. One block per batch row.
// ---------------------------------------------------------------------------
__device__ __forceinline__ int hlookup(const unsigned* hkey, const int* hslot, unsigned id)
{
    unsigned p = (id * 2654435761u) & (GE_HASH - 1);
    while (hkey[p] != id) p = (p + 1) & (GE_HASH - 1);
    return hslot[p];
}

__global__ void __launch_bounds__(256)
graph_emb_kernel(const int* __restrict__ retrieved, const int* __restrict__ pool_nodes,
                 const float* __restrict__ hgcn, const float* __restrict__ gcn_b,
                 float* __restrict__ glob)
{
    __shared__ float agg[400 * 64];
    __shared__ unsigned hkey[GE_HASH];
    __shared__ int hslot[GE_HASH];
    __shared__ unsigned ekey[GE_HASH];
    __shared__ int slot_id[400];
    __shared__ unsigned deg[400];
    __shared__ float dis[400];
    __shared__ unsigned elist[400];
    __shared__ int ids[400];
    __shared__ int pids[8];
    __shared__ int cntU, cntE;
    __shared__ float gcnb_s[64];
    __shared__ float red[4][64];

    const int b = blockIdx.x;
    const int tid = threadIdx.x;
    const int lane = tid & 63, wid = tid >> 6;

    if (tid < 8)  pids[tid] = retrieved[b * 8 + tid];
    if (tid < 64) gcnb_s[tid] = gcn_b[tid];
    if (tid == 0) { cntU = 0; cntE = 0; }
    for (int i = tid; i < GE_HASH; i += 256) { hkey[i] = 0u; ekey[i] = 0u; }
    for (int i = tid; i < 400; i += 256) deg[i] = 0u;
    __syncthreads();

    for (int i = tid; i < 400; i += 256) {
        int k = i / 50, p = i % 50;
        ids[i] = pool_nodes[(size_t)pids[k] * 50 + p];
    }
    __syncthreads();

    for (int i = tid; i < 400; i += 256) {
        int idi = ids[i];
        if (idi > 0) {
            unsigned id = (unsigned)idi;
            unsigned p = (id * 2654435761u) & (GE_HASH - 1);
            while (true) {
                unsigned old = atomicCAS(&hkey[p], 0u, id);
                if (old == 0u) {
                    int s = atomicAdd(&cntU, 1);
                    hslot[p] = s; slot_id[s] = idi;
                    break;
                }
                if (old == id) break;
                p = (p + 1) & (GE_HASH - 1);
            }
        }
    }
    __syncthreads();

    for (int i = tid; i < 8 * 49; i += 256) {
        int k = i / 49, p = i % 49;
        int u = ids[k * 50 + p], v = ids[k * 50 + p + 1];
        if (u > 0 && v > 0) {
            unsigned a = (unsigned)min(u, v), bb = (unsigned)max(u, v);
            unsigned key = a * 40000u + bb;
            unsigned p2 = (key * 2654435761u) & (GE_HASH - 1);
            while (true) {
                unsigned old = atomicCAS(&ekey[p2], 0u, key);
                if (old == 0u) {
                    int su = hlookup(hkey, hslot, a);
                    int sv = hlookup(hkey, hslot, bb);
                    int e = atomicAdd(&cntE, 1);
                    elist[e] = ((unsigned)su << 16) | (unsigned)sv;
                    atomicAdd(&deg[su], 1u);
                    atomicAdd(&deg[sv], 1u);
                    break;
                }
                if (old == key) break;
                p2 = (p2 + 1) & (GE_HASH - 1);
            }
        }
    }
    __syncthreads();

    const int U = cntU, EC = cntE;
    for (int s = tid; s < U; s += 256) dis[s] = rsqrtf((float)deg[s] + 1.0f);
    __syncthreads();

    for (int s = wid; s < U; s += 4) {
        float d2 = dis[s] * dis[s];
        float hval = hgcn[(size_t)slot_id[s] * 64 + lane];
        agg[s * 64 + lane] = gcnb_s[lane] + d2 * hval;
    }
    __syncthreads();

    for (int e = wid; e < EC; e += 4) {
        unsigned pk = elist[e];
        int su = (int)(pk >> 16), sv = (int)(pk & 0xffffu);
        float nrm = dis[su] * dis[sv];
        float hu = hgcn[(size_t)slot_id[su] * 64 + lane];
        float hv = hgcn[(size_t)slot_id[sv] * 64 + lane];
        atomicAdd(&agg[sv * 64 + lane], nrm * hu);
        atomicAdd(&agg[su * 64 + lane], nrm * hv);
    }
    __syncthreads();

    float acc = 0.f;
    for (int s = wid; s < U; s += 4) acc += fmaxf(agg[s * 64 + lane], 0.f);
    red[wid][lane] = acc;
    __syncthreads();
    if (tid < 64) {
        float tot = red[0][tid] + red[1][tid] + red[2][tid] + red[3][tid];
        glob[(size_t)b * 64 + tid] = tot / (float)max(U, 1);
    }
}

// ---------------------------------------------------------------------------
// K4: fusion + output heads.
// ---------------------------------------------------------------------------
__global__ void __launch_bounds__(64)
head_kernel(const float* __restrict__ local_emb, const float* __restrict__ glob,
            const float* __restrict__ q_emb,
            const float* __restrict__ fus_W, const float* __restrict__ fus_b,
            const float* __restrict__ out_W, const float* __restrict__ out_b,
            float* __restrict__ out)
{
    __shared__ float cat[128];
    __shared__ float fus[64];
    __shared__ float qv[64];
    const int b = blockIdx.x, d = threadIdx.x;
    cat[d]      = local_emb[(size_t)b * 64 + d];
    cat[64 + d] = glob[(size_t)b * 64 + d];
    qv[d]       = q_emb[(size_t)b * 64 + d];
    __syncthreads();
    float acc = fus_b[d];
    const float* fw = fus_W + (size_t)d * 128;
#pragma unroll 4
    for (int k = 0; k < 128; ++k) acc += cat[k] * fw[k];
    fus[d] = fmaxf(acc, 0.f);
    __syncthreads();
    float o0 = out_b[d], o1 = out_b[d];
    const float* ow = out_W + (size_t)d * 64;
#pragma unroll 4
    for (int k = 0; k < 64; ++k) { float ww = ow[k]; o0 += fus[k] * ww; o1 += qv[k] * ww; }
    out[(size_t)b * 64 + d] = o0;
    out[(size_t)BB * 64 + (size_t)b * 64 + d] = o1;
}

// ---------------------------------------------------------------------------
extern "C" void kernel_launch(void* const* d_in, const int* in_sizes, int n_in,
                              void* d_out, int out_size, void* d_ws, size_t ws_size,
                              hipStream_t stream)
{
    const int*   src_ids    = (const int*)d_in[0];
    const int*   dst_ids    = (const int*)d_in[1];
    const int*   l_nids     = (const int*)d_in[2];
    const int*   l_eids     = (const int*)d_in[3];
    const float* l_times    = (const float*)d_in[4];
    const int*   d_nids     = (const int*)d_in[5];
    const int*   d_eids     = (const int*)d_in[6];
    const float* d_times    = (const float*)d_in[7];
    const int*   retr       = (const int*)d_in[8];
    const float* node_raw   = (const float*)d_in[9];
    const float* edge_raw   = (const float*)d_in[10];
    const int*   pool_nodes = (const int*)d_in[11];
    const float* Wfeat  = (const float*)d_in[12];
    const float* bfeat  = (const float*)d_in[13];
    const float* Wedge  = (const float*)d_in[14];
    const float* bedge  = (const float*)d_in[15];
    const float* Wtime  = (const float*)d_in[16];
    const float* btime  = (const float*)d_in[17];
    const float* Wstruct= (const float*)d_in[18];
    const float* bstruct= (const float*)d_in[19];
    const float* ln_g   = (const float*)d_in[20];
    const float* ln_b   = (const float*)d_in[21];
    const float* gruL_Wih = (const float*)d_in[22];
    const float* gruL_Whh = (const float*)d_in[23];
    const float* gruL_bih = (const float*)d_in[24];
    const float* gruL_bhh = (const float*)d_in[25];
    const float* gruQ_Wih = (const float*)d_in[26];
    const float* gruQ_Whh = (const float*)d_in[27];
    const float* gruQ_bih = (const float*)d_in[28];
    const float* gruQ_bhh = (const float*)d_in[29];
    const float* gcn_W  = (const float*)d_in[30];
    const float* gcn_b  = (const float*)d_in[31];
    const float* fus_W  = (const float*)d_in[32];
    const float* fus_b  = (const float*)d_in[33];
    const float* out_W  = (const float*)d_in[34];
    const float* out_b  = (const float*)d_in[35];

    float* ws = (float*)d_ws;
    float* proj_node = ws;                              ws += (size_t)NN * DD;
    float* hgcn      = ws;                              ws += (size_t)NN * DD;
    float* TnL       = ws;                              ws += (size_t)NN * 192;
    float* TnQ       = ws;                              ws += (size_t)NN * 192;
    float* cstL      = ws;                              ws += 4096;
    float* cstQ      = ws;                              ws += 4096;
    float* ctab      = ws;                              ws += (size_t)2 * BB * LHH * TDD;
    float* stats     = ws;                              ws += (size_t)2 * BB * LHH * 2;
    float* local_emb = ws;                              ws += (size_t)BB * DD;
    float* q_emb     = ws;                              ws += (size_t)BB * DD;
    float* glob      = ws;                              ws += (size_t)BB * DD;

    dim3 g1((NN + 127) / 128);
    gemm_nt_kernel<FF><<<g1, 256, 0, stream>>>(node_raw, Wfeat, bfeat, proj_node, NN);
    gemm_nt_kernel<DD><<<g1, 256, 0, stream>>>(proj_node, gcn_W, nullptr, hgcn, NN);

    consts_kernel<<<1, 192, 0, stream>>>(gruL_Wih, gruL_bih, ln_g, ln_b, Wedge, bedge,
                                         Wtime, btime, Wstruct, bstruct, cstL);
    consts_kernel<<<1, 192, 0, stream>>>(gruQ_Wih, gruQ_bih, ln_g, ln_b, Wedge, bedge,
                                         Wtime, btime, Wstruct, bstruct, cstQ);

    tn_gemm_kernel<<<NN / 64, 256, 0, stream>>>(proj_node, gruL_Wih, ln_g, TnL);
    tn_gemm_kernel<<<NN / 64, 256, 0, stream>>>(proj_node, gruQ_Wih, ln_g, TnQ);

    stats_kernel<<<BB, 192, 0, stream>>>(l_nids, l_eids, l_times, dst_ids,
        node_raw, edge_raw, proj_node, Wedge, bedge, Wtime, btime, Wstruct, bstruct,
        ctab, stats);
    stats_kernel<<<BB, 192, 0, stream>>>(d_nids, d_eids, d_times, src_ids,
        node_raw, edge_raw, proj_node, Wedge, bedge, Wtime, btime, Wstruct, bstruct,
        ctab + (size_t)BB * LHH * TDD, stats + (size_t)BB * LHH * 2);

    gru_wave_kernel<<<2 * BB, 64, 0, stream>>>(
        l_nids, l_eids, dst_ids, d_nids, d_eids, src_ids,
        node_raw, edge_raw, TnL, TnQ, cstL, cstQ, ctab, stats,
        gruL_Whh, gruL_bhh, gruQ_Whh, gruQ_bhh, local_emb, q_emb);

    graph_emb_kernel<<<BB, 256, 0, stream>>>(retr, pool_nodes, hgcn, gcn_b, glob);

    head_kernel<<<BB, 64, 0, stream>>>(local_emb, glob, q_emb,
        fus_W, fus_b, out_W, out_b, (float*)d_out);
}

// Round 3
// 546.310 us; speedup vs baseline: 1.3714x; 1.3714x over previous
//
#include <hip/hip_runtime.h>
#include <math.h>

#define NN 40000
#define FF 256
#define DD 64
#define LHH 200
#define BB 512
#define TDD 16
#define GE_HASH 1024

__constant__ float TFREQ[16] = {
    1.0f,            0.48696753f,    0.23713737f,    0.115478195f,
    0.056234132f,    0.027384196f,   0.013335215f,   0.0064938162f,
    0.0031622776f,   0.0015399265f,  0.00074989421f, 0.00036517414f,
    0.00017782794f,  8.6596433e-05f, 4.2169650e-05f, 2.0535251e-05f
};

// ---------------------------------------------------------------------------
// K1: C[n][0:64] = A[n][:] @ W[64][KDIM]^T + bias
// ---------------------------------------------------------------------------
template<int KDIM>
__global__ void __launch_bounds__(256)
gemm_nt_kernel(const float* __restrict__ A, const float* __restrict__ W,
               const float* __restrict__ bias, float* __restrict__ C, int Nrows)
{
    __shared__ __align__(16) float a_t[128][8];
    __shared__ __align__(16) float wt[8][64];
    const int tid = threadIdx.x;
    const int tx = tid & 15;
    const int ty = tid >> 4;
    const int n0 = blockIdx.x * 128;

    float4 acc[8];
#pragma unroll
    for (int r = 0; r < 8; ++r) acc[r] = make_float4(0.f, 0.f, 0.f, 0.f);

    for (int kc = 0; kc < KDIM; kc += 8) {
        __syncthreads();
        {
            int r = tid >> 1;
            int cc = (tid & 1) * 4;
            int n = n0 + r;
            float4 v = make_float4(0.f, 0.f, 0.f, 0.f);
            if (n < Nrows) v = *(const float4*)(A + (size_t)n * KDIM + kc + cc);
            *(float4*)&a_t[r][cc] = v;
        }
        {
            int m = tid >> 2;
            int f0 = (tid & 3) * 2;
            float2 v = *(const float2*)(W + (size_t)m * KDIM + kc + f0);
            wt[f0][m] = v.x; wt[f0 + 1][m] = v.y;
        }
        __syncthreads();
        float4 w4[8];
#pragma unroll
        for (int f = 0; f < 8; ++f) w4[f] = *(float4*)&wt[f][tx * 4];
#pragma unroll
        for (int rr = 0; rr < 8; ++rr) {
            int row = ty + rr * 16;
            float4 a0 = *(float4*)&a_t[row][0];
            float4 a1 = *(float4*)&a_t[row][4];
            float av[8] = {a0.x, a0.y, a0.z, a0.w, a1.x, a1.y, a1.z, a1.w};
#pragma unroll
            for (int f = 0; f < 8; ++f) {
                acc[rr].x += av[f] * w4[f].x;
                acc[rr].y += av[f] * w4[f].y;
                acc[rr].z += av[f] * w4[f].z;
                acc[rr].w += av[f] * w4[f].w;
            }
        }
    }
    float4 bv = make_float4(0.f, 0.f, 0.f, 0.f);
    if (bias) bv = *(const float4*)(bias + tx * 4);
#pragma unroll
    for (int rr = 0; rr < 8; ++rr) {
        int n = n0 + ty + rr * 16;
        if (n < Nrows) {
            float4 o = acc[rr];
            o.x += bv.x; o.y += bv.y; o.z += bv.z; o.w += bv.w;
            *(float4*)(C + (size_t)n * DD + tx * 4) = o;
        }
    }
}

// ---------------------------------------------------------------------------
// Tn[n][j] = sum_k proj[n][k] * Wih[j][k] * ln_g[k]; grid.y selects L/Q.
// ---------------------------------------------------------------------------
__global__ void __launch_bounds__(256)
tn_gemm_kernel(const float* __restrict__ proj,
               const float* __restrict__ WihL, const float* __restrict__ WihQ,
               const float* __restrict__ ln_g,
               float* __restrict__ TnL, float* __restrict__ TnQ)
{
    const float* Wih = blockIdx.y ? WihQ : WihL;
    float* Tn = blockIdx.y ? TnQ : TnL;
    __shared__ float wgT[64][193];
    __shared__ __align__(16) float4 at4[64][16];
    const int tid = threadIdx.x;
    const int n0 = blockIdx.x * 64;
    for (int i = tid; i < 192 * 64; i += 256) {
        int j = i >> 6, k = i & 63;
        wgT[k][j] = Wih[i] * ln_g[k];
    }
    for (int i = tid; i < 1024; i += 256) {
        int r = i >> 4, kc = i & 15;
        at4[r][kc] = ((const float4*)(proj + (size_t)(n0 + r) * DD))[kc];
    }
    __syncthreads();
    const int c = tid & 63, wv = tid >> 6;
    float acc0[16], acc1[16], acc2[16];
#pragma unroll
    for (int r = 0; r < 16; ++r) { acc0[r] = 0.f; acc1[r] = 0.f; acc2[r] = 0.f; }
    for (int kc = 0; kc < 16; ++kc) {
        float w0[4], w1[4], w2[4];
#pragma unroll
        for (int q = 0; q < 4; ++q) {
            w0[q] = wgT[kc * 4 + q][c];
            w1[q] = wgT[kc * 4 + q][64 + c];
            w2[q] = wgT[kc * 4 + q][128 + c];
        }
#pragma unroll
        for (int r = 0; r < 16; ++r) {
            float4 a = at4[wv * 16 + r][kc];
            acc0[r] += a.x * w0[0] + a.y * w0[1] + a.z * w0[2] + a.w * w0[3];
            acc1[r] += a.x * w1[0] + a.y * w1[1] + a.z * w1[2] + a.w * w1[3];
            acc2[r] += a.x * w2[0] + a.y * w2[1] + a.z * w2[2] + a.w * w2[3];
        }
    }
#pragma unroll
    for (int r = 0; r < 16; ++r) {
        size_t row = (size_t)(n0 + wv * 16 + r) * 192;
        Tn[row + c]       = acc0[r];
        Tn[row + 64 + c]  = acc1[r];
        Tn[row + 128 + c] = acc2[r];
    }
}

// ---------------------------------------------------------------------------
// Per-gate-row constants: out[21][192]; grid.x = 2 (L, Q)
// ---------------------------------------------------------------------------
__global__ void __launch_bounds__(192)
consts_kernel(const float* __restrict__ WihL, const float* __restrict__ bihL, float* __restrict__ outL,
              const float* __restrict__ WihQ, const float* __restrict__ bihQ, float* __restrict__ outQ,
              const float* __restrict__ ln_g, const float* __restrict__ ln_b,
              const float* __restrict__ Wedge, const float* __restrict__ bedge,
              const float* __restrict__ Wtime, const float* __restrict__ btime,
              const float* __restrict__ Wstruct, const float* __restrict__ bstruct)
{
    const float* Wih = blockIdx.x ? WihQ : WihL;
    const float* bih = blockIdx.x ? bihQ : bihL;
    float* out = blockIdx.x ? outQ : outL;
    const int j = threadIdx.x;
    float te = 0.f, tw = 0.f, t1 = 0.f, tb0 = 0.f, cc = 0.f;
    float tt[16];
#pragma unroll
    for (int t = 0; t < 16; ++t) tt[t] = 0.f;
    for (int k = 0; k < DD; ++k) {
        float wv = Wih[j * DD + k];
        float wg = wv * ln_g[k];
        te  += wg * Wedge[k];
        tw  += wg * Wstruct[k];
        t1  += wg;
        tb0 += wg * (bedge[k] + btime[k] + 2.f * bstruct[k]);
        cc  += wv * ln_b[k];
#pragma unroll
        for (int t = 0; t < 16; ++t) tt[t] += wg * Wtime[k * TDD + t];
    }
    out[0 * 192 + j] = te;
    out[1 * 192 + j] = tw;
    out[2 * 192 + j] = t1;
    out[3 * 192 + j] = tb0;
    out[4 * 192 + j] = cc + bih[j];
    for (int t = 0; t < 16; ++t) out[(5 + t) * 192 + j] = tt[t];
}

// ---------------------------------------------------------------------------
// Stats: per (b,l) LN mean + rsqrt(var), plus cos table. grid = 2*BB.
// ---------------------------------------------------------------------------
__global__ void __launch_bounds__(256)
stats_kernel(const int* __restrict__ nidsL, const int* __restrict__ eidsL,
             const float* __restrict__ timesL, const int* __restrict__ curL,
             const int* __restrict__ nidsQ, const int* __restrict__ eidsQ,
             const float* __restrict__ timesQ, const int* __restrict__ curQ,
             const float* __restrict__ node_raw, const float* __restrict__ edge_raw,
             const float* __restrict__ proj_node,
             const float* __restrict__ Wedge, const float* __restrict__ bedge,
             const float* __restrict__ Wtime, const float* __restrict__ btime,
             const float* __restrict__ Wstruct, const float* __restrict__ bstruct,
             float* __restrict__ ctab_out, float* __restrict__ stats_out)
{
    __shared__ float wtimeT[TDD][DD];
    __shared__ float cbuf[LHH][TDD];
    __shared__ float we_s[DD], ws_s[DD], b0_s[DD];
    const int blk = blockIdx.x;
    const int g = blk >> 9, b = blk & 511;
    const int* nids = g ? nidsQ : nidsL;
    const int* eids = g ? eidsQ : eidsL;
    const float* times = g ? timesQ : timesL;
    const int* curp = g ? curQ : curL;
    const int tid = threadIdx.x, lane = tid & 63, w = tid >> 6;
    if (tid < DD) {
        we_s[tid] = Wedge[tid];
        ws_s[tid] = Wstruct[tid];
        b0_s[tid] = bedge[tid] + btime[tid] + 2.f * bstruct[tid];
    }
    for (int i = tid; i < DD * TDD; i += 256) wtimeT[i & 15][i >> 4] = Wtime[i];
    for (int i = tid; i < LHH * TDD; i += 256) {
        int l = i >> 4, j = i & 15;
        float t = times[b * LHH + l];
        float cv = cosf(t * TFREQ[j]);
        cbuf[l][j] = cv;
        ctab_out[(size_t)blk * LHH * TDD + i] = cv;
    }
    const int cur = curp[b];
    const int csk = (int)node_raw[(size_t)cur * FF];
    __syncthreads();
    for (int l = w; l < LHH; l += 4) {
        int nid = nids[b * LHH + l];
        int eid = eids[b * LHH + l];
        float f = proj_node[(size_t)nid * DD + lane]
                + edge_raw[(size_t)eid * 4] * we_s[lane]
                + b0_s[lane];
        float flg = ((nid == cur) ? 1.f : 0.f)
                  + (((int)node_raw[(size_t)nid * FF] == csk) ? 1.f : 0.f);
        f += flg * ws_s[lane];
        float tf = 0.f;
#pragma unroll
        for (int j = 0; j < TDD; ++j) tf += cbuf[l][j] * wtimeT[j][lane];
        f += tf;
        float m = f;
#pragma unroll
        for (int off = 32; off; off >>= 1) m += __shfl_xor(m, off);
        m *= (1.f / 64.f);
        float dv = f - m, v = dv * dv;
#pragma unroll
        for (int off = 32; off; off >>= 1) v += __shfl_xor(v, off);
        v *= (1.f / 64.f);
        if (lane == 0)
            *(float2*)(stats_out + (size_t)(blk * LHH + l) * 2) = make_float2(m, rsqrtf(v + 1e-5f));
    }
}

// ---------------------------------------------------------------------------
// GRU: one sequence per 2-wave block; k-split matvec; readlane h broadcast.
// ---------------------------------------------------------------------------
__device__ __forceinline__ float sigm(float x) {
    return __builtin_amdgcn_rcpf(1.f + __expf(-x));
}
__device__ __forceinline__ float tanh_f(float x) {
    float e = __expf(2.f * x);
    return 1.f - 2.f * __builtin_amdgcn_rcpf(e + 1.f);
}
__device__ __forceinline__ float rl(float v, int l) {
    return __int_as_float(__builtin_amdgcn_readlane(__float_as_int(v), l));
}

__global__ void __launch_bounds__(128, 1)
gru2_kernel(const int* __restrict__ nidsL, const int* __restrict__ eidsL, const int* __restrict__ curL,
            const int* __restrict__ nidsQ, const int* __restrict__ eidsQ, const int* __restrict__ curQ,
            const float* __restrict__ node_raw, const float* __restrict__ edge_raw,
            const float* __restrict__ TnL, const float* __restrict__ TnQ,
            const float* __restrict__ cstL, const float* __restrict__ cstQ,
            const float* __restrict__ ctab, const float* __restrict__ stats,
            const float* __restrict__ WhhL, const float* __restrict__ bhhL,
            const float* __restrict__ WhhQ, const float* __restrict__ bhhQ,
            float* __restrict__ embL, float* __restrict__ embQ)
{
    __shared__ __align__(16) float part[2][2][64][4];   // [buf][wave][lane][{pr,pz,gin,an}]
    const int blk = blockIdx.x;
    const int g = blk >> 9, s = blk & 511;
    const int tid = threadIdx.x;
    const int d = tid & 63;
    const int wv = tid >> 6;
    const int kbase = wv * 32;

    const int*   nids = g ? nidsQ : nidsL;
    const int*   eids = g ? eidsQ : eidsL;
    const int*   curp = g ? curQ : curL;
    const float* Tn   = g ? TnQ : TnL;
    const float* cst  = g ? cstQ : cstL;
    const float* Whh  = g ? WhhQ : WhhL;
    const float* bhh  = g ? bhhQ : bhhL;
    float*       emb  = g ? embQ : embL;

    // --- per-thread Whh half-rows (k in [kbase, kbase+32)) : 96 VGPRs
    float w0[32], w1[32], w2[32];
#pragma unroll
    for (int k4 = 0; k4 < 8; ++k4) {
        float4 a = *(const float4*)(Whh + (size_t)d * DD + kbase + k4 * 4);
        w0[4*k4] = a.x; w0[4*k4+1] = a.y; w0[4*k4+2] = a.z; w0[4*k4+3] = a.w;
        float4 bq = *(const float4*)(Whh + (size_t)(64 + d) * DD + kbase + k4 * 4);
        w1[4*k4] = bq.x; w1[4*k4+1] = bq.y; w1[4*k4+2] = bq.z; w1[4*k4+3] = bq.w;
        float4 cq = *(const float4*)(Whh + (size_t)(128 + d) * DD + kbase + k4 * 4);
        w2[4*k4] = cq.x; w2[4*k4+1] = cq.y; w2[4*k4+2] = cq.z; w2[4*k4+3] = cq.w;
    }
    // --- cos-dot weights: wave wv takes t in [8wv, 8wv+8)
    float tt0[8], tt1[8], tt2[8];
#pragma unroll
    for (int t = 0; t < 8; ++t) {
        int tb = 8 * wv + t;
        tt0[t] = cst[(5 + tb) * 192 + d];
        tt1[t] = cst[(5 + tb) * 192 + 64 + d];
        tt2[t] = cst[(5 + tb) * 192 + 128 + d];
    }
    // --- additive consts (only wave 1 applies them)
    float TE0=0,TE1=0,TE2=0, TW0=0,TW1=0,TW2=0, T10=0,T11=0,T12=0,
          TB0=0,TB1=0,TB2=0, CC0=0,CC1=0,CC2=0, BH2=0;
    if (wv == 1) {
        TE0 = cst[0*192 + d]; TE1 = cst[0*192 + 64 + d]; TE2 = cst[0*192 + 128 + d];
        TW0 = cst[1*192 + d]; TW1 = cst[1*192 + 64 + d]; TW2 = cst[1*192 + 128 + d];
        T10 = cst[2*192 + d]; T11 = cst[2*192 + 64 + d]; T12 = cst[2*192 + 128 + d];
        TB0 = cst[3*192 + d]; TB1 = cst[3*192 + 64 + d]; TB2 = cst[3*192 + 128 + d];
        CC0 = cst[4*192 + d] + bhh[d];
        CC1 = cst[4*192 + 64 + d] + bhh[64 + d];
        CC2 = cst[4*192 + 128 + d];
        BH2 = bhh[128 + d];
    }
    const int cur = curp[s];
    const int csk = (int)node_raw[(size_t)cur * FF];
    const float* ct_b = ctab  + (size_t)blk * LHH * TDD + 8 * wv;
    const float* st_b = stats + (size_t)blk * LHH * 2;
    const int* nrow = nids + s * LHH;
    const int* erow = eids + s * LHH;

    // --- software pipeline, depth 2
    int nid0 = nrow[0], eid0 = erow[0];
    int nid1 = nrow[1], eid1 = erow[1];
    int nid2 = nrow[2], eid2 = erow[2];

    float tnC0=0, tnC1=0, tnC2=0, tnN0=0, tnN1=0, tnN2=0;
    float e0C=0, e0N=0, skC=0, skN=0;
    if (wv == 0) {
        tnC0 = Tn[(size_t)nid0 * 192 + d];
        tnC1 = Tn[(size_t)nid0 * 192 + 64 + d];
        tnC2 = Tn[(size_t)nid0 * 192 + 128 + d];
        tnN0 = Tn[(size_t)nid1 * 192 + d];
        tnN1 = Tn[(size_t)nid1 * 192 + 64 + d];
        tnN2 = Tn[(size_t)nid1 * 192 + 128 + d];
    } else {
        e0C = edge_raw[(size_t)eid0 * 4];
        e0N = edge_raw[(size_t)eid1 * 4];
        skC = node_raw[(size_t)nid0 * FF];
        skN = node_raw[(size_t)nid1 * FF];
    }
    float2 stC = *(const float2*)(st_b);
    float2 stN = *(const float2*)(st_b + 2);
    float4 cvC0 = *(const float4*)(ct_b);
    float4 cvC1 = *(const float4*)(ct_b + 4);
    float4 cvN0 = *(const float4*)(ct_b + TDD);
    float4 cvN1 = *(const float4*)(ct_b + TDD + 4);

    float h = 0.f;

    for (int l = 0; l < LHH; ++l) {
        // ---- issue loads for l+2 (ids already in nid2/eid2)
        float tnF0=0, tnF1=0, tnF2=0, e0F=0, skF=0;
        if (wv == 0) {
            tnF0 = Tn[(size_t)nid2 * 192 + d];
            tnF1 = Tn[(size_t)nid2 * 192 + 64 + d];
            tnF2 = Tn[(size_t)nid2 * 192 + 128 + d];
        } else {
            e0F = edge_raw[(size_t)eid2 * 4];
            skF = node_raw[(size_t)nid2 * FF];
        }
        int lc2 = (l + 2 < LHH) ? l + 2 : LHH - 1;
        int lc3 = (l + 3 < LHH) ? l + 3 : LHH - 1;
        float2 stF = *(const float2*)(st_b + 2 * lc2);
        float4 cvF0 = *(const float4*)(ct_b + (size_t)lc2 * TDD);
        float4 cvF1 = *(const float4*)(ct_b + (size_t)lc2 * TDD + 4);
        int nid3 = nrow[lc3], eid3 = erow[lc3];

        // ---- matvec partial over k-half (readlane broadcast of h)
        float p0a=0,p1a=0,p2a=0, p0b=0,p1b=0,p2b=0;
#pragma unroll
        for (int k = 0; k < 32; k += 2) {
            float ha = rl(h, kbase + k);
            float hb = rl(h, kbase + k + 1);
            p0a += w0[k] * ha;   p1a += w1[k] * ha;   p2a += w2[k] * ha;
            p0b += w0[k+1] * hb; p1b += w1[k+1] * hb; p2b += w2[k+1] * hb;
        }
        float mv0 = p0a + p0b, mv1 = p1a + p1b, mv2 = p2a + p2b;

        // ---- gi pre-terms (rs-scaled), wave-split additively
        float mu = stC.x, rs = stC.y;
        float pre0, pre1, pre2;
        {
            float c0 = tt0[0]*cvC0.x + tt0[1]*cvC0.y + tt0[2]*cvC0.z + tt0[3]*cvC0.w
                     + tt0[4]*cvC1.x + tt0[5]*cvC1.y + tt0[6]*cvC1.z + tt0[7]*cvC1.w;
            float c1 = tt1[0]*cvC0.x + tt1[1]*cvC0.y + tt1[2]*cvC0.z + tt1[3]*cvC0.w
                     + tt1[4]*cvC1.x + tt1[5]*cvC1.y + tt1[6]*cvC1.z + tt1[7]*cvC1.w;
            float c2 = tt2[0]*cvC0.x + tt2[1]*cvC0.y + tt2[2]*cvC0.z + tt2[3]*cvC0.w
                     + tt2[4]*cvC1.x + tt2[5]*cvC1.y + tt2[6]*cvC1.z + tt2[7]*cvC1.w;
            if (wv == 0) {
                pre0 = c0 + tnC0; pre1 = c1 + tnC1; pre2 = c2 + tnC2;
            } else {
                float flg = ((nid0 == cur) ? 1.f : 0.f) + (((int)skC == csk) ? 1.f : 0.f);
                pre0 = c0 + e0C * TE0 + flg * TW0 + TB0 - mu * T10;
                pre1 = c1 + e0C * TE1 + flg * TW1 + TB1 - mu * T11;
                pre2 = c2 + e0C * TE2 + flg * TW2 + TB2 - mu * T12;
            }
        }
        // partials: pr/pz merge gi+gh (+bias on wave1); n-gate keeps gi, gh separate
        float pr  = pre0 * rs + mv0 + CC0;       // CC0 includes bhh_r on wave1, 0 on wave0
        float pz  = pre1 * rs + mv1 + CC1;
        float gin = pre2 * rs + CC2;
        float an  = mv2 + BH2;

        // ---- exchange
        const int buf = l & 1;
        *(float4*)&part[buf][wv][d][0] = make_float4(pr, pz, gin, an);
        __syncthreads();
        float4 o = *(const float4*)&part[buf][1 - wv][d][0];

        float r = sigm(pr + o.x);
        float z = sigm(pz + o.y);
        float n = tanh_f((gin + o.z) + r * (an + o.w));
        h = (1.f - z) * n + z * h;

        // ---- rotate pipeline
        nid0 = nid1; nid1 = nid2; nid2 = nid3; eid2 = eid3;
        if (wv == 0) { tnC0 = tnN0; tnC1 = tnN1; tnC2 = tnN2; tnN0 = tnF0; tnN1 = tnF1; tnN2 = tnF2; }
        else         { e0C = e0N; e0N = e0F; skC = skN; skN = skF; }
        stC = stN; stN = stF;
        cvC0 = cvN0; cvC1 = cvN1; cvN0 = cvF0; cvN1 = cvF1;
    }
    if (wv == 0) emb[(size_t)s * DD + d] = h;
}

// ---------------------------------------------------------------------------
// K3: graph_emb — hash-dedup'd GCNConv + mean pool. 512 thr (8 waves)/block.
// ---------------------------------------------------------------------------
__device__ __forceinline__ int hlookup(const unsigned* hkey, const int* hslot, unsigned id)
{
    unsigned p = (id * 2654435761u) & (GE_HASH - 1);
    while (hkey[p] != id) p = (p + 1) & (GE_HASH - 1);
    return hslot[p];
}

__global__ void __launch_bounds__(512)
graph_emb_kernel(const int* __restrict__ retrieved, const int* __restrict__ pool_nodes,
                 const float* __restrict__ hgcn, const float* __restrict__ gcn_b,
                 float* __restrict__ glob)
{
    __shared__ float agg[400 * 64];
    __shared__ unsigned hkey[GE_HASH];
    __shared__ int hslot[GE_HASH];
    __shared__ unsigned ekey[GE_HASH];
    __shared__ int slot_id[400];
    __shared__ unsigned deg[400];
    __shared__ float dis[400];
    __shared__ unsigned elist[400];
    __shared__ int ids[400];
    __shared__ int pids[8];
    __shared__ int cntU, cntE;
    __shared__ float gcnb_s[64];
    __shared__ float red[8][64];

    const int b = blockIdx.x;
    const int tid = threadIdx.x;
    const int lane = tid & 63, wid = tid >> 6;

    if (tid < 8)  pids[tid] = retrieved[b * 8 + tid];
    if (tid < 64) gcnb_s[tid] = gcn_b[tid];
    if (tid == 0) { cntU = 0; cntE = 0; }
    for (int i = tid; i < GE_HASH; i += 512) { hkey[i] = 0u; ekey[i] = 0u; }
    if (tid < 400) deg[tid] = 0u;
    __syncthreads();

    if (tid < 400) {
        int k = tid / 50, p = tid % 50;
        ids[tid] = pool_nodes[(size_t)pids[k] * 50 + p];
    }
    __syncthreads();

    if (tid < 400) {
        int idi = ids[tid];
        if (idi > 0) {
            unsigned id = (unsigned)idi;
            unsigned p = (id * 2654435761u) & (GE_HASH - 1);
            while (true) {
                unsigned old = atomicCAS(&hkey[p], 0u, id);
                if (old == 0u) {
                    int s = atomicAdd(&cntU, 1);
                    hslot[p] = s; slot_id[s] = idi;
                    break;
                }
                if (old == id) break;
                p = (p + 1) & (GE_HASH - 1);
            }
        }
    }
    __syncthreads();

    if (tid < 8 * 49) {
        int k = tid / 49, p = tid % 49;
        int u = ids[k * 50 + p], v = ids[k * 50 + p + 1];
        if (u > 0 && v > 0) {
            unsigned a = (unsigned)min(u, v), bb = (unsigned)max(u, v);
            unsigned key = a * 40000u + bb;
            unsigned p2 = (key * 2654435761u) & (GE_HASH - 1);
            while (true) {
                unsigned old = atomicCAS(&ekey[p2], 0u, key);
                if (old == 0u) {
                    int su = hlookup(hkey, hslot, a);
                    int sv = hlookup(hkey, hslot, bb);
                    int e = atomicAdd(&cntE, 1);
                    elist[e] = ((unsigned)su << 16) | (unsigned)sv;
                    atomicAdd(&deg[su], 1u);
                    atomicAdd(&deg[sv], 1u);
                    break;
                }
                if (old == key) break;
                p2 = (p2 + 1) & (GE_HASH - 1);
            }
        }
    }
    __syncthreads();

    const int U = cntU, EC = cntE;
    if (tid < U) dis[tid] = rsqrtf((float)deg[tid] + 1.0f);
    __syncthreads();

    for (int s = wid; s < U; s += 8) {
        float d2 = dis[s] * dis[s];
        float hval = hgcn[(size_t)slot_id[s] * 64 + lane];
        agg[s * 64 + lane] = gcnb_s[lane] + d2 * hval;
    }
    __syncthreads();

    for (int e = wid; e < EC; e += 8) {
        unsigned pk = elist[e];
        int su = (int)(pk >> 16), sv = (int)(pk & 0xffffu);
        float nrm = dis[su] * dis[sv];
        float hu = hgcn[(size_t)slot_id[su] * 64 + lane];
        float hv = hgcn[(size_t)slot_id[sv] * 64 + lane];
        atomicAdd(&agg[sv * 64 + lane], nrm * hu);
        atomicAdd(&agg[su * 64 + lane], nrm * hv);
    }
    __syncthreads();

    float acc = 0.f;
    for (int s = wid; s < U; s += 8) acc += fmaxf(agg[s * 64 + lane], 0.f);
    red[wid][lane] = acc;
    __syncthreads();
    if (tid < 64) {
        float tot = 0.f;
#pragma unroll
        for (int q = 0; q < 8; ++q) tot += red[q][tid];
        glob[(size_t)b * 64 + tid] = tot / (float)max(U, 1);
    }
}

// ---------------------------------------------------------------------------
// K4: fusion + output heads.
// ---------------------------------------------------------------------------
__global__ void __launch_bounds__(64)
head_kernel(const float* __restrict__ local_emb, const float* __restrict__ glob,
            const float* __restrict__ q_emb,
            const float* __restrict__ fus_W, const float* __restrict__ fus_b,
            const float* __restrict__ out_W, const float* __restrict__ out_b,
            float* __restrict__ out)
{
    __shared__ float cat[128];
    __shared__ float fus[64];
    __shared__ float qv[64];
    const int b = blockIdx.x, d = threadIdx.x;
    cat[d]      = local_emb[(size_t)b * 64 + d];
    cat[64 + d] = glob[(size_t)b * 64 + d];
    qv[d]       = q_emb[(size_t)b * 64 + d];
    __syncthreads();
    float acc = fus_b[d];
    const float* fw = fus_W + (size_t)d * 128;
#pragma unroll 4
    for (int k = 0; k < 128; ++k) acc += cat[k] * fw[k];
    fus[d] = fmaxf(acc, 0.f);
    __syncthreads();
    float o0 = out_b[d], o1 = out_b[d];
    const float* ow = out_W + (size_t)d * 64;
#pragma unroll 4
    for (int k = 0; k < 64; ++k) { float ww = ow[k]; o0 += fus[k] * ww; o1 += qv[k] * ww; }
    out[(size_t)b * 64 + d] = o0;
    out[(size_t)BB * 64 + (size_t)b * 64 + d] = o1;
}

// ---------------------------------------------------------------------------
extern "C" void kernel_launch(void* const* d_in, const int* in_sizes, int n_in,
                              void* d_out, int out_size, void* d_ws, size_t ws_size,
                              hipStream_t stream)
{
    const int*   src_ids    = (const int*)d_in[0];
    const int*   dst_ids    = (const int*)d_in[1];
    const int*   l_nids     = (const int*)d_in[2];
    const int*   l_eids     = (const int*)d_in[3];
    const float* l_times    = (const float*)d_in[4];
    const int*   d_nids     = (const int*)d_in[5];
    const int*   d_eids     = (const int*)d_in[6];
    const float* d_times    = (const float*)d_in[7];
    const int*   retr       = (const int*)d_in[8];
    const float* node_raw   = (const float*)d_in[9];
    const float* edge_raw   = (const float*)d_in[10];
    const int*   pool_nodes = (const int*)d_in[11];
    const float* Wfeat  = (const float*)d_in[12];
    const float* bfeat  = (const float*)d_in[13];
    const float* Wedge  = (const float*)d_in[14];
    const float* bedge  = (const float*)d_in[15];
    const float* Wtime  = (const float*)d_in[16];
    const float* btime  = (const float*)d_in[17];
    const float* Wstruct= (const float*)d_in[18];
    const float* bstruct= (const float*)d_in[19];
    const float* ln_g   = (const float*)d_in[20];
    const float* ln_b   = (const float*)d_in[21];
    const float* gruL_Wih = (const float*)d_in[22];
    const float* gruL_Whh = (const float*)d_in[23];
    const float* gruL_bih = (const float*)d_in[24];
    const float* gruL_bhh = (const float*)d_in[25];
    const float* gruQ_Wih = (const float*)d_in[26];
    const float* gruQ_Whh = (const float*)d_in[27];
    const float* gruQ_bih = (const float*)d_in[28];
    const float* gruQ_bhh = (const float*)d_in[29];
    const float* gcn_W  = (const float*)d_in[30];
    const float* gcn_b  = (const float*)d_in[31];
    const float* fus_W  = (const float*)d_in[32];
    const float* fus_b  = (const float*)d_in[33];
    const float* out_W  = (const float*)d_in[34];
    const float* out_b  = (const float*)d_in[35];

    float* ws = (float*)d_ws;
    float* proj_node = ws;                              ws += (size_t)NN * DD;
    float* hgcn      = ws;                              ws += (size_t)NN * DD;
    float* TnL       = ws;                              ws += (size_t)NN * 192;
    float* TnQ       = ws;                              ws += (size_t)NN * 192;
    float* cstL      = ws;                              ws += 4096;
    float* cstQ      = ws;                              ws += 4096;
    float* ctab      = ws;                              ws += (size_t)2 * BB * LHH * TDD;
    float* stats     = ws;                              ws += (size_t)2 * BB * LHH * 2;
    float* local_emb = ws;                              ws += (size_t)BB * DD;
    float* q_emb     = ws;                              ws += (size_t)BB * DD;
    float* glob      = ws;                              ws += (size_t)BB * DD;

    dim3 g1((NN + 127) / 128);
    gemm_nt_kernel<FF><<<g1, 256, 0, stream>>>(node_raw, Wfeat, bfeat, proj_node, NN);

    consts_kernel<<<2, 192, 0, stream>>>(gruL_Wih, gruL_bih, cstL,
                                         gruQ_Wih, gruQ_bih, cstQ,
                                         ln_g, ln_b, Wedge, bedge, Wtime, btime,
                                         Wstruct, bstruct);

    gemm_nt_kernel<DD><<<g1, 256, 0, stream>>>(proj_node, gcn_W, nullptr, hgcn, NN);

    tn_gemm_kernel<<<dim3(NN / 64, 2), 256, 0, stream>>>(proj_node, gruL_Wih, gruQ_Wih,
                                                         ln_g, TnL, TnQ);

    stats_kernel<<<2 * BB, 256, 0, stream>>>(l_nids, l_eids, l_times, dst_ids,
        d_nids, d_eids, d_times, src_ids,
        node_raw, edge_raw, proj_node, Wedge, bedge, Wtime, btime, Wstruct, bstruct,
        ctab, stats);

    gru2_kernel<<<2 * BB, 128, 0, stream>>>(
        l_nids, l_eids, dst_ids, d_nids, d_eids, src_ids,
        node_raw, edge_raw, TnL, TnQ, cstL, cstQ, ctab, stats,
        gruL_Whh, gruL_bhh, gruQ_Whh, gruQ_bhh, local_emb, q_emb);

    graph_emb_kernel<<<BB, 512, 0, stream>>>(retr, pool_nodes, hgcn, gcn_b, glob);

    head_kernel<<<BB, 64, 0, stream>>>(local_emb, glob, q_emb,
        fus_W, fus_b, out_W, out_b, (float*)d_out);
}

// Round 5
// 510.830 us; speedup vs baseline: 1.4667x; 1.0695x over previous
//
#include <hip/hip_runtime.h>
#include <math.h>

#define NN 40000
#define FF 256
#define DD 64
#define LHH 200
#define BB 512
#define TDD 16
#define GE_HASH 1024

typedef _Float16 h2f __attribute__((ext_vector_type(2)));

__constant__ float TFREQ[16] = {
    1.0f,            0.48696753f,    0.23713737f,    0.115478195f,
    0.056234132f,    0.027384196f,   0.013335215f,   0.0064938162f,
    0.0031622776f,   0.0015399265f,  0.00074989421f, 0.00036517414f,
    0.00017782794f,  8.6596433e-05f, 4.2169650e-05f, 2.0535251e-05f
};

__device__ __forceinline__ float fd2(unsigned a, unsigned b, float c) {
    union { unsigned u; h2f h; } ua, ub;
    ua.u = a; ub.u = b;
    return __builtin_amdgcn_fdot2(ua.h, ub.h, c, false);
}
__device__ __forceinline__ unsigned packrn(float a, float b) {
    union { h2f h; unsigned u; } x;
    x.h.x = (_Float16)a; x.h.y = (_Float16)b;
    return x.u;
}
__device__ __forceinline__ unsigned pkrtz_u(float a, float b) {
    auto pk = __builtin_amdgcn_cvt_pkrtz(a, b);
    union { decltype(pk) h; unsigned u; } x;
    x.h = pk;
    return x.u;
}

// ---------------------------------------------------------------------------
// K1: C[n][0:64] = A[n][:] @ W[64][KDIM]^T + bias
// ---------------------------------------------------------------------------
template<int KDIM>
__global__ void __launch_bounds__(256)
gemm_nt_kernel(const float* __restrict__ A, const float* __restrict__ W,
               const float* __restrict__ bias, float* __restrict__ C, int Nrows)
{
    __shared__ __align__(16) float a_t[128][8];
    __shared__ __align__(16) float wt[8][64];
    const int tid = threadIdx.x;
    const int tx = tid & 15;
    const int ty = tid >> 4;
    const int n0 = blockIdx.x * 128;

    float4 acc[8];
#pragma unroll
    for (int r = 0; r < 8; ++r) acc[r] = make_float4(0.f, 0.f, 0.f, 0.f);

    for (int kc = 0; kc < KDIM; kc += 8) {
        __syncthreads();
        {
            int r = tid >> 1;
            int cc = (tid & 1) * 4;
            int n = n0 + r;
            float4 v = make_float4(0.f, 0.f, 0.f, 0.f);
            if (n < Nrows) v = *(const float4*)(A + (size_t)n * KDIM + kc + cc);
            *(float4*)&a_t[r][cc] = v;
        }
        {
            int m = tid >> 2;
            int f0 = (tid & 3) * 2;
            float2 v = *(const float2*)(W + (size_t)m * KDIM + kc + f0);
            wt[f0][m] = v.x; wt[f0 + 1][m] = v.y;
        }
        __syncthreads();
        float4 w4[8];
#pragma unroll
        for (int f = 0; f < 8; ++f) w4[f] = *(float4*)&wt[f][tx * 4];
#pragma unroll
        for (int rr = 0; rr < 8; ++rr) {
            int row = ty + rr * 16;
            float4 a0 = *(float4*)&a_t[row][0];
            float4 a1 = *(float4*)&a_t[row][4];
            float av[8] = {a0.x, a0.y, a0.z, a0.w, a1.x, a1.y, a1.z, a1.w};
#pragma unroll
            for (int f = 0; f < 8; ++f) {
                acc[rr].x += av[f] * w4[f].x;
                acc[rr].y += av[f] * w4[f].y;
                acc[rr].z += av[f] * w4[f].z;
                acc[rr].w += av[f] * w4[f].w;
            }
        }
    }
    float4 bv = make_float4(0.f, 0.f, 0.f, 0.f);
    if (bias) bv = *(const float4*)(bias + tx * 4);
#pragma unroll
    for (int rr = 0; rr < 8; ++rr) {
        int n = n0 + ty + rr * 16;
        if (n < Nrows) {
            float4 o = acc[rr];
            o.x += bv.x; o.y += bv.y; o.z += bv.z; o.w += bv.w;
            *(float4*)(C + (size_t)n * DD + tx * 4) = o;
        }
    }
}

// ---------------------------------------------------------------------------
// Tn[n][j] = sum_k proj[n][k] * Wih[j][k] * ln_g[k]; grid.y selects L/Q.
// ---------------------------------------------------------------------------
__global__ void __launch_bounds__(256)
tn_gemm_kernel(const float* __restrict__ proj,
               const float* __restrict__ WihL, const float* __restrict__ WihQ,
               const float* __restrict__ ln_g,
               float* __restrict__ TnL, float* __restrict__ TnQ)
{
    const float* Wih = blockIdx.y ? WihQ : WihL;
    float* Tn = blockIdx.y ? TnQ : TnL;
    __shared__ float wgT[64][193];
    __shared__ __align__(16) float4 at4[64][16];
    const int tid = threadIdx.x;
    const int n0 = blockIdx.x * 64;
    for (int i = tid; i < 192 * 64; i += 256) {
        int j = i >> 6, k = i & 63;
        wgT[k][j] = Wih[i] * ln_g[k];
    }
    for (int i = tid; i < 1024; i += 256) {
        int r = i >> 4, kc = i & 15;
        at4[r][kc] = ((const float4*)(proj + (size_t)(n0 + r) * DD))[kc];
    }
    __syncthreads();
    const int c = tid & 63, wv = tid >> 6;
    float acc0[16], acc1[16], acc2[16];
#pragma unroll
    for (int r = 0; r < 16; ++r) { acc0[r] = 0.f; acc1[r] = 0.f; acc2[r] = 0.f; }
    for (int kc = 0; kc < 16; ++kc) {
        float w0[4], w1[4], w2[4];
#pragma unroll
        for (int q = 0; q < 4; ++q) {
            w0[q] = wgT[kc * 4 + q][c];
            w1[q] = wgT[kc * 4 + q][64 + c];
            w2[q] = wgT[kc * 4 + q][128 + c];
        }
#pragma unroll
        for (int r = 0; r < 16; ++r) {
            float4 a = at4[wv * 16 + r][kc];
            acc0[r] += a.x * w0[0] + a.y * w0[1] + a.z * w0[2] + a.w * w0[3];
            acc1[r] += a.x * w1[0] + a.y * w1[1] + a.z * w1[2] + a.w * w1[3];
            acc2[r] += a.x * w2[0] + a.y * w2[1] + a.z * w2[2] + a.w * w2[3];
        }
    }
#pragma unroll
    for (int r = 0; r < 16; ++r) {
        size_t row = (size_t)(n0 + wv * 16 + r) * 192;
        Tn[row + c]       = acc0[r];
        Tn[row + 64 + c]  = acc1[r];
        Tn[row + 128 + c] = acc2[r];
    }
}

// ---------------------------------------------------------------------------
// Per-gate-row constants out[21][192] + f16-packed Whh (whp[192][32] u32).
// grid.x = 2 (L, Q)
// ---------------------------------------------------------------------------
__global__ void __launch_bounds__(192)
consts_kernel(const float* __restrict__ WihL, const float* __restrict__ bihL,
              const float* __restrict__ WhhL, float* __restrict__ outL, unsigned* __restrict__ whpL,
              const float* __restrict__ WihQ, const float* __restrict__ bihQ,
              const float* __restrict__ WhhQ, float* __restrict__ outQ, unsigned* __restrict__ whpQ,
              const float* __restrict__ ln_g, const float* __restrict__ ln_b,
              const float* __restrict__ Wedge, const float* __restrict__ bedge,
              const float* __restrict__ Wtime, const float* __restrict__ btime,
              const float* __restrict__ Wstruct, const float* __restrict__ bstruct)
{
    const float* Wih = blockIdx.x ? WihQ : WihL;
    const float* bih = blockIdx.x ? bihQ : bihL;
    const float* Whh = blockIdx.x ? WhhQ : WhhL;
    float* out = blockIdx.x ? outQ : outL;
    unsigned* whp = blockIdx.x ? whpQ : whpL;
    const int j = threadIdx.x;
    float te = 0.f, tw = 0.f, t1 = 0.f, tb0 = 0.f, cc = 0.f;
    float tt[16];
#pragma unroll
    for (int t = 0; t < 16; ++t) tt[t] = 0.f;
    for (int k = 0; k < DD; ++k) {
        float wv = Wih[j * DD + k];
        float wg = wv * ln_g[k];
        te  += wg * Wedge[k];
        tw  += wg * Wstruct[k];
        t1  += wg;
        tb0 += wg * (bedge[k] + btime[k] + 2.f * bstruct[k]);
        cc  += wv * ln_b[k];
#pragma unroll
        for (int t = 0; t < 16; ++t) tt[t] += wg * Wtime[k * TDD + t];
    }
    out[0 * 192 + j] = te;
    out[1 * 192 + j] = tw;
    out[2 * 192 + j] = t1;
    out[3 * 192 + j] = tb0;
    out[4 * 192 + j] = cc + bih[j];
    for (int t = 0; t < 16; ++t) out[(5 + t) * 192 + j] = tt[t];
    // f16-pack Whh row j (pairs along k)
    for (int k2 = 0; k2 < 32; ++k2)
        whp[j * 32 + k2] = packrn(Whh[j * DD + 2 * k2], Whh[j * DD + 2 * k2 + 1]);
}

// ---------------------------------------------------------------------------
// Stats: per (b,l) LN mean + rsqrt(var), plus packed-f16 cos table. grid=2*BB.
// ---------------------------------------------------------------------------
__global__ void __launch_bounds__(256)
stats_kernel(const int* __restrict__ nidsL, const int* __restrict__ eidsL,
             const float* __restrict__ timesL, const int* __restrict__ curL,
             const int* __restrict__ nidsQ, const int* __restrict__ eidsQ,
             const float* __restrict__ timesQ, const int* __restrict__ curQ,
             const float* __restrict__ node_raw, const float* __restrict__ edge_raw,
             const float* __restrict__ proj_node,
             const float* __restrict__ Wedge, const float* __restrict__ bedge,
             const float* __restrict__ Wtime, const float* __restrict__ btime,
             const float* __restrict__ Wstruct, const float* __restrict__ bstruct,
             unsigned* __restrict__ ctp_out, float* __restrict__ stats_out)
{
    __shared__ float wtimeT[TDD][DD];
    __shared__ float cbuf[LHH][TDD];
    __shared__ float we_s[DD], ws_s[DD], b0_s[DD];
    const int blk = blockIdx.x;
    const int g = blk >> 9, b = blk & 511;
    const int* nids = g ? nidsQ : nidsL;
    const int* eids = g ? eidsQ : eidsL;
    const float* times = g ? timesQ : timesL;
    const int* curp = g ? curQ : curL;
    const int tid = threadIdx.x, lane = tid & 63, w = tid >> 6;
    if (tid < DD) {
        we_s[tid] = Wedge[tid];
        ws_s[tid] = Wstruct[tid];
        b0_s[tid] = bedge[tid] + btime[tid] + 2.f * bstruct[tid];
    }
    for (int i = tid; i < DD * TDD; i += 256) wtimeT[i & 15][i >> 4] = Wtime[i];
    for (int i = tid; i < LHH * TDD; i += 256) {
        int l = i >> 4, j = i & 15;
        float t = times[b * LHH + l];
        cbuf[l][j] = cosf(t * TFREQ[j]);
    }
    const int cur = curp[b];
    const int csk = (int)node_raw[(size_t)cur * FF];
    __syncthreads();
    // packed cos table: 8 u32 per l
    for (int i = tid; i < LHH * 8; i += 256) {
        int l = i >> 3, p = i & 7;
        ctp_out[(size_t)blk * LHH * 8 + i] = packrn(cbuf[l][2 * p], cbuf[l][2 * p + 1]);
    }
    for (int l = w; l < LHH; l += 4) {
        int nid = nids[b * LHH + l];
        int eid = eids[b * LHH + l];
        float f = proj_node[(size_t)nid * DD + lane]
                + edge_raw[(size_t)eid * 4] * we_s[lane]
                + b0_s[lane];
        float flg = ((nid == cur) ? 1.f : 0.f)
                  + (((int)node_raw[(size_t)nid * FF] == csk) ? 1.f : 0.f);
        f += flg * ws_s[lane];
        float tf = 0.f;
#pragma unroll
        for (int j = 0; j < TDD; ++j) tf += cbuf[l][j] * wtimeT[j][lane];
        f += tf;
        float m = f;
#pragma unroll
        for (int off = 32; off; off >>= 1) m += __shfl_xor(m, off);
        m *= (1.f / 64.f);
        float dv = f - m, v = dv * dv;
#pragma unroll
        for (int off = 32; off; off >>= 1) v += __shfl_xor(v, off);
        v *= (1.f / 64.f);
        if (lane == 0)
            *(float2*)(stats_out + (size_t)(blk * LHH + l) * 2) = make_float2(m, rsqrtf(v + 1e-5f));
    }
}

// ---------------------------------------------------------------------------
// GRU: one sequence per 2-wave block; f16 dot2 matvec; readlane broadcast.
// ---------------------------------------------------------------------------
__device__ __forceinline__ float sigm(float x) {
    return __builtin_amdgcn_rcpf(1.f + __expf(-x));
}
__device__ __forceinline__ float tanh_f(float x) {
    float e = __expf(2.f * x);
    return 1.f - 2.f * __builtin_amdgcn_rcpf(e + 1.f);
}
__device__ __forceinline__ unsigned rlu(unsigned v, int l) {
    return (unsigned)__builtin_amdgcn_readlane((int)v, l);
}

struct Pos {
    int nid;
    float tn0, tn1, tn2;   // wave 0
    float e0, sk;          // wave 1
    float2 st;
    uint4 cv;
};

__global__ void __launch_bounds__(128, 1)
gru2_kernel(const int* __restrict__ nidsL, const int* __restrict__ eidsL, const int* __restrict__ curL,
            const int* __restrict__ nidsQ, const int* __restrict__ eidsQ, const int* __restrict__ curQ,
            const float* __restrict__ node_raw, const float* __restrict__ edge_raw,
            const float* __restrict__ TnL, const float* __restrict__ TnQ,
            const float* __restrict__ cstL, const float* __restrict__ cstQ,
            const unsigned* __restrict__ whpL, const unsigned* __restrict__ whpQ,
            const unsigned* __restrict__ ctp, const float* __restrict__ stats,
            const float* __restrict__ bhhL, const float* __restrict__ bhhQ,
            float* __restrict__ embL, float* __restrict__ embQ)
{
    __shared__ __align__(16) float part[2][2][64][4];
    const int blk = blockIdx.x;
    const int g = blk >> 9, s = blk & 511;
    const int tid = threadIdx.x;
    const int d = tid & 63;
    const int wv = __builtin_amdgcn_readfirstlane(tid >> 6);
    const int kbase = wv * 32;

    const int*      nids = g ? nidsQ : nidsL;
    const int*      eids = g ? eidsQ : eidsL;
    const int*      curp = g ? curQ : curL;
    const float*    Tn   = g ? TnQ : TnL;
    const float*    cst  = g ? cstQ : cstL;
    const unsigned* whp  = g ? whpQ : whpL;
    const float*    bhh  = g ? bhhQ : bhhL;
    float*          emb  = g ? embQ : embL;

    // packed Whh half-rows: 3 gates x 16 pairs = 48 VGPRs
    unsigned w0[16], w1[16], w2[16];
    {
        const unsigned* p0 = whp + (size_t)d * 32 + 16 * wv;
        const unsigned* p1 = whp + (size_t)(64 + d) * 32 + 16 * wv;
        const unsigned* p2 = whp + (size_t)(128 + d) * 32 + 16 * wv;
#pragma unroll
        for (int q4 = 0; q4 < 4; ++q4) {
            uint4 a = *(const uint4*)(p0 + 4 * q4);
            w0[4*q4] = a.x; w0[4*q4+1] = a.y; w0[4*q4+2] = a.z; w0[4*q4+3] = a.w;
            uint4 b = *(const uint4*)(p1 + 4 * q4);
            w1[4*q4] = b.x; w1[4*q4+1] = b.y; w1[4*q4+2] = b.z; w1[4*q4+3] = b.w;
            uint4 c = *(const uint4*)(p2 + 4 * q4);
            w2[4*q4] = c.x; w2[4*q4+1] = c.y; w2[4*q4+2] = c.z; w2[4*q4+3] = c.w;
        }
    }
    // packed cos-dot weights: wave's t in [8wv, 8wv+8) -> 4 pairs per gate
    unsigned tp0[4], tp1[4], tp2[4];
#pragma unroll
    for (int q = 0; q < 4; ++q) {
        int t = 8 * wv + 2 * q;
        tp0[q] = packrn(cst[(5 + t) * 192 + d],       cst[(6 + t) * 192 + d]);
        tp1[q] = packrn(cst[(5 + t) * 192 + 64 + d],  cst[(6 + t) * 192 + 64 + d]);
        tp2[q] = packrn(cst[(5 + t) * 192 + 128 + d], cst[(6 + t) * 192 + 128 + d]);
    }
    float TE0=0,TE1=0,TE2=0, TW0=0,TW1=0,TW2=0, T10=0,T11=0,T12=0,
          TB0=0,TB1=0,TB2=0, CC0=0,CC1=0,CC2=0, BH2=0;
    if (wv == 1) {
        TE0 = cst[0*192 + d]; TE1 = cst[0*192 + 64 + d]; TE2 = cst[0*192 + 128 + d];
        TW0 = cst[1*192 + d]; TW1 = cst[1*192 + 64 + d]; TW2 = cst[1*192 + 128 + d];
        T10 = cst[2*192 + d]; T11 = cst[2*192 + 64 + d]; T12 = cst[2*192 + 128 + d];
        TB0 = cst[3*192 + d]; TB1 = cst[3*192 + 64 + d]; TB2 = cst[3*192 + 128 + d];
        CC0 = cst[4*192 + d] + bhh[d];
        CC1 = cst[4*192 + 64 + d] + bhh[64 + d];
        CC2 = cst[4*192 + 128 + d];
        BH2 = bhh[128 + d];
    }
    const int cur = curp[s];
    const int csk = (int)node_raw[(size_t)cur * FF];
    const unsigned* ct_b = ctp + (size_t)blk * LHH * 8 + 4 * wv;
    const float* st_b = stats + (size_t)blk * LHH * 2;
    const int* nrow = nids + s * LHH;
    const int* erow = eids + s * LHH;

    float h = 0.f;

    auto LOADPOS = [&](Pos& P, int nid, int eid, int lpos) {
        P.nid = nid;
        if (wv == 0) {
            P.tn0 = Tn[(size_t)nid * 192 + d];
            P.tn1 = Tn[(size_t)nid * 192 + 64 + d];
            P.tn2 = Tn[(size_t)nid * 192 + 128 + d];
        } else {
            P.e0 = edge_raw[(size_t)eid * 4];
            P.sk = node_raw[(size_t)nid * FF];
        }
        P.st = *(const float2*)(st_b + 2 * lpos);
        P.cv = *(const uint4*)(ct_b + (size_t)lpos * 8);
    };

    auto COMPUTE = [&](const Pos& P, int buf) {
        // pack h with neighbor (quad_perm xor-1); even lanes hold (h[2k],h[2k+1])
        float hx = __int_as_float(
            __builtin_amdgcn_mov_dpp(__float_as_int(h), 0xB1, 0xF, 0xF, true));
        unsigned hpu = pkrtz_u(h, hx);
        float a0=0,a1=0,a2=0, b0=0,b1=0,b2=0;
#pragma unroll
        for (int q = 0; q < 16; q += 2) {
            unsigned sa = rlu(hpu, kbase + 2 * q);
            unsigned sb = rlu(hpu, kbase + 2 * q + 2);
            a0 = fd2(w0[q], sa, a0);
            a1 = fd2(w1[q], sa, a1);
            a2 = fd2(w2[q], sa, a2);
            b0 = fd2(w0[q+1], sb, b0);
            b1 = fd2(w1[q+1], sb, b1);
            b2 = fd2(w2[q+1], sb, b2);
        }
        float mv0 = a0 + b0, mv1 = a1 + b1, mv2 = a2 + b2;

        float c0 = fd2(tp0[3], P.cv.w, fd2(tp0[2], P.cv.z, fd2(tp0[1], P.cv.y, fd2(tp0[0], P.cv.x, 0.f))));
        float c1 = fd2(tp1[3], P.cv.w, fd2(tp1[2], P.cv.z, fd2(tp1[1], P.cv.y, fd2(tp1[0], P.cv.x, 0.f))));
        float c2 = fd2(tp2[3], P.cv.w, fd2(tp2[2], P.cv.z, fd2(tp2[1], P.cv.y, fd2(tp2[0], P.cv.x, 0.f))));

        float mu = P.st.x, rs = P.st.y;
        float pre0, pre1, pre2;
        if (wv == 0) {
            pre0 = c0 + P.tn0; pre1 = c1 + P.tn1; pre2 = c2 + P.tn2;
        } else {
            float flg = ((P.nid == cur) ? 1.f : 0.f) + (((int)P.sk == csk) ? 1.f : 0.f);
            pre0 = c0 + P.e0 * TE0 + flg * TW0 + TB0 - mu * T10;
            pre1 = c1 + P.e0 * TE1 + flg * TW1 + TB1 - mu * T11;
            pre2 = c2 + P.e0 * TE2 + flg * TW2 + TB2 - mu * T12;
        }
        float pr  = pre0 * rs + mv0 + CC0;
        float pz  = pre1 * rs + mv1 + CC1;
        float gin = pre2 * rs + CC2;
        float an  = mv2 + BH2;

        *(float4*)&part[buf][wv][d][0] = make_float4(pr, pz, gin, an);
        __syncthreads();
        float4 o = *(const float4*)&part[buf][1 - wv][d][0];

        float r = sigm(pr + o.x);
        float z = sigm(pz + o.y);
        float n = tanh_f((gin + o.z) + r * (an + o.w));
        h = (1.f - z) * n + z * h;
    };

    Pos PA, PB;
    LOADPOS(PA, nrow[0], erow[0], 0);
    LOADPOS(PB, nrow[1], erow[1], 1);
    int nid2 = nrow[2], eid2 = erow[2];

    for (int l = 0; l < LHH; l += 2) {
        {
            int l2 = (l + 2 < LHH) ? l + 2 : LHH - 1;
            int l3 = (l + 3 < LHH) ? l + 3 : LHH - 1;
            int nidF = nid2, eidF = eid2;
            nid2 = nrow[l3]; eid2 = erow[l3];
            Pos PF; LOADPOS(PF, nidF, eidF, l2);
            COMPUTE(PA, 0);
            PA = PF;
        }
        {
            int l2 = (l + 3 < LHH) ? l + 3 : LHH - 1;
            int l3 = (l + 4 < LHH) ? l + 4 : LHH - 1;
            int nidF = nid2, eidF = eid2;
            nid2 = nrow[l3]; eid2 = erow[l3];
            Pos PF; LOADPOS(PF, nidF, eidF, l2);
            COMPUTE(PB, 1);
            PB = PF;
        }
    }
    if (wv == 0) emb[(size_t)s * DD + d] = h;
}

// ---------------------------------------------------------------------------
// K3: graph_emb — hash-dedup'd GCNConv + mean pool. 512 thr (8 waves)/block.
// ---------------------------------------------------------------------------
__device__ __forceinline__ int hlookup(const unsigned* hkey, const int* hslot, unsigned id)
{
    unsigned p = (id * 2654435761u) & (GE_HASH - 1);
    while (hkey[p] != id) p = (p + 1) & (GE_HASH - 1);
    return hslot[p];
}

__global__ void __launch_bounds__(512)
graph_emb_kernel(const int* __restrict__ retrieved, const int* __restrict__ pool_nodes,
                 const float* __restrict__ hgcn, const float* __restrict__ gcn_b,
                 float* __restrict__ glob)
{
    __shared__ float agg[400 * 64];
    __shared__ unsigned hkey[GE_HASH];
    __shared__ int hslot[GE_HASH];
    __shared__ unsigned ekey[GE_HASH];
    __shared__ int slot_id[400];
    __shared__ unsigned deg[400];
    __shared__ float dis[400];
    __shared__ unsigned elist[400];
    __shared__ int ids[400];
    __shared__ int pids[8];
    __shared__ int cntU, cntE;
    __shared__ float gcnb_s[64];
    __shared__ float red[8][64];

    const int b = blockIdx.x;
    const int tid = threadIdx.x;
    const int lane = tid & 63, wid = tid >> 6;

    if (tid < 8)  pids[tid] = retrieved[b * 8 + tid];
    if (tid < 64) gcnb_s[tid] = gcn_b[tid];
    if (tid == 0) { cntU = 0; cntE = 0; }
    for (int i = tid; i < GE_HASH; i += 512) { hkey[i] = 0u; ekey[i] = 0u; }
    if (tid < 400) deg[tid] = 0u;
    __syncthreads();

    if (tid < 400) {
        int k = tid / 50, p = tid % 50;
        ids[tid] = pool_nodes[(size_t)pids[k] * 50 + p];
    }
    __syncthreads();

    if (tid < 400) {
        int idi = ids[tid];
        if (idi > 0) {
            unsigned id = (unsigned)idi;
            unsigned p = (id * 2654435761u) & (GE_HASH - 1);
            while (true) {
                unsigned old = atomicCAS(&hkey[p], 0u, id);
                if (old == 0u) {
                    int s = atomicAdd(&cntU, 1);
                    hslot[p] = s; slot_id[s] = idi;
                    break;
                }
                if (old == id) break;
                p = (p + 1) & (GE_HASH - 1);
            }
        }
    }
    __syncthreads();

    if (tid < 8 * 49) {
        int k = tid / 49, p = tid % 49;
        int u = ids[k * 50 + p], v = ids[k * 50 + p + 1];
        if (u > 0 && v > 0) {
            unsigned a = (unsigned)min(u, v), bb = (unsigned)max(u, v);
            unsigned key = a * 40000u + bb;
            unsigned p2 = (key * 2654435761u) & (GE_HASH - 1);
            while (true) {
                unsigned old = atomicCAS(&ekey[p2], 0u, key);
                if (old == 0u) {
                    int su = hlookup(hkey, hslot, a);
                    int sv = hlookup(hkey, hslot, bb);
                    int e = atomicAdd(&cntE, 1);
                    elist[e] = ((unsigned)su << 16) | (unsigned)sv;
                    atomicAdd(&deg[su], 1u);
                    atomicAdd(&deg[sv], 1u);
                    break;
                }
                if (old == key) break;
                p2 = (p2 + 1) & (GE_HASH - 1);
            }
        }
    }
    __syncthreads();

    const int U = cntU, EC = cntE;
    if (tid < U) dis[tid] = rsqrtf((float)deg[tid] + 1.0f);
    __syncthreads();

    for (int s = wid; s < U; s += 8) {
        float d2 = dis[s] * dis[s];
        float hval = hgcn[(size_t)slot_id[s] * 64 + lane];
        agg[s * 64 + lane] = gcnb_s[lane] + d2 * hval;
    }
    __syncthreads();

    for (int e = wid; e < EC; e += 8) {
        unsigned pk = elist[e];
        int su = (int)(pk >> 16), sv = (int)(pk & 0xffffu);
        float nrm = dis[su] * dis[sv];
        float hu = hgcn[(size_t)slot_id[su] * 64 + lane];
        float hv = hgcn[(size_t)slot_id[sv] * 64 + lane];
        atomicAdd(&agg[sv * 64 + lane], nrm * hu);
        atomicAdd(&agg[su * 64 + lane], nrm * hv);
    }
    __syncthreads();

    float acc = 0.f;
    for (int s = wid; s < U; s += 8) acc += fmaxf(agg[s * 64 + lane], 0.f);
    red[wid][lane] = acc;
    __syncthreads();
    if (tid < 64) {
        float tot = 0.f;
#pragma unroll
        for (int q = 0; q < 8; ++q) tot += red[q][tid];
        glob[(size_t)b * 64 + tid] = tot / (float)max(U, 1);
    }
}

// ---------------------------------------------------------------------------
// K4: fusion + output heads.
// ---------------------------------------------------------------------------
__global__ void __launch_bounds__(64)
head_kernel(const float* __restrict__ local_emb, const float* __restrict__ glob,
            const float* __restrict__ q_emb,
            const float* __restrict__ fus_W, const float* __restrict__ fus_b,
            const float* __restrict__ out_W, const float* __restrict__ out_b,
            float* __restrict__ out)
{
    __shared__ float cat[128];
    __shared__ float fus[64];
    __shared__ float qv[64];
    const int b = blockIdx.x, d = threadIdx.x;
    cat[d]      = local_emb[(size_t)b * 64 + d];
    cat[64 + d] = glob[(size_t)b * 64 + d];
    qv[d]       = q_emb[(size_t)b * 64 + d];
    __syncthreads();
    float acc = fus_b[d];
    const float* fw = fus_W + (size_t)d * 128;
#pragma unroll 4
    for (int k = 0; k < 128; ++k) acc += cat[k] * fw[k];
    fus[d] = fmaxf(acc, 0.f);
    __syncthreads();
    float o0 = out_b[d], o1 = out_b[d];
    const float* ow = out_W + (size_t)d * 64;
#pragma unroll 4
    for (int k = 0; k < 64; ++k) { float ww = ow[k]; o0 += fus[k] * ww; o1 += qv[k] * ww; }
    out[(size_t)b * 64 + d] = o0;
    out[(size_t)BB * 64 + (size_t)b * 64 + d] = o1;
}

// ---------------------------------------------------------------------------
extern "C" void kernel_launch(void* const* d_in, const int* in_sizes, int n_in,
                              void* d_out, int out_size, void* d_ws, size_t ws_size,
                              hipStream_t stream)
{
    const int*   src_ids    = (const int*)d_in[0];
    const int*   dst_ids    = (const int*)d_in[1];
    const int*   l_nids     = (const int*)d_in[2];
    const int*   l_eids     = (const int*)d_in[3];
    const float* l_times    = (const float*)d_in[4];
    const int*   d_nids     = (const int*)d_in[5];
    const int*   d_eids     = (const int*)d_in[6];
    const float* d_times    = (const float*)d_in[7];
    const int*   retr       = (const int*)d_in[8];
    const float* node_raw   = (const float*)d_in[9];
    const float* edge_raw   = (const float*)d_in[10];
    const int*   pool_nodes = (const int*)d_in[11];
    const float* Wfeat  = (const float*)d_in[12];
    const float* bfeat  = (const float*)d_in[13];
    const float* Wedge  = (const float*)d_in[14];
    const float* bedge  = (const float*)d_in[15];
    const float* Wtime  = (const float*)d_in[16];
    const float* btime  = (const float*)d_in[17];
    const float* Wstruct= (const float*)d_in[18];
    const float* bstruct= (const float*)d_in[19];
    const float* ln_g   = (const float*)d_in[20];
    const float* ln_b   = (const float*)d_in[21];
    const float* gruL_Wih = (const float*)d_in[22];
    const float* gruL_Whh = (const float*)d_in[23];
    const float* gruL_bih = (const float*)d_in[24];
    const float* gruL_bhh = (const float*)d_in[25];
    const float* gruQ_Wih = (const float*)d_in[26];
    const float* gruQ_Whh = (const float*)d_in[27];
    const float* gruQ_bih = (const float*)d_in[28];
    const float* gruQ_bhh = (const float*)d_in[29];
    const float* gcn_W  = (const float*)d_in[30];
    const float* gcn_b  = (const float*)d_in[31];
    const float* fus_W  = (const float*)d_in[32];
    const float* fus_b  = (const float*)d_in[33];
    const float* out_W  = (const float*)d_in[34];
    const float* out_b  = (const float*)d_in[35];

    float* ws = (float*)d_ws;
    float* proj_node = ws;                              ws += (size_t)NN * DD;
    float* hgcn      = ws;                              ws += (size_t)NN * DD;
    float* TnL       = ws;                              ws += (size_t)NN * 192;
    float* TnQ       = ws;                              ws += (size_t)NN * 192;
    float* cstL      = ws;                              ws += 4096;
    float* cstQ      = ws;                              ws += 4096;
    unsigned* whpL   = (unsigned*)ws;                   ws += 192 * 32;
    unsigned* whpQ   = (unsigned*)ws;                   ws += 192 * 32;
    unsigned* ctp    = (unsigned*)ws;                   ws += (size_t)2 * BB * LHH * 8;
    float* stats     = ws;                              ws += (size_t)2 * BB * LHH * 2;
    float* local_emb = ws;                              ws += (size_t)BB * DD;
    float* q_emb     = ws;                              ws += (size_t)BB * DD;
    float* glob      = ws;                              ws += (size_t)BB * DD;

    dim3 g1((NN + 127) / 128);
    gemm_nt_kernel<FF><<<g1, 256, 0, stream>>>(node_raw, Wfeat, bfeat, proj_node, NN);

    consts_kernel<<<2, 192, 0, stream>>>(gruL_Wih, gruL_bih, gruL_Whh, cstL, whpL,
                                         gruQ_Wih, gruQ_bih, gruQ_Whh, cstQ, whpQ,
                                         ln_g, ln_b, Wedge, bedge, Wtime, btime,
                                         Wstruct, bstruct);

    gemm_nt_kernel<DD><<<g1, 256, 0, stream>>>(proj_node, gcn_W, nullptr, hgcn, NN);

    tn_gemm_kernel<<<dim3(NN / 64, 2), 256, 0, stream>>>(proj_node, gruL_Wih, gruQ_Wih,
                                                         ln_g, TnL, TnQ);

    stats_kernel<<<2 * BB, 256, 0, stream>>>(l_nids, l_eids, l_times, dst_ids,
        d_nids, d_eids, d_times, src_ids,
        node_raw, edge_raw, proj_node, Wedge, bedge, Wtime, btime, Wstruct, bstruct,
        ctp, stats);

    gru2_kernel<<<2 * BB, 128, 0, stream>>>(
        l_nids, l_eids, dst_ids, d_nids, d_eids, src_ids,
        node_raw, edge_raw, TnL, TnQ, cstL, cstQ, whpL, whpQ, ctp, stats,
        gruL_bhh, gruQ_bhh, local_emb, q_emb);

    graph_emb_kernel<<<BB, 512, 0, stream>>>(retr, pool_nodes, hgcn, gcn_b, glob);

    head_kernel<<<BB, 64, 0, stream>>>(local_emb, glob, q_emb,
        fus_W, fus_b, out_W, out_b, (float*)d_out);
}

// Round 6
// 510.000 us; speedup vs baseline: 1.4691x; 1.0016x over previous
//
#include <hip/hip_runtime.h>
#include <math.h>

#define NN 40000
#define FF 256
#define DD 64
#define LHH 200
#define BB 512
#define TDD 16
#define GE_HASH 1024

typedef _Float16 h2f __attribute__((ext_vector_type(2)));

__constant__ float TFREQ[16] = {
    1.0f,            0.48696753f,    0.23713737f,    0.115478195f,
    0.056234132f,    0.027384196f,   0.013335215f,   0.0064938162f,
    0.0031622776f,   0.0015399265f,  0.00074989421f, 0.00036517414f,
    0.00017782794f,  8.6596433e-05f, 4.2169650e-05f, 2.0535251e-05f
};

__device__ __forceinline__ float fd2(unsigned a, unsigned b, float c) {
    union { unsigned u; h2f h; } ua, ub;
    ua.u = a; ub.u = b;
    return __builtin_amdgcn_fdot2(ua.h, ub.h, c, false);
}
__device__ __forceinline__ unsigned packrn(float a, float b) {
    union { h2f h; unsigned u; } x;
    x.h.x = (_Float16)a; x.h.y = (_Float16)b;
    return x.u;
}
__device__ __forceinline__ unsigned pkrtz_u(float a, float b) {
    auto pk = __builtin_amdgcn_cvt_pkrtz(a, b);
    union { decltype(pk) h; unsigned u; } x;
    x.h = pk;
    return x.u;
}

// ---------------------------------------------------------------------------
// K1: C[n][0:64] = A[n][:] @ W[64][KDIM]^T + bias
// ---------------------------------------------------------------------------
template<int KDIM>
__global__ void __launch_bounds__(256)
gemm_nt_kernel(const float* __restrict__ A, const float* __restrict__ W,
               const float* __restrict__ bias, float* __restrict__ C, int Nrows)
{
    __shared__ __align__(16) float a_t[128][8];
    __shared__ __align__(16) float wt[8][64];
    const int tid = threadIdx.x;
    const int tx = tid & 15;
    const int ty = tid >> 4;
    const int n0 = blockIdx.x * 128;

    float4 acc[8];
#pragma unroll
    for (int r = 0; r < 8; ++r) acc[r] = make_float4(0.f, 0.f, 0.f, 0.f);

    for (int kc = 0; kc < KDIM; kc += 8) {
        __syncthreads();
        {
            int r = tid >> 1;
            int cc = (tid & 1) * 4;
            int n = n0 + r;
            float4 v = make_float4(0.f, 0.f, 0.f, 0.f);
            if (n < Nrows) v = *(const float4*)(A + (size_t)n * KDIM + kc + cc);
            *(float4*)&a_t[r][cc] = v;
        }
        {
            int m = tid >> 2;
            int f0 = (tid & 3) * 2;
            float2 v = *(const float2*)(W + (size_t)m * KDIM + kc + f0);
            wt[f0][m] = v.x; wt[f0 + 1][m] = v.y;
        }
        __syncthreads();
        float4 w4[8];
#pragma unroll
        for (int f = 0; f < 8; ++f) w4[f] = *(float4*)&wt[f][tx * 4];
#pragma unroll
        for (int rr = 0; rr < 8; ++rr) {
            int row = ty + rr * 16;
            float4 a0 = *(float4*)&a_t[row][0];
            float4 a1 = *(float4*)&a_t[row][4];
            float av[8] = {a0.x, a0.y, a0.z, a0.w, a1.x, a1.y, a1.z, a1.w};
#pragma unroll
            for (int f = 0; f < 8; ++f) {
                acc[rr].x += av[f] * w4[f].x;
                acc[rr].y += av[f] * w4[f].y;
                acc[rr].z += av[f] * w4[f].z;
                acc[rr].w += av[f] * w4[f].w;
            }
        }
    }
    float4 bv = make_float4(0.f, 0.f, 0.f, 0.f);
    if (bias) bv = *(const float4*)(bias + tx * 4);
#pragma unroll
    for (int rr = 0; rr < 8; ++rr) {
        int n = n0 + ty + rr * 16;
        if (n < Nrows) {
            float4 o = acc[rr];
            o.x += bv.x; o.y += bv.y; o.z += bv.z; o.w += bv.w;
            *(float4*)(C + (size_t)n * DD + tx * 4) = o;
        }
    }
}

// ---------------------------------------------------------------------------
// Tn[n][j] = sum_k proj[n][k] * Wih[j][k] * ln_g[k]; grid.y selects L/Q.
// ---------------------------------------------------------------------------
__global__ void __launch_bounds__(256)
tn_gemm_kernel(const float* __restrict__ proj,
               const float* __restrict__ WihL, const float* __restrict__ WihQ,
               const float* __restrict__ ln_g,
               float* __restrict__ TnL, float* __restrict__ TnQ)
{
    const float* Wih = blockIdx.y ? WihQ : WihL;
    float* Tn = blockIdx.y ? TnQ : TnL;
    __shared__ float wgT[64][193];
    __shared__ __align__(16) float4 at4[64][16];
    const int tid = threadIdx.x;
    const int n0 = blockIdx.x * 64;
    for (int i = tid; i < 192 * 64; i += 256) {
        int j = i >> 6, k = i & 63;
        wgT[k][j] = Wih[i] * ln_g[k];
    }
    for (int i = tid; i < 1024; i += 256) {
        int r = i >> 4, kc = i & 15;
        at4[r][kc] = ((const float4*)(proj + (size_t)(n0 + r) * DD))[kc];
    }
    __syncthreads();
    const int c = tid & 63, wv = tid >> 6;
    float acc0[16], acc1[16], acc2[16];
#pragma unroll
    for (int r = 0; r < 16; ++r) { acc0[r] = 0.f; acc1[r] = 0.f; acc2[r] = 0.f; }
    for (int kc = 0; kc < 16; ++kc) {
        float w0[4], w1[4], w2[4];
#pragma unroll
        for (int q = 0; q < 4; ++q) {
            w0[q] = wgT[kc * 4 + q][c];
            w1[q] = wgT[kc * 4 + q][64 + c];
            w2[q] = wgT[kc * 4 + q][128 + c];
        }
#pragma unroll
        for (int r = 0; r < 16; ++r) {
            float4 a = at4[wv * 16 + r][kc];
            acc0[r] += a.x * w0[0] + a.y * w0[1] + a.z * w0[2] + a.w * w0[3];
            acc1[r] += a.x * w1[0] + a.y * w1[1] + a.z * w1[2] + a.w * w1[3];
            acc2[r] += a.x * w2[0] + a.y * w2[1] + a.z * w2[2] + a.w * w2[3];
        }
    }
#pragma unroll
    for (int r = 0; r < 16; ++r) {
        size_t row = (size_t)(n0 + wv * 16 + r) * 192;
        Tn[row + c]       = acc0[r];
        Tn[row + 64 + c]  = acc1[r];
        Tn[row + 128 + c] = acc2[r];
    }
}

// ---------------------------------------------------------------------------
// Per-gate-row constants out[21][192] + f16-packed Whh (whp[192][32] u32).
// grid.x = 2 (L, Q)
// ---------------------------------------------------------------------------
__global__ void __launch_bounds__(192)
consts_kernel(const float* __restrict__ WihL, const float* __restrict__ bihL,
              const float* __restrict__ WhhL, float* __restrict__ outL, unsigned* __restrict__ whpL,
              const float* __restrict__ WihQ, const float* __restrict__ bihQ,
              const float* __restrict__ WhhQ, float* __restrict__ outQ, unsigned* __restrict__ whpQ,
              const float* __restrict__ ln_g, const float* __restrict__ ln_b,
              const float* __restrict__ Wedge, const float* __restrict__ bedge,
              const float* __restrict__ Wtime, const float* __restrict__ btime,
              const float* __restrict__ Wstruct, const float* __restrict__ bstruct)
{
    const float* Wih = blockIdx.x ? WihQ : WihL;
    const float* bih = blockIdx.x ? bihQ : bihL;
    const float* Whh = blockIdx.x ? WhhQ : WhhL;
    float* out = blockIdx.x ? outQ : outL;
    unsigned* whp = blockIdx.x ? whpQ : whpL;
    const int j = threadIdx.x;
    float te = 0.f, tw = 0.f, t1 = 0.f, tb0 = 0.f, cc = 0.f;
    float tt[16];
#pragma unroll
    for (int t = 0; t < 16; ++t) tt[t] = 0.f;
    for (int k = 0; k < DD; ++k) {
        float wv = Wih[j * DD + k];
        float wg = wv * ln_g[k];
        te  += wg * Wedge[k];
        tw  += wg * Wstruct[k];
        t1  += wg;
        tb0 += wg * (bedge[k] + btime[k] + 2.f * bstruct[k]);
        cc  += wv * ln_b[k];
#pragma unroll
        for (int t = 0; t < 16; ++t) tt[t] += wg * Wtime[k * TDD + t];
    }
    out[0 * 192 + j] = te;
    out[1 * 192 + j] = tw;
    out[2 * 192 + j] = t1;
    out[3 * 192 + j] = tb0;
    out[4 * 192 + j] = cc + bih[j];
    for (int t = 0; t < 16; ++t) out[(5 + t) * 192 + j] = tt[t];
    // f16-pack Whh row j (pairs along k)
    for (int k2 = 0; k2 < 32; ++k2)
        whp[j * 32 + k2] = packrn(Whh[j * DD + 2 * k2], Whh[j * DD + 2 * k2 + 1]);
}

// ---------------------------------------------------------------------------
// Stats: per (b,l) LN mean + rsqrt(var), plus packed-f16 cos table. grid=2*BB.
// ---------------------------------------------------------------------------
__global__ void __launch_bounds__(256)
stats_kernel(const int* __restrict__ nidsL, const int* __restrict__ eidsL,
             const float* __restrict__ timesL, const int* __restrict__ curL,
             const int* __restrict__ nidsQ, const int* __restrict__ eidsQ,
             const float* __restrict__ timesQ, const int* __restrict__ curQ,
             const float* __restrict__ node_raw, const float* __restrict__ edge_raw,
             const float* __restrict__ proj_node,
             const float* __restrict__ Wedge, const float* __restrict__ bedge,
             const float* __restrict__ Wtime, const float* __restrict__ btime,
             const float* __restrict__ Wstruct, const float* __restrict__ bstruct,
             unsigned* __restrict__ ctp_out, float* __restrict__ stats_out)
{
    __shared__ float wtimeT[TDD][DD];
    __shared__ float cbuf[LHH][TDD];
    __shared__ float we_s[DD], ws_s[DD], b0_s[DD];
    const int blk = blockIdx.x;
    const int g = blk >> 9, b = blk & 511;
    const int* nids = g ? nidsQ : nidsL;
    const int* eids = g ? eidsQ : eidsL;
    const float* times = g ? timesQ : timesL;
    const int* curp = g ? curQ : curL;
    const int tid = threadIdx.x, lane = tid & 63, w = tid >> 6;
    if (tid < DD) {
        we_s[tid] = Wedge[tid];
        ws_s[tid] = Wstruct[tid];
        b0_s[tid] = bedge[tid] + btime[tid] + 2.f * bstruct[tid];
    }
    for (int i = tid; i < DD * TDD; i += 256) wtimeT[i & 15][i >> 4] = Wtime[i];
    for (int i = tid; i < LHH * TDD; i += 256) {
        int l = i >> 4, j = i & 15;
        float t = times[b * LHH + l];
        cbuf[l][j] = cosf(t * TFREQ[j]);
    }
    const int cur = curp[b];
    const int csk = (int)node_raw[(size_t)cur * FF];
    __syncthreads();
    // packed cos table: 8 u32 per l
    for (int i = tid; i < LHH * 8; i += 256) {
        int l = i >> 3, p = i & 7;
        ctp_out[(size_t)blk * LHH * 8 + i] = packrn(cbuf[l][2 * p], cbuf[l][2 * p + 1]);
    }
    for (int l = w; l < LHH; l += 4) {
        int nid = nids[b * LHH + l];
        int eid = eids[b * LHH + l];
        float f = proj_node[(size_t)nid * DD + lane]
                + edge_raw[(size_t)eid * 4] * we_s[lane]
                + b0_s[lane];
        float flg = ((nid == cur) ? 1.f : 0.f)
                  + (((int)node_raw[(size_t)nid * FF] == csk) ? 1.f : 0.f);
        f += flg * ws_s[lane];
        float tf = 0.f;
#pragma unroll
        for (int j = 0; j < TDD; ++j) tf += cbuf[l][j] * wtimeT[j][lane];
        f += tf;
        float m = f;
#pragma unroll
        for (int off = 32; off; off >>= 1) m += __shfl_xor(m, off);
        m *= (1.f / 64.f);
        float dv = f - m, v = dv * dv;
#pragma unroll
        for (int off = 32; off; off >>= 1) v += __shfl_xor(v, off);
        v *= (1.f / 64.f);
        if (lane == 0)
            *(float2*)(stats_out + (size_t)(blk * LHH + l) * 2) = make_float2(m, rsqrtf(v + 1e-5f));
    }
}

// ---------------------------------------------------------------------------
// GRU: ONE wave per sequence. Full-k f16 matvec in-wave (96 weight VGPRs),
// h broadcast via dpp-pack + readlane. No LDS, no barriers.
// 4-slot zero-copy software pipeline (loads issued 3 steps ahead).
// ---------------------------------------------------------------------------
__device__ __forceinline__ float sigm(float x) {
    return __builtin_amdgcn_rcpf(1.f + __expf(-x));
}
__device__ __forceinline__ float tanh_f(float x) {
    float e = __expf(2.f * x);
    return 1.f - 2.f * __builtin_amdgcn_rcpf(e + 1.f);
}
__device__ __forceinline__ unsigned rlu(unsigned v, int l) {
    return (unsigned)__builtin_amdgcn_readlane((int)v, l);
}

struct Pos {
    int nid;
    float tn0, tn1, tn2;
    float e0, sk;
    float2 st;
    uint4 cv0, cv1;
};

__global__ void __launch_bounds__(64, 1)
gru1_kernel(const int* __restrict__ nidsL, const int* __restrict__ eidsL, const int* __restrict__ curL,
            const int* __restrict__ nidsQ, const int* __restrict__ eidsQ, const int* __restrict__ curQ,
            const float* __restrict__ node_raw, const float* __restrict__ edge_raw,
            const float* __restrict__ TnL, const float* __restrict__ TnQ,
            const float* __restrict__ cstL, const float* __restrict__ cstQ,
            const unsigned* __restrict__ whpL, const unsigned* __restrict__ whpQ,
            const unsigned* __restrict__ ctp, const float* __restrict__ stats,
            const float* __restrict__ bhhL, const float* __restrict__ bhhQ,
            float* __restrict__ embL, float* __restrict__ embQ)
{
    const int blk = blockIdx.x;
    const int g = blk >> 9, s = blk & 511;
    const int d = threadIdx.x;

    const int*      nids = g ? nidsQ : nidsL;
    const int*      eids = g ? eidsQ : eidsL;
    const int*      curp = g ? curQ : curL;
    const float*    Tn   = g ? TnQ : TnL;
    const float*    cst  = g ? cstQ : cstL;
    const unsigned* whp  = g ? whpQ : whpL;
    const float*    bhh  = g ? bhhQ : bhhL;
    float*          emb  = g ? embQ : embL;

    // full packed Whh rows: 3 gates x 32 pairs = 96 VGPRs
    unsigned w0[32], w1[32], w2[32];
    {
        const unsigned* p0 = whp + (size_t)d * 32;
        const unsigned* p1 = whp + (size_t)(64 + d) * 32;
        const unsigned* p2 = whp + (size_t)(128 + d) * 32;
#pragma unroll
        for (int q4 = 0; q4 < 8; ++q4) {
            uint4 a = *(const uint4*)(p0 + 4 * q4);
            w0[4*q4] = a.x; w0[4*q4+1] = a.y; w0[4*q4+2] = a.z; w0[4*q4+3] = a.w;
            uint4 b = *(const uint4*)(p1 + 4 * q4);
            w1[4*q4] = b.x; w1[4*q4+1] = b.y; w1[4*q4+2] = b.z; w1[4*q4+3] = b.w;
            uint4 c = *(const uint4*)(p2 + 4 * q4);
            w2[4*q4] = c.x; w2[4*q4+1] = c.y; w2[4*q4+2] = c.z; w2[4*q4+3] = c.w;
        }
    }
    // packed cos-dot weights: 8 pairs per gate
    unsigned tp0[8], tp1[8], tp2[8];
#pragma unroll
    for (int q = 0; q < 8; ++q) {
        int t = 2 * q;
        tp0[q] = packrn(cst[(5 + t) * 192 + d],       cst[(6 + t) * 192 + d]);
        tp1[q] = packrn(cst[(5 + t) * 192 + 64 + d],  cst[(6 + t) * 192 + 64 + d]);
        tp2[q] = packrn(cst[(5 + t) * 192 + 128 + d], cst[(6 + t) * 192 + 128 + d]);
    }
    const float TE0 = cst[0*192 + d], TE1 = cst[0*192 + 64 + d], TE2 = cst[0*192 + 128 + d];
    const float TW0 = cst[1*192 + d], TW1 = cst[1*192 + 64 + d], TW2 = cst[1*192 + 128 + d];
    const float T10 = cst[2*192 + d], T11 = cst[2*192 + 64 + d], T12 = cst[2*192 + 128 + d];
    const float TB0 = cst[3*192 + d], TB1 = cst[3*192 + 64 + d], TB2 = cst[3*192 + 128 + d];
    const float CC0 = cst[4*192 + d] + bhh[d];
    const float CC1 = cst[4*192 + 64 + d] + bhh[64 + d];
    const float CC2 = cst[4*192 + 128 + d];
    const float BH2 = bhh[128 + d];

    const int cur = curp[s];
    const int csk = (int)node_raw[(size_t)cur * FF];
    const unsigned* ct_b = ctp + (size_t)blk * LHH * 8;
    const float* st_b = stats + (size_t)blk * LHH * 2;
    const int* nrow = nids + s * LHH;
    const int* erow = eids + s * LHH;

    float h = 0.f;

    auto LOADPOS = [&](Pos& P, int lpos) {
        int nid = nrow[lpos];
        int eid = erow[lpos];
        P.nid = nid;
        const float* tb = Tn + (size_t)nid * 192;
        P.tn0 = tb[d];
        P.tn1 = tb[64 + d];
        P.tn2 = tb[128 + d];
        P.e0 = edge_raw[(size_t)eid * 4];
        P.sk = node_raw[(size_t)nid * FF];
        P.st = *(const float2*)(st_b + 2 * lpos);
        const uint4* cp = (const uint4*)(ct_b + (size_t)lpos * 8);
        P.cv0 = cp[0];
        P.cv1 = cp[1];
    };

    auto COMPUTE = [&](const Pos& P) {
        // pack h pairs: lane 2k holds (h[2k], h[2k+1])
        float hx = __int_as_float(
            __builtin_amdgcn_mov_dpp(__float_as_int(h), 0xB1, 0xF, 0xF, true));
        unsigned hpu = pkrtz_u(h, hx);
        float a0=0,a1=0,a2=0, b0=0,b1=0,b2=0;
#pragma unroll
        for (int q = 0; q < 32; q += 2) {
            unsigned sa = rlu(hpu, 2 * q);
            unsigned sb = rlu(hpu, 2 * q + 2);
            a0 = fd2(w0[q], sa, a0);
            a1 = fd2(w1[q], sa, a1);
            a2 = fd2(w2[q], sa, a2);
            b0 = fd2(w0[q+1], sb, b0);
            b1 = fd2(w1[q+1], sb, b1);
            b2 = fd2(w2[q+1], sb, b2);
        }
        float mv0 = a0 + b0, mv1 = a1 + b1, mv2 = a2 + b2;

        unsigned cvu[8] = {P.cv0.x, P.cv0.y, P.cv0.z, P.cv0.w,
                           P.cv1.x, P.cv1.y, P.cv1.z, P.cv1.w};
        float c0 = 0.f, c1 = 0.f, c2 = 0.f;
#pragma unroll
        for (int q = 0; q < 8; ++q) {
            c0 = fd2(tp0[q], cvu[q], c0);
            c1 = fd2(tp1[q], cvu[q], c1);
            c2 = fd2(tp2[q], cvu[q], c2);
        }

        float mu = P.st.x, rs = P.st.y;
        float flg = ((P.nid == cur) ? 1.f : 0.f) + (((int)P.sk == csk) ? 1.f : 0.f);
        float pre0 = c0 + P.tn0 + P.e0 * TE0 + flg * TW0 + TB0 - mu * T10;
        float pre1 = c1 + P.tn1 + P.e0 * TE1 + flg * TW1 + TB1 - mu * T11;
        float pre2 = c2 + P.tn2 + P.e0 * TE2 + flg * TW2 + TB2 - mu * T12;

        float pr  = pre0 * rs + mv0 + CC0;
        float pz  = pre1 * rs + mv1 + CC1;
        float gin = pre2 * rs + CC2;
        float an  = mv2 + BH2;

        float r = sigm(pr);
        float z = sigm(pz);
        float n = tanh_f(gin + r * an);
        h = (1.f - z) * n + z * h;
    };

    Pos P0, P1, P2, P3;
    LOADPOS(P0, 0);
    LOADPOS(P1, 1);
    LOADPOS(P2, 2);

    for (int l = 0; l < LHH; l += 4) {
        int l3 = (l + 3 < LHH) ? l + 3 : LHH - 1;
        int l4 = (l + 4 < LHH) ? l + 4 : LHH - 1;
        int l5 = (l + 5 < LHH) ? l + 5 : LHH - 1;
        int l6 = (l + 6 < LHH) ? l + 6 : LHH - 1;
        LOADPOS(P3, l3);
        COMPUTE(P0);
        LOADPOS(P0, l4);
        COMPUTE(P1);
        LOADPOS(P1, l5);
        COMPUTE(P2);
        LOADPOS(P2, l6);
        COMPUTE(P3);
    }
    emb[(size_t)s * DD + d] = h;
}

// ---------------------------------------------------------------------------
// K3: graph_emb — hash-dedup'd GCNConv + mean pool. 512 thr (8 waves)/block.
// ---------------------------------------------------------------------------
__device__ __forceinline__ int hlookup(const unsigned* hkey, const int* hslot, unsigned id)
{
    unsigned p = (id * 2654435761u) & (GE_HASH - 1);
    while (hkey[p] != id) p = (p + 1) & (GE_HASH - 1);
    return hslot[p];
}

__global__ void __launch_bounds__(512)
graph_emb_kernel(const int* __restrict__ retrieved, const int* __restrict__ pool_nodes,
                 const float* __restrict__ hgcn, const float* __restrict__ gcn_b,
                 float* __restrict__ glob)
{
    __shared__ float agg[400 * 64];
    __shared__ unsigned hkey[GE_HASH];
    __shared__ int hslot[GE_HASH];
    __shared__ unsigned ekey[GE_HASH];
    __shared__ int slot_id[400];
    __shared__ unsigned deg[400];
    __shared__ float dis[400];
    __shared__ unsigned elist[400];
    __shared__ int ids[400];
    __shared__ int pids[8];
    __shared__ int cntU, cntE;
    __shared__ float gcnb_s[64];
    __shared__ float red[8][64];

    const int b = blockIdx.x;
    const int tid = threadIdx.x;
    const int lane = tid & 63, wid = tid >> 6;

    if (tid < 8)  pids[tid] = retrieved[b * 8 + tid];
    if (tid < 64) gcnb_s[tid] = gcn_b[tid];
    if (tid == 0) { cntU = 0; cntE = 0; }
    for (int i = tid; i < GE_HASH; i += 512) { hkey[i] = 0u; ekey[i] = 0u; }
    if (tid < 400) deg[tid] = 0u;
    __syncthreads();

    if (tid < 400) {
        int k = tid / 50, p = tid % 50;
        ids[tid] = pool_nodes[(size_t)pids[k] * 50 + p];
    }
    __syncthreads();

    if (tid < 400) {
        int idi = ids[tid];
        if (idi > 0) {
            unsigned id = (unsigned)idi;
            unsigned p = (id * 2654435761u) & (GE_HASH - 1);
            while (true) {
                unsigned old = atomicCAS(&hkey[p], 0u, id);
                if (old == 0u) {
                    int s = atomicAdd(&cntU, 1);
                    hslot[p] = s; slot_id[s] = idi;
                    break;
                }
                if (old == id) break;
                p = (p + 1) & (GE_HASH - 1);
            }
        }
    }
    __syncthreads();

    if (tid < 8 * 49) {
        int k = tid / 49, p = tid % 49;
        int u = ids[k * 50 + p], v = ids[k * 50 + p + 1];
        if (u > 0 && v > 0) {
            unsigned a = (unsigned)min(u, v), bb = (unsigned)max(u, v);
            unsigned key = a * 40000u + bb;
            unsigned p2 = (key * 2654435761u) & (GE_HASH - 1);
            while (true) {
                unsigned old = atomicCAS(&ekey[p2], 0u, key);
                if (old == 0u) {
                    int su = hlookup(hkey, hslot, a);
                    int sv = hlookup(hkey, hslot, bb);
                    int e = atomicAdd(&cntE, 1);
                    elist[e] = ((unsigned)su << 16) | (unsigned)sv;
                    atomicAdd(&deg[su], 1u);
                    atomicAdd(&deg[sv], 1u);
                    break;
                }
                if (old == key) break;
                p2 = (p2 + 1) & (GE_HASH - 1);
            }
        }
    }
    __syncthreads();

    const int U = cntU, EC = cntE;
    if (tid < U) dis[tid] = rsqrtf((float)deg[tid] + 1.0f);
    __syncthreads();

    for (int s = wid; s < U; s += 8) {
        float d2 = dis[s] * dis[s];
        float hval = hgcn[(size_t)slot_id[s] * 64 + lane];
        agg[s * 64 + lane] = gcnb_s[lane] + d2 * hval;
    }
    __syncthreads();

    for (int e = wid; e < EC; e += 8) {
        unsigned pk = elist[e];
        int su = (int)(pk >> 16), sv = (int)(pk & 0xffffu);
        float nrm = dis[su] * dis[sv];
        float hu = hgcn[(size_t)slot_id[su] * 64 + lane];
        float hv = hgcn[(size_t)slot_id[sv] * 64 + lane];
        atomicAdd(&agg[sv * 64 + lane], nrm * hu);
        atomicAdd(&agg[su * 64 + lane], nrm * hv);
    }
    __syncthreads();

    float acc = 0.f;
    for (int s = wid; s < U; s += 8) acc += fmaxf(agg[s * 64 + lane], 0.f);
    red[wid][lane] = acc;
    __syncthreads();
    if (tid < 64) {
        float tot = 0.f;
#pragma unroll
        for (int q = 0; q < 8; ++q) tot += red[q][tid];
        glob[(size_t)b * 64 + tid] = tot / (float)max(U, 1);
    }
}

// ---------------------------------------------------------------------------
// K4: fusion + output heads.
// ---------------------------------------------------------------------------
__global__ void __launch_bounds__(64)
head_kernel(const float* __restrict__ local_emb, const float* __restrict__ glob,
            const float* __restrict__ q_emb,
            const float* __restrict__ fus_W, const float* __restrict__ fus_b,
            const float* __restrict__ out_W, const float* __restrict__ out_b,
            float* __restrict__ out)
{
    __shared__ float cat[128];
    __shared__ float fus[64];
    __shared__ float qv[64];
    const int b = blockIdx.x, d = threadIdx.x;
    cat[d]      = local_emb[(size_t)b * 64 + d];
    cat[64 + d] = glob[(size_t)b * 64 + d];
    qv[d]       = q_emb[(size_t)b * 64 + d];
    __syncthreads();
    float acc = fus_b[d];
    const float* fw = fus_W + (size_t)d * 128;
#pragma unroll 4
    for (int k = 0; k < 128; ++k) acc += cat[k] * fw[k];
    fus[d] = fmaxf(acc, 0.f);
    __syncthreads();
    float o0 = out_b[d], o1 = out_b[d];
    const float* ow = out_W + (size_t)d * 64;
#pragma unroll 4
    for (int k = 0; k < 64; ++k) { float ww = ow[k]; o0 += fus[k] * ww; o1 += qv[k] * ww; }
    out[(size_t)b * 64 + d] = o0;
    out[(size_t)BB * 64 + (size_t)b * 64 + d] = o1;
}

// ---------------------------------------------------------------------------
extern "C" void kernel_launch(void* const* d_in, const int* in_sizes, int n_in,
                              void* d_out, int out_size, void* d_ws, size_t ws_size,
                              hipStream_t stream)
{
    const int*   src_ids    = (const int*)d_in[0];
    const int*   dst_ids    = (const int*)d_in[1];
    const int*   l_nids     = (const int*)d_in[2];
    const int*   l_eids     = (const int*)d_in[3];
    const float* l_times    = (const float*)d_in[4];
    const int*   d_nids     = (const int*)d_in[5];
    const int*   d_eids     = (const int*)d_in[6];
    const float* d_times    = (const float*)d_in[7];
    const int*   retr       = (const int*)d_in[8];
    const float* node_raw   = (const float*)d_in[9];
    const float* edge_raw   = (const float*)d_in[10];
    const int*   pool_nodes = (const int*)d_in[11];
    const float* Wfeat  = (const float*)d_in[12];
    const float* bfeat  = (const float*)d_in[13];
    const float* Wedge  = (const float*)d_in[14];
    const float* bedge  = (const float*)d_in[15];
    const float* Wtime  = (const float*)d_in[16];
    const float* btime  = (const float*)d_in[17];
    const float* Wstruct= (const float*)d_in[18];
    const float* bstruct= (const float*)d_in[19];
    const float* ln_g   = (const float*)d_in[20];
    const float* ln_b   = (const float*)d_in[21];
    const float* gruL_Wih = (const float*)d_in[22];
    const float* gruL_Whh = (const float*)d_in[23];
    const float* gruL_bih = (const float*)d_in[24];
    const float* gruL_bhh = (const float*)d_in[25];
    const float* gruQ_Wih = (const float*)d_in[26];
    const float* gruQ_Whh = (const float*)d_in[27];
    const float* gruQ_bih = (const float*)d_in[28];
    const float* gruQ_bhh = (const float*)d_in[29];
    const float* gcn_W  = (const float*)d_in[30];
    const float* gcn_b  = (const float*)d_in[31];
    const float* fus_W  = (const float*)d_in[32];
    const float* fus_b  = (const float*)d_in[33];
    const float* out_W  = (const float*)d_in[34];
    const float* out_b  = (const float*)d_in[35];

    float* ws = (float*)d_ws;
    float* proj_node = ws;                              ws += (size_t)NN * DD;
    float* hgcn      = ws;                              ws += (size_t)NN * DD;
    float* TnL       = ws;                              ws += (size_t)NN * 192;
    float* TnQ       = ws;                              ws += (size_t)NN * 192;
    float* cstL      = ws;                              ws += 4096;
    float* cstQ      = ws;                              ws += 4096;
    unsigned* whpL   = (unsigned*)ws;                   ws += 192 * 32;
    unsigned* whpQ   = (unsigned*)ws;                   ws += 192 * 32;
    unsigned* ctp    = (unsigned*)ws;                   ws += (size_t)2 * BB * LHH * 8;
    float* stats     = ws;                              ws += (size_t)2 * BB * LHH * 2;
    float* local_emb = ws;                              ws += (size_t)BB * DD;
    float* q_emb     = ws;                              ws += (size_t)BB * DD;
    float* glob      = ws;                              ws += (size_t)BB * DD;

    dim3 g1((NN + 127) / 128);
    gemm_nt_kernel<FF><<<g1, 256, 0, stream>>>(node_raw, Wfeat, bfeat, proj_node, NN);

    consts_kernel<<<2, 192, 0, stream>>>(gruL_Wih, gruL_bih, gruL_Whh, cstL, whpL,
                                         gruQ_Wih, gruQ_bih, gruQ_Whh, cstQ, whpQ,
                                         ln_g, ln_b, Wedge, bedge, Wtime, btime,
                                         Wstruct, bstruct);

    gemm_nt_kernel<DD><<<g1, 256, 0, stream>>>(proj_node, gcn_W, nullptr, hgcn, NN);

    tn_gemm_kernel<<<dim3(NN / 64, 2), 256, 0, stream>>>(proj_node, gruL_Wih, gruQ_Wih,
                                                         ln_g, TnL, TnQ);

    stats_kernel<<<2 * BB, 256, 0, stream>>>(l_nids, l_eids, l_times, dst_ids,
        d_nids, d_eids, d_times, src_ids,
        node_raw, edge_raw, proj_node, Wedge, bedge, Wtime, btime, Wstruct, bstruct,
        ctp, stats);

    gru1_kernel<<<2 * BB, 64, 0, stream>>>(
        l_nids, l_eids, dst_ids, d_nids, d_eids, src_ids,
        node_raw, edge_raw, TnL, TnQ, cstL, cstQ, whpL, whpQ, ctp, stats,
        gruL_bhh, gruQ_bhh, local_emb, q_emb);

    graph_emb_kernel<<<BB, 512, 0, stream>>>(retr, pool_nodes, hgcn, gcn_b, glob);

    head_kernel<<<BB, 64, 0, stream>>>(local_emb, glob, q_emb,
        fus_W, fus_b, out_W, out_b, (float*)d_out);
}

// Round 7
// 453.465 us; speedup vs baseline: 1.6522x; 1.1247x over previous
//
#include <hip/hip_runtime.h>
#include <math.h>

#define NN 40000
#define FF 256
#define DD 64
#define LHH 200
#define BB 512
#define TDD 16
#define GE_HASH 1024

typedef _Float16 h2f __attribute__((ext_vector_type(2)));

__constant__ float TFREQ[16] = {
    1.0f,            0.48696753f,    0.23713737f,    0.115478195f,
    0.056234132f,    0.027384196f,   0.013335215f,   0.0064938162f,
    0.0031622776f,   0.0015399265f,  0.00074989421f, 0.00036517414f,
    0.00017782794f,  8.6596433e-05f, 4.2169650e-05f, 2.0535251e-05f
};

__device__ __forceinline__ float fd2(unsigned a, unsigned b, float c) {
    union { unsigned u; h2f h; } ua, ub;
    ua.u = a; ub.u = b;
    return __builtin_amdgcn_fdot2(ua.h, ub.h, c, false);
}
__device__ __forceinline__ unsigned packrn(float a, float b) {
    union { h2f h; unsigned u; } x;
    x.h.x = (_Float16)a; x.h.y = (_Float16)b;
    return x.u;
}
__device__ __forceinline__ unsigned pkrtz_u(float a, float b) {
    auto pk = __builtin_amdgcn_cvt_pkrtz(a, b);
    union { decltype(pk) h; unsigned u; } x;
    x.h = pk;
    return x.u;
}
__device__ __forceinline__ float dpp_xor1(float v) {
    return __int_as_float(
        __builtin_amdgcn_mov_dpp(__float_as_int(v), 0xB1, 0xF, 0xF, true));
}
__device__ __forceinline__ unsigned rlu(unsigned v, int l) {
    return (unsigned)__builtin_amdgcn_readlane((int)v, l);
}
__device__ __forceinline__ float sigm(float x) {
    return __builtin_amdgcn_rcpf(1.f + __expf(-x));
}
__device__ __forceinline__ float tanh_f(float x) {
    float e = __expf(2.f * x);
    return 1.f - 2.f * __builtin_amdgcn_rcpf(e + 1.f);
}

// ---------------------------------------------------------------------------
// K1: C[n][0:64] = A[n][:] @ W[64][KDIM]^T + bias
// ---------------------------------------------------------------------------
template<int KDIM>
__global__ void __launch_bounds__(256)
gemm_nt_kernel(const float* __restrict__ A, const float* __restrict__ W,
               const float* __restrict__ bias, float* __restrict__ C, int Nrows)
{
    __shared__ __align__(16) float a_t[128][8];
    __shared__ __align__(16) float wt[8][64];
    const int tid = threadIdx.x;
    const int tx = tid & 15;
    const int ty = tid >> 4;
    const int n0 = blockIdx.x * 128;

    float4 acc[8];
#pragma unroll
    for (int r = 0; r < 8; ++r) acc[r] = make_float4(0.f, 0.f, 0.f, 0.f);

    for (int kc = 0; kc < KDIM; kc += 8) {
        __syncthreads();
        {
            int r = tid >> 1;
            int cc = (tid & 1) * 4;
            int n = n0 + r;
            float4 v = make_float4(0.f, 0.f, 0.f, 0.f);
            if (n < Nrows) v = *(const float4*)(A + (size_t)n * KDIM + kc + cc);
            *(float4*)&a_t[r][cc] = v;
        }
        {
            int m = tid >> 2;
            int f0 = (tid & 3) * 2;
            float2 v = *(const float2*)(W + (size_t)m * KDIM + kc + f0);
            wt[f0][m] = v.x; wt[f0 + 1][m] = v.y;
        }
        __syncthreads();
        float4 w4[8];
#pragma unroll
        for (int f = 0; f < 8; ++f) w4[f] = *(float4*)&wt[f][tx * 4];
#pragma unroll
        for (int rr = 0; rr < 8; ++rr) {
            int row = ty + rr * 16;
            float4 a0 = *(float4*)&a_t[row][0];
            float4 a1 = *(float4*)&a_t[row][4];
            float av[8] = {a0.x, a0.y, a0.z, a0.w, a1.x, a1.y, a1.z, a1.w};
#pragma unroll
            for (int f = 0; f < 8; ++f) {
                acc[rr].x += av[f] * w4[f].x;
                acc[rr].y += av[f] * w4[f].y;
                acc[rr].z += av[f] * w4[f].z;
                acc[rr].w += av[f] * w4[f].w;
            }
        }
    }
    float4 bv = make_float4(0.f, 0.f, 0.f, 0.f);
    if (bias) bv = *(const float4*)(bias + tx * 4);
#pragma unroll
    for (int rr = 0; rr < 8; ++rr) {
        int n = n0 + ty + rr * 16;
        if (n < Nrows) {
            float4 o = acc[rr];
            o.x += bv.x; o.y += bv.y; o.z += bv.z; o.w += bv.w;
            *(float4*)(C + (size_t)n * DD + tx * 4) = o;
        }
    }
}

// ---------------------------------------------------------------------------
// Tn[n][j] = sum_k proj[n][k] * Wih[j][k] * ln_g[k]; grid.y selects L/Q.
// ---------------------------------------------------------------------------
__global__ void __launch_bounds__(256)
tn_gemm_kernel(const float* __restrict__ proj,
               const float* __restrict__ WihL, const float* __restrict__ WihQ,
               const float* __restrict__ ln_g,
               float* __restrict__ TnL, float* __restrict__ TnQ)
{
    const float* Wih = blockIdx.y ? WihQ : WihL;
    float* Tn = blockIdx.y ? TnQ : TnL;
    __shared__ float wgT[64][193];
    __shared__ __align__(16) float4 at4[64][16];
    const int tid = threadIdx.x;
    const int n0 = blockIdx.x * 64;
    for (int i = tid; i < 192 * 64; i += 256) {
        int j = i >> 6, k = i & 63;
        wgT[k][j] = Wih[i] * ln_g[k];
    }
    for (int i = tid; i < 1024; i += 256) {
        int r = i >> 4, kc = i & 15;
        at4[r][kc] = ((const float4*)(proj + (size_t)(n0 + r) * DD))[kc];
    }
    __syncthreads();
    const int c = tid & 63, wv = tid >> 6;
    float acc0[16], acc1[16], acc2[16];
#pragma unroll
    for (int r = 0; r < 16; ++r) { acc0[r] = 0.f; acc1[r] = 0.f; acc2[r] = 0.f; }
    for (int kc = 0; kc < 16; ++kc) {
        float w0[4], w1[4], w2[4];
#pragma unroll
        for (int q = 0; q < 4; ++q) {
            w0[q] = wgT[kc * 4 + q][c];
            w1[q] = wgT[kc * 4 + q][64 + c];
            w2[q] = wgT[kc * 4 + q][128 + c];
        }
#pragma unroll
        for (int r = 0; r < 16; ++r) {
            float4 a = at4[wv * 16 + r][kc];
            acc0[r] += a.x * w0[0] + a.y * w0[1] + a.z * w0[2] + a.w * w0[3];
            acc1[r] += a.x * w1[0] + a.y * w1[1] + a.z * w1[2] + a.w * w1[3];
            acc2[r] += a.x * w2[0] + a.y * w2[1] + a.z * w2[2] + a.w * w2[3];
        }
    }
#pragma unroll
    for (int r = 0; r < 16; ++r) {
        size_t row = (size_t)(n0 + wv * 16 + r) * 192;
        Tn[row + c]       = acc0[r];
        Tn[row + 64 + c]  = acc1[r];
        Tn[row + 128 + c] = acc2[r];
    }
}

// ---------------------------------------------------------------------------
// Per-gate-row constants out[21][192] + f16-packed Whh (whp[192][32] u32).
// ---------------------------------------------------------------------------
__global__ void __launch_bounds__(192)
consts_kernel(const float* __restrict__ WihL, const float* __restrict__ bihL,
              const float* __restrict__ WhhL, float* __restrict__ outL, unsigned* __restrict__ whpL,
              const float* __restrict__ WihQ, const float* __restrict__ bihQ,
              const float* __restrict__ WhhQ, float* __restrict__ outQ, unsigned* __restrict__ whpQ,
              const float* __restrict__ ln_g, const float* __restrict__ ln_b,
              const float* __restrict__ Wedge, const float* __restrict__ bedge,
              const float* __restrict__ Wtime, const float* __restrict__ btime,
              const float* __restrict__ Wstruct, const float* __restrict__ bstruct)
{
    const float* Wih = blockIdx.x ? WihQ : WihL;
    const float* bih = blockIdx.x ? bihQ : bihL;
    const float* Whh = blockIdx.x ? WhhQ : WhhL;
    float* out = blockIdx.x ? outQ : outL;
    unsigned* whp = blockIdx.x ? whpQ : whpL;
    const int j = threadIdx.x;
    float te = 0.f, tw = 0.f, t1 = 0.f, tb0 = 0.f, cc = 0.f;
    float tt[16];
#pragma unroll
    for (int t = 0; t < 16; ++t) tt[t] = 0.f;
    for (int k = 0; k < DD; ++k) {
        float wv = Wih[j * DD + k];
        float wg = wv * ln_g[k];
        te  += wg * Wedge[k];
        tw  += wg * Wstruct[k];
        t1  += wg;
        tb0 += wg * (bedge[k] + btime[k] + 2.f * bstruct[k]);
        cc  += wv * ln_b[k];
#pragma unroll
        for (int t = 0; t < 16; ++t) tt[t] += wg * Wtime[k * TDD + t];
    }
    out[0 * 192 + j] = te;
    out[1 * 192 + j] = tw;
    out[2 * 192 + j] = t1;
    out[3 * 192 + j] = tb0;
    out[4 * 192 + j] = cc + bih[j];
    for (int t = 0; t < 16; ++t) out[(5 + t) * 192 + j] = tt[t];
    for (int k2 = 0; k2 < 32; ++k2)
        whp[j * 32 + k2] = packrn(Whh[j * DD + 2 * k2], Whh[j * DD + 2 * k2 + 1]);
}

// ---------------------------------------------------------------------------
// GRU: ONE wave per sequence; weights pinned in VGPRs; 3-stage static
// pipeline (idx +10, gather +6, prep +2, compute). LN stats computed inline
// (stats kernel eliminated). No LDS, no barriers.
// ---------------------------------------------------------------------------
struct GS {
    int nid;
    float tn0, tn1, tn2, pv, e0, sk, t;
};

__global__ void __launch_bounds__(64, 1) __attribute__((amdgpu_waves_per_eu(1)))
gru1_kernel(const int* __restrict__ nidsL, const int* __restrict__ eidsL,
            const float* __restrict__ timesL, const int* __restrict__ curL,
            const int* __restrict__ nidsQ, const int* __restrict__ eidsQ,
            const float* __restrict__ timesQ, const int* __restrict__ curQ,
            const float* __restrict__ node_raw, const float* __restrict__ edge_raw,
            const float* __restrict__ proj_node,
            const float* __restrict__ TnL, const float* __restrict__ TnQ,
            const float* __restrict__ cstL, const float* __restrict__ cstQ,
            const unsigned* __restrict__ whpL, const unsigned* __restrict__ whpQ,
            const float* __restrict__ bhhL, const float* __restrict__ bhhQ,
            const float* __restrict__ Wedge, const float* __restrict__ bedge,
            const float* __restrict__ Wtime, const float* __restrict__ btime,
            const float* __restrict__ Wstruct, const float* __restrict__ bstruct,
            float* __restrict__ embL, float* __restrict__ embQ)
{
    const int blk = blockIdx.x;
    const int g = blk >> 9, s = blk & 511;
    const int d = threadIdx.x;

    const int*      nids  = g ? nidsQ : nidsL;
    const int*      eids  = g ? eidsQ : eidsL;
    const float*    times = g ? timesQ : timesL;
    const int*      curp  = g ? curQ : curL;
    const float*    Tn    = g ? TnQ : TnL;
    const float*    cst   = g ? cstQ : cstL;
    const unsigned* whp   = g ? whpQ : whpL;
    const float*    bhh   = g ? bhhQ : bhhL;
    float*          emb   = g ? embQ : embL;

    // ---- packed Whh rows: 96 u32, pinned in VGPRs
    unsigned w0[32], w1[32], w2[32];
    {
        const unsigned* p0 = whp + (size_t)d * 32;
        const unsigned* p1 = whp + (size_t)(64 + d) * 32;
        const unsigned* p2 = whp + (size_t)(128 + d) * 32;
#pragma unroll
        for (int q4 = 0; q4 < 8; ++q4) {
            uint4 a = *(const uint4*)(p0 + 4 * q4);
            w0[4*q4] = a.x; w0[4*q4+1] = a.y; w0[4*q4+2] = a.z; w0[4*q4+3] = a.w;
            uint4 b = *(const uint4*)(p1 + 4 * q4);
            w1[4*q4] = b.x; w1[4*q4+1] = b.y; w1[4*q4+2] = b.z; w1[4*q4+3] = b.w;
            uint4 c = *(const uint4*)(p2 + 4 * q4);
            w2[4*q4] = c.x; w2[4*q4+1] = c.y; w2[4*q4+2] = c.z; w2[4*q4+3] = c.w;
        }
    }
#pragma unroll
    for (int i = 0; i < 32; ++i) {
        asm volatile("" : "+v"(w0[i]));
        asm volatile("" : "+v"(w1[i]));
        asm volatile("" : "+v"(w2[i]));
    }
    // packed cos-dot weights (8 pairs per gate) and time-row weights
    unsigned tp0[8], tp1[8], tp2[8], wtp[8];
#pragma unroll
    for (int q = 0; q < 8; ++q) {
        int t = 2 * q;
        tp0[q] = packrn(cst[(5 + t) * 192 + d],       cst[(6 + t) * 192 + d]);
        tp1[q] = packrn(cst[(5 + t) * 192 + 64 + d],  cst[(6 + t) * 192 + 64 + d]);
        tp2[q] = packrn(cst[(5 + t) * 192 + 128 + d], cst[(6 + t) * 192 + 128 + d]);
        wtp[q] = packrn(Wtime[d * TDD + t], Wtime[d * TDD + t + 1]);
    }
#pragma unroll
    for (int i = 0; i < 8; ++i) {
        asm volatile("" : "+v"(tp0[i]));
        asm volatile("" : "+v"(tp1[i]));
        asm volatile("" : "+v"(tp2[i]));
        asm volatile("" : "+v"(wtp[i]));
    }
    const float TE0 = cst[0*192 + d], TE1 = cst[0*192 + 64 + d], TE2 = cst[0*192 + 128 + d];
    const float TW0 = cst[1*192 + d], TW1 = cst[1*192 + 64 + d], TW2 = cst[1*192 + 128 + d];
    const float T10 = cst[2*192 + d], T11 = cst[2*192 + 64 + d], T12 = cst[2*192 + 128 + d];
    const float TB0 = cst[3*192 + d], TB1 = cst[3*192 + 64 + d], TB2 = cst[3*192 + 128 + d];
    const float CC0 = cst[4*192 + d] + bhh[d];
    const float CC1 = cst[4*192 + 64 + d] + bhh[64 + d];
    const float CC2 = cst[4*192 + 128 + d];
    const float BH2 = bhh[128 + d];
    const float we_l = Wedge[d];
    const float ws_l = Wstruct[d];
    const float b0_l = bedge[d] + btime[d] + 2.f * bstruct[d];
    const float tfl  = TFREQ[d & 15];

    const int cur = curp[s];
    const int csk = (int)node_raw[(size_t)cur * FF];
    const int* nrow = nids + s * LHH;
    const int* erow = eids + s * LHH;
    const float* trow = times + s * LHH;

    float h = 0.f;

    auto GATH = [&](GS& G, int nid, int eid, int lpos) {
        G.nid = nid;
        const float* tb = Tn + (size_t)nid * 192;
        G.tn0 = tb[d];
        G.tn1 = tb[64 + d];
        G.tn2 = tb[128 + d];
        G.pv  = proj_node[(size_t)nid * DD + d];
        G.e0  = edge_raw[(size_t)eid * 4];
        G.sk  = node_raw[(size_t)nid * FF];
        G.t   = trow[lpos];
    };

    auto PREP = [&](const GS& G, float& g0, float& g1, float& g2) {
        // cos features in-register: lane j computes cos(t * freq[j&15])
        float cv = __cosf(G.t * tfl);
        float cx = dpp_xor1(cv);
        unsigned cp = pkrtz_u(cv, cx);
        unsigned s0 = rlu(cp, 0),  s1 = rlu(cp, 2),  s2 = rlu(cp, 4),  s3 = rlu(cp, 6);
        unsigned s4 = rlu(cp, 8),  s5 = rlu(cp, 10), s6 = rlu(cp, 12), s7 = rlu(cp, 14);
        // tf[d] = sum_j cos_j * Wtime[d][j]
        float tf = fd2(wtp[7], s7, fd2(wtp[6], s6, fd2(wtp[5], s5, fd2(wtp[4], s4, 0.f))));
        tf = fd2(wtp[3], s3, fd2(wtp[2], s2, fd2(wtp[1], s1, fd2(wtp[0], s0, tf))));
        float flg = ((G.nid == cur) ? 1.f : 0.f) + (((int)G.sk == csk) ? 1.f : 0.f);
        float f = G.pv + G.e0 * we_l + flg * ws_l + b0_l + tf;
        // wave LayerNorm stats
        float mu = f;
#pragma unroll
        for (int off = 32; off; off >>= 1) mu += __shfl_xor(mu, off);
        mu *= (1.f / 64.f);
        float dv = f - mu, var = dv * dv;
#pragma unroll
        for (int off = 32; off; off >>= 1) var += __shfl_xor(var, off);
        float rs = rsqrtf(var * (1.f / 64.f) + 1e-5f);
        // c = Wg @ time-feature part, per gate
        float c0 = fd2(tp0[7], s7, fd2(tp0[6], s6, fd2(tp0[5], s5, fd2(tp0[4], s4, 0.f))));
        c0 = fd2(tp0[3], s3, fd2(tp0[2], s2, fd2(tp0[1], s1, fd2(tp0[0], s0, c0))));
        float c1 = fd2(tp1[7], s7, fd2(tp1[6], s6, fd2(tp1[5], s5, fd2(tp1[4], s4, 0.f))));
        c1 = fd2(tp1[3], s3, fd2(tp1[2], s2, fd2(tp1[1], s1, fd2(tp1[0], s0, c1))));
        float c2 = fd2(tp2[7], s7, fd2(tp2[6], s6, fd2(tp2[5], s5, fd2(tp2[4], s4, 0.f))));
        c2 = fd2(tp2[3], s3, fd2(tp2[2], s2, fd2(tp2[1], s1, fd2(tp2[0], s0, c2))));
        g0 = (c0 + G.tn0 + G.e0 * TE0 + flg * TW0 + TB0 - mu * T10) * rs + CC0;
        g1 = (c1 + G.tn1 + G.e0 * TE1 + flg * TW1 + TB1 - mu * T11) * rs + CC1;
        g2 = (c2 + G.tn2 + G.e0 * TE2 + flg * TW2 + TB2 - mu * T12) * rs + CC2;
    };

    auto COMPUTE = [&](float g0, float g1, float g2) {
        float hx = dpp_xor1(h);
        unsigned hpu = pkrtz_u(h, hx);
        float a0 = 0.f, a1 = 0.f, a2 = 0.f, e0 = 0.f, e1 = 0.f, e2 = 0.f;
#pragma unroll
        for (int q = 0; q < 32; q += 2) {
            unsigned sa = rlu(hpu, 2 * q);
            unsigned sb = rlu(hpu, 2 * q + 2);
            a0 = fd2(w0[q], sa, a0);
            a1 = fd2(w1[q], sa, a1);
            a2 = fd2(w2[q], sa, a2);
            e0 = fd2(w0[q+1], sb, e0);
            e1 = fd2(w1[q+1], sb, e1);
            e2 = fd2(w2[q+1], sb, e2);
        }
        float mv0 = a0 + e0, mv1 = a1 + e1, mv2 = a2 + e2;
        float r = sigm(g0 + mv0);
        float z = sigm(g1 + mv1);
        float n = tanh_f(g2 + r * (mv2 + BH2));
        h = (1.f - z) * n + z * h;
    };

    // ---- prologue
    int in0, in1, in2, in3, ie0, ie1, ie2, ie3;
    GS G0, G1, G2, G3;
    float gA0, gA1, gA2, gB0, gB1, gB2;
    {
        int pn[10], pe[10];
#pragma unroll
        for (int i = 0; i < 10; ++i) { pn[i] = nrow[i]; pe[i] = erow[i]; }
        GS Gp0, Gp1;
        GATH(Gp0, pn[0], pe[0], 0);
        GATH(Gp1, pn[1], pe[1], 1);
        GATH(G0, pn[2], pe[2], 2);
        GATH(G1, pn[3], pe[3], 3);
        GATH(G2, pn[4], pe[4], 4);
        GATH(G3, pn[5], pe[5], 5);
        in0 = pn[6]; in1 = pn[7]; in2 = pn[8]; in3 = pn[9];
        ie0 = pe[6]; ie1 = pe[7]; ie2 = pe[8]; ie3 = pe[9];
        PREP(Gp0, gA0, gA1, gA2);
        PREP(Gp1, gB0, gB1, gB2);
    }

    // ---- main loop: 4 steps / iteration
    for (int l = 0; l < LHH; l += 4) {
        // idx loads for l+10..l+13
        int i10 = (l + 10 < LHH) ? l + 10 : LHH - 1;
        int i11 = (l + 11 < LHH) ? l + 11 : LHH - 1;
        int i12 = (l + 12 < LHH) ? l + 12 : LHH - 1;
        int i13 = (l + 13 < LHH) ? l + 13 : LHH - 1;
        int nn0 = nrow[i10], nn1 = nrow[i11], nn2 = nrow[i12], nn3 = nrow[i13];
        int ne0 = erow[i10], ne1 = erow[i11], ne2 = erow[i12], ne3 = erow[i13];
        // gathers for l+6..l+9 (idx arrived last iteration)
        int p6 = (l + 6 < LHH) ? l + 6 : LHH - 1;
        int p7 = (l + 7 < LHH) ? l + 7 : LHH - 1;
        int p8 = (l + 8 < LHH) ? l + 8 : LHH - 1;
        int p9 = (l + 9 < LHH) ? l + 9 : LHH - 1;
        GS N0, N1, N2, N3;
        GATH(N0, in0, ie0, p6);
        GATH(N1, in1, ie1, p7);
        GATH(N2, in2, ie2, p8);
        GATH(N3, in3, ie3, p9);
        // prep l+2..l+5 (gathers arrived last iteration)
        float gC0, gC1, gC2, gD0, gD1, gD2, gE0, gE1, gE2, gF0, gF1, gF2;
        PREP(G0, gC0, gC1, gC2);
        PREP(G1, gD0, gD1, gD2);
        PREP(G2, gE0, gE1, gE2);
        PREP(G3, gF0, gF1, gF2);
        // compute l..l+3
        COMPUTE(gA0, gA1, gA2);
        COMPUTE(gB0, gB1, gB2);
        COMPUTE(gC0, gC1, gC2);
        COMPUTE(gD0, gD1, gD2);
        // rotate
        gA0 = gE0; gA1 = gE1; gA2 = gE2;
        gB0 = gF0; gB1 = gF1; gB2 = gF2;
        G0 = N0; G1 = N1; G2 = N2; G3 = N3;
        in0 = nn0; in1 = nn1; in2 = nn2; in3 = nn3;
        ie0 = ne0; ie1 = ne1; ie2 = ne2; ie3 = ne3;
    }
    emb[(size_t)s * DD + d] = h;
}

// ---------------------------------------------------------------------------
// K3: graph_emb — hash-dedup'd GCNConv + mean pool. 512 thr (8 waves)/block.
// ---------------------------------------------------------------------------
__device__ __forceinline__ int hlookup(const unsigned* hkey, const int* hslot, unsigned id)
{
    unsigned p = (id * 2654435761u) & (GE_HASH - 1);
    while (hkey[p] != id) p = (p + 1) & (GE_HASH - 1);
    return hslot[p];
}

__global__ void __launch_bounds__(512)
graph_emb_kernel(const int* __restrict__ retrieved, const int* __restrict__ pool_nodes,
                 const float* __restrict__ hgcn, const float* __restrict__ gcn_b,
                 float* __restrict__ glob)
{
    __shared__ float agg[400 * 64];
    __shared__ unsigned hkey[GE_HASH];
    __shared__ int hslot[GE_HASH];
    __shared__ unsigned ekey[GE_HASH];
    __shared__ int slot_id[400];
    __shared__ unsigned deg[400];
    __shared__ float dis[400];
    __shared__ unsigned elist[400];
    __shared__ int ids[400];
    __shared__ int pids[8];
    __shared__ int cntU, cntE;
    __shared__ float gcnb_s[64];
    __shared__ float red[8][64];

    const int b = blockIdx.x;
    const int tid = threadIdx.x;
    const int lane = tid & 63, wid = tid >> 6;

    if (tid < 8)  pids[tid] = retrieved[b * 8 + tid];
    if (tid < 64) gcnb_s[tid] = gcn_b[tid];
    if (tid == 0) { cntU = 0; cntE = 0; }
    for (int i = tid; i < GE_HASH; i += 512) { hkey[i] = 0u; ekey[i] = 0u; }
    if (tid < 400) deg[tid] = 0u;
    __syncthreads();

    if (tid < 400) {
        int k = tid / 50, p = tid % 50;
        ids[tid] = pool_nodes[(size_t)pids[k] * 50 + p];
    }
    __syncthreads();

    if (tid < 400) {
        int idi = ids[tid];
        if (idi > 0) {
            unsigned id = (unsigned)idi;
            unsigned p = (id * 2654435761u) & (GE_HASH - 1);
            while (true) {
                unsigned old = atomicCAS(&hkey[p], 0u, id);
                if (old == 0u) {
                    int s = atomicAdd(&cntU, 1);
                    hslot[p] = s; slot_id[s] = idi;
                    break;
                }
                if (old == id) break;
                p = (p + 1) & (GE_HASH - 1);
            }
        }
    }
    __syncthreads();

    if (tid < 8 * 49) {
        int k = tid / 49, p = tid % 49;
        int u = ids[k * 50 + p], v = ids[k * 50 + p + 1];
        if (u > 0 && v > 0) {
            unsigned a = (unsigned)min(u, v), bb = (unsigned)max(u, v);
            unsigned key = a * 40000u + bb;
            unsigned p2 = (key * 2654435761u) & (GE_HASH - 1);
            while (true) {
                unsigned old = atomicCAS(&ekey[p2], 0u, key);
                if (old == 0u) {
                    int su = hlookup(hkey, hslot, a);
                    int sv = hlookup(hkey, hslot, bb);
                    int e = atomicAdd(&cntE, 1);
                    elist[e] = ((unsigned)su << 16) | (unsigned)sv;
                    atomicAdd(&deg[su], 1u);
                    atomicAdd(&deg[sv], 1u);
                    break;
                }
                if (old == key) break;
                p2 = (p2 + 1) & (GE_HASH - 1);
            }
        }
    }
    __syncthreads();

    const int U = cntU, EC = cntE;
    if (tid < U) dis[tid] = rsqrtf((float)deg[tid] + 1.0f);
    __syncthreads();

    for (int s = wid; s < U; s += 8) {
        float d2 = dis[s] * dis[s];
        float hval = hgcn[(size_t)slot_id[s] * 64 + lane];
        agg[s * 64 + lane] = gcnb_s[lane] + d2 * hval;
    }
    __syncthreads();

    for (int e = wid; e < EC; e += 8) {
        unsigned pk = elist[e];
        int su = (int)(pk >> 16), sv = (int)(pk & 0xffffu);
        float nrm = dis[su] * dis[sv];
        float hu = hgcn[(size_t)slot_id[su] * 64 + lane];
        float hv = hgcn[(size_t)slot_id[sv] * 64 + lane];
        atomicAdd(&agg[sv * 64 + lane], nrm * hu);
        atomicAdd(&agg[su * 64 + lane], nrm * hv);
    }
    __syncthreads();

    float acc = 0.f;
    for (int s = wid; s < U; s += 8) acc += fmaxf(agg[s * 64 + lane], 0.f);
    red[wid][lane] = acc;
    __syncthreads();
    if (tid < 64) {
        float tot = 0.f;
#pragma unroll
        for (int q = 0; q < 8; ++q) tot += red[q][tid];
        glob[(size_t)b * 64 + tid] = tot / (float)max(U, 1);
    }
}

// ---------------------------------------------------------------------------
// K4: fusion + output heads.
// ---------------------------------------------------------------------------
__global__ void __launch_bounds__(64)
head_kernel(const float* __restrict__ local_emb, const float* __restrict__ glob,
            const float* __restrict__ q_emb,
            const float* __restrict__ fus_W, const float* __restrict__ fus_b,
            const float* __restrict__ out_W, const float* __restrict__ out_b,
            float* __restrict__ out)
{
    __shared__ float cat[128];
    __shared__ float fus[64];
    __shared__ float qv[64];
    const int b = blockIdx.x, d = threadIdx.x;
    cat[d]      = local_emb[(size_t)b * 64 + d];
    cat[64 + d] = glob[(size_t)b * 64 + d];
    qv[d]       = q_emb[(size_t)b * 64 + d];
    __syncthreads();
    float acc = fus_b[d];
    const float* fw = fus_W + (size_t)d * 128;
#pragma unroll 4
    for (int k = 0; k < 128; ++k) acc += cat[k] * fw[k];
    fus[d] = fmaxf(acc, 0.f);
    __syncthreads();
    float o0 = out_b[d], o1 = out_b[d];
    const float* ow = out_W + (size_t)d * 64;
#pragma unroll 4
    for (int k = 0; k < 64; ++k) { float ww = ow[k]; o0 += fus[k] * ww; o1 += qv[k] * ww; }
    out[(size_t)b * 64 + d] = o0;
    out[(size_t)BB * 64 + (size_t)b * 64 + d] = o1;
}

// ---------------------------------------------------------------------------
extern "C" void kernel_launch(void* const* d_in, const int* in_sizes, int n_in,
                              void* d_out, int out_size, void* d_ws, size_t ws_size,
                              hipStream_t stream)
{
    const int*   src_ids    = (const int*)d_in[0];
    const int*   dst_ids    = (const int*)d_in[1];
    const int*   l_nids     = (const int*)d_in[2];
    const int*   l_eids     = (const int*)d_in[3];
    const float* l_times    = (const float*)d_in[4];
    const int*   d_nids     = (const int*)d_in[5];
    const int*   d_eids     = (const int*)d_in[6];
    const float* d_times    = (const float*)d_in[7];
    const int*   retr       = (const int*)d_in[8];
    const float* node_raw   = (const float*)d_in[9];
    const float* edge_raw   = (const float*)d_in[10];
    const int*   pool_nodes = (const int*)d_in[11];
    const float* Wfeat  = (const float*)d_in[12];
    const float* bfeat  = (const float*)d_in[13];
    const float* Wedge  = (const float*)d_in[14];
    const float* bedge  = (const float*)d_in[15];
    const float* Wtime  = (const float*)d_in[16];
    const float* btime  = (const float*)d_in[17];
    const float* Wstruct= (const float*)d_in[18];
    const float* bstruct= (const float*)d_in[19];
    const float* ln_g   = (const float*)d_in[20];
    const float* ln_b   = (const float*)d_in[21];
    const float* gruL_Wih = (const float*)d_in[22];
    const float* gruL_Whh = (const float*)d_in[23];
    const float* gruL_bih = (const float*)d_in[24];
    const float* gruL_bhh = (const float*)d_in[25];
    const float* gruQ_Wih = (const float*)d_in[26];
    const float* gruQ_Whh = (const float*)d_in[27];
    const float* gruQ_bih = (const float*)d_in[28];
    const float* gruQ_bhh = (const float*)d_in[29];
    const float* gcn_W  = (const float*)d_in[30];
    const float* gcn_b  = (const float*)d_in[31];
    const float* fus_W  = (const float*)d_in[32];
    const float* fus_b  = (const float*)d_in[33];
    const float* out_W  = (const float*)d_in[34];
    const float* out_b  = (const float*)d_in[35];

    float* ws = (float*)d_ws;
    float* proj_node = ws;                              ws += (size_t)NN * DD;
    float* hgcn      = ws;                              ws += (size_t)NN * DD;
    float* TnL       = ws;                              ws += (size_t)NN * 192;
    float* TnQ       = ws;                              ws += (size_t)NN * 192;
    float* cstL      = ws;                              ws += 4096;
    float* cstQ      = ws;                              ws += 4096;
    unsigned* whpL   = (unsigned*)ws;                   ws += 192 * 32;
    unsigned* whpQ   = (unsigned*)ws;                   ws += 192 * 32;
    float* local_emb = ws;                              ws += (size_t)BB * DD;
    float* q_emb     = ws;                              ws += (size_t)BB * DD;
    float* glob      = ws;                              ws += (size_t)BB * DD;

    dim3 g1((NN + 127) / 128);
    gemm_nt_kernel<FF><<<g1, 256, 0, stream>>>(node_raw, Wfeat, bfeat, proj_node, NN);

    consts_kernel<<<2, 192, 0, stream>>>(gruL_Wih, gruL_bih, gruL_Whh, cstL, whpL,
                                         gruQ_Wih, gruQ_bih, gruQ_Whh, cstQ, whpQ,
                                         ln_g, ln_b, Wedge, bedge, Wtime, btime,
                                         Wstruct, bstruct);

    gemm_nt_kernel<DD><<<g1, 256, 0, stream>>>(proj_node, gcn_W, nullptr, hgcn, NN);

    tn_gemm_kernel<<<dim3(NN / 64, 2), 256, 0, stream>>>(proj_node, gruL_Wih, gruQ_Wih,
                                                         ln_g, TnL, TnQ);

    gru1_kernel<<<2 * BB, 64, 0, stream>>>(
        l_nids, l_eids, l_times, dst_ids,
        d_nids, d_eids, d_times, src_ids,
        node_raw, edge_raw, proj_node, TnL, TnQ, cstL, cstQ, whpL, whpQ,
        gruL_bhh, gruQ_bhh, Wedge, bedge, Wtime, btime, Wstruct, bstruct,
        local_emb, q_emb);

    graph_emb_kernel<<<BB, 512, 0, stream>>>(retr, pool_nodes, hgcn, gcn_b, glob);

    head_kernel<<<BB, 64, 0, stream>>>(local_emb, glob, q_emb,
        fus_W, fus_b, out_W, out_b, (float*)d_out);
}

// Round 8
// 384.334 us; speedup vs baseline: 1.9494x; 1.1799x over previous
//
#include <hip/hip_runtime.h>
#include <math.h>

#define NN 40000
#define FF 256
#define DD 64
#define LHH 200
#define BB 512
#define TDD 16
#define GE_HASH 1024

typedef _Float16 h2f __attribute__((ext_vector_type(2)));

__constant__ float TFREQ[16] = {
    1.0f,            0.48696753f,    0.23713737f,    0.115478195f,
    0.056234132f,    0.027384196f,   0.013335215f,   0.0064938162f,
    0.0031622776f,   0.0015399265f,  0.00074989421f, 0.00036517414f,
    0.00017782794f,  8.6596433e-05f, 4.2169650e-05f, 2.0535251e-05f
};

__device__ __forceinline__ float fd2(unsigned a, unsigned b, float c) {
    union { unsigned u; h2f h; } ua, ub;
    ua.u = a; ub.u = b;
    return __builtin_amdgcn_fdot2(ua.h, ub.h, c, false);
}
__device__ __forceinline__ unsigned packrn(float a, float b) {
    union { h2f h; unsigned u; } x;
    x.h.x = (_Float16)a; x.h.y = (_Float16)b;
    return x.u;
}
__device__ __forceinline__ unsigned pkrtz_u(float a, float b) {
    auto pk = __builtin_amdgcn_cvt_pkrtz(a, b);
    union { decltype(pk) h; unsigned u; } x;
    x.h = pk;
    return x.u;
}
__device__ __forceinline__ float dpp_xor1(float v) {
    return __int_as_float(
        __builtin_amdgcn_mov_dpp(__float_as_int(v), 0xB1, 0xF, 0xF, true));
}
__device__ __forceinline__ unsigned rlu(unsigned v, int l) {
    return (unsigned)__builtin_amdgcn_readlane((int)v, l);
}
__device__ __forceinline__ float sigm(float x) {
    return __builtin_amdgcn_rcpf(1.f + __expf(-x));
}
__device__ __forceinline__ float tanh_f(float x) {
    float e = __expf(2.f * x);
    return 1.f - 2.f * __builtin_amdgcn_rcpf(e + 1.f);
}

// ---------------------------------------------------------------------------
// K1: C[n][0:64] = A[n][:] @ W[64][KDIM]^T + bias
// ---------------------------------------------------------------------------
template<int KDIM>
__global__ void __launch_bounds__(256)
gemm_nt_kernel(const float* __restrict__ A, const float* __restrict__ W,
               const float* __restrict__ bias, float* __restrict__ C, int Nrows)
{
    __shared__ __align__(16) float a_t[128][8];
    __shared__ __align__(16) float wt[8][64];
    const int tid = threadIdx.x;
    const int tx = tid & 15;
    const int ty = tid >> 4;
    const int n0 = blockIdx.x * 128;

    float4 acc[8];
#pragma unroll
    for (int r = 0; r < 8; ++r) acc[r] = make_float4(0.f, 0.f, 0.f, 0.f);

    for (int kc = 0; kc < KDIM; kc += 8) {
        __syncthreads();
        {
            int r = tid >> 1;
            int cc = (tid & 1) * 4;
            int n = n0 + r;
            float4 v = make_float4(0.f, 0.f, 0.f, 0.f);
            if (n < Nrows) v = *(const float4*)(A + (size_t)n * KDIM + kc + cc);
            *(float4*)&a_t[r][cc] = v;
        }
        {
            int m = tid >> 2;
            int f0 = (tid & 3) * 2;
            float2 v = *(const float2*)(W + (size_t)m * KDIM + kc + f0);
            wt[f0][m] = v.x; wt[f0 + 1][m] = v.y;
        }
        __syncthreads();
        float4 w4[8];
#pragma unroll
        for (int f = 0; f < 8; ++f) w4[f] = *(float4*)&wt[f][tx * 4];
#pragma unroll
        for (int rr = 0; rr < 8; ++rr) {
            int row = ty + rr * 16;
            float4 a0 = *(float4*)&a_t[row][0];
            float4 a1 = *(float4*)&a_t[row][4];
            float av[8] = {a0.x, a0.y, a0.z, a0.w, a1.x, a1.y, a1.z, a1.w};
#pragma unroll
            for (int f = 0; f < 8; ++f) {
                acc[rr].x += av[f] * w4[f].x;
                acc[rr].y += av[f] * w4[f].y;
                acc[rr].z += av[f] * w4[f].z;
                acc[rr].w += av[f] * w4[f].w;
            }
        }
    }
    float4 bv = make_float4(0.f, 0.f, 0.f, 0.f);
    if (bias) bv = *(const float4*)(bias + tx * 4);
#pragma unroll
    for (int rr = 0; rr < 8; ++rr) {
        int n = n0 + ty + rr * 16;
        if (n < Nrows) {
            float4 o = acc[rr];
            o.x += bv.x; o.y += bv.y; o.z += bv.z; o.w += bv.w;
            *(float4*)(C + (size_t)n * DD + tx * 4) = o;
        }
    }
}

// ---------------------------------------------------------------------------
// Tn[n][j] = sum_k proj[n][k] * Wih[j][k] * ln_g[k]; grid.y selects L/Q.
// ---------------------------------------------------------------------------
__global__ void __launch_bounds__(256)
tn_gemm_kernel(const float* __restrict__ proj,
               const float* __restrict__ WihL, const float* __restrict__ WihQ,
               const float* __restrict__ ln_g,
               float* __restrict__ TnL, float* __restrict__ TnQ)
{
    const float* Wih = blockIdx.y ? WihQ : WihL;
    float* Tn = blockIdx.y ? TnQ : TnL;
    __shared__ float wgT[64][193];
    __shared__ __align__(16) float4 at4[64][16];
    const int tid = threadIdx.x;
    const int n0 = blockIdx.x * 64;
    for (int i = tid; i < 192 * 64; i += 256) {
        int j = i >> 6, k = i & 63;
        wgT[k][j] = Wih[i] * ln_g[k];
    }
    for (int i = tid; i < 1024; i += 256) {
        int r = i >> 4, kc = i & 15;
        at4[r][kc] = ((const float4*)(proj + (size_t)(n0 + r) * DD))[kc];
    }
    __syncthreads();
    const int c = tid & 63, wv = tid >> 6;
    float acc0[16], acc1[16], acc2[16];
#pragma unroll
    for (int r = 0; r < 16; ++r) { acc0[r] = 0.f; acc1[r] = 0.f; acc2[r] = 0.f; }
    for (int kc = 0; kc < 16; ++kc) {
        float w0[4], w1[4], w2[4];
#pragma unroll
        for (int q = 0; q < 4; ++q) {
            w0[q] = wgT[kc * 4 + q][c];
            w1[q] = wgT[kc * 4 + q][64 + c];
            w2[q] = wgT[kc * 4 + q][128 + c];
        }
#pragma unroll
        for (int r = 0; r < 16; ++r) {
            float4 a = at4[wv * 16 + r][kc];
            acc0[r] += a.x * w0[0] + a.y * w0[1] + a.z * w0[2] + a.w * w0[3];
            acc1[r] += a.x * w1[0] + a.y * w1[1] + a.z * w1[2] + a.w * w1[3];
            acc2[r] += a.x * w2[0] + a.y * w2[1] + a.z * w2[2] + a.w * w2[3];
        }
    }
#pragma unroll
    for (int r = 0; r < 16; ++r) {
        size_t row = (size_t)(n0 + wv * 16 + r) * 192;
        Tn[row + c]       = acc0[r];
        Tn[row + 64 + c]  = acc1[r];
        Tn[row + 128 + c] = acc2[r];
    }
}

// ---------------------------------------------------------------------------
// Per-gate-row constants out[21][192] + f16-packed Whh (whp[192][32] u32)
// + packed time-dot weights tpk[(g*64+d)*8+q] and wtpk[d*8+q].
// ---------------------------------------------------------------------------
__global__ void __launch_bounds__(192)
consts_kernel(const float* __restrict__ WihL, const float* __restrict__ bihL,
              const float* __restrict__ WhhL, float* __restrict__ outL,
              unsigned* __restrict__ whpL, unsigned* __restrict__ tpkL,
              const float* __restrict__ WihQ, const float* __restrict__ bihQ,
              const float* __restrict__ WhhQ, float* __restrict__ outQ,
              unsigned* __restrict__ whpQ, unsigned* __restrict__ tpkQ,
              unsigned* __restrict__ wtpk,
              const float* __restrict__ ln_g, const float* __restrict__ ln_b,
              const float* __restrict__ Wedge, const float* __restrict__ bedge,
              const float* __restrict__ Wtime, const float* __restrict__ btime,
              const float* __restrict__ Wstruct, const float* __restrict__ bstruct)
{
    const float* Wih = blockIdx.x ? WihQ : WihL;
    const float* bih = blockIdx.x ? bihQ : bihL;
    const float* Whh = blockIdx.x ? WhhQ : WhhL;
    float* out = blockIdx.x ? outQ : outL;
    unsigned* whp = blockIdx.x ? whpQ : whpL;
    unsigned* tpk = blockIdx.x ? tpkQ : tpkL;
    const int j = threadIdx.x;
    float te = 0.f, tw = 0.f, t1 = 0.f, tb0 = 0.f, cc = 0.f;
    float tt[16];
#pragma unroll
    for (int t = 0; t < 16; ++t) tt[t] = 0.f;
    for (int k = 0; k < DD; ++k) {
        float wv = Wih[j * DD + k];
        float wg = wv * ln_g[k];
        te  += wg * Wedge[k];
        tw  += wg * Wstruct[k];
        t1  += wg;
        tb0 += wg * (bedge[k] + btime[k] + 2.f * bstruct[k]);
        cc  += wv * ln_b[k];
#pragma unroll
        for (int t = 0; t < 16; ++t) tt[t] += wg * Wtime[k * TDD + t];
    }
    out[0 * 192 + j] = te;
    out[1 * 192 + j] = tw;
    out[2 * 192 + j] = t1;
    out[3 * 192 + j] = tb0;
    out[4 * 192 + j] = cc + bih[j];
    for (int t = 0; t < 16; ++t) out[(5 + t) * 192 + j] = tt[t];
    // packed time-dot weights for the GRU: tpk[(g*64+d)*8 + q]
    for (int q = 0; q < 8; ++q)
        tpk[j * 8 + q] = packrn(tt[2 * q], tt[2 * q + 1]);
    // shared packed Wtime rows
    if (blockIdx.x == 0 && j < 64)
        for (int q = 0; q < 8; ++q)
            wtpk[j * 8 + q] = packrn(Wtime[j * TDD + 2 * q], Wtime[j * TDD + 2 * q + 1]);
    // f16-pack Whh row j (pairs along k)
    for (int k2 = 0; k2 < 32; ++k2)
        whp[j * 32 + k2] = packrn(Whh[j * DD + 2 * k2], Whh[j * DD + 2 * k2 + 1]);
}

// ---------------------------------------------------------------------------
// GRU: ONE wave per sequence; waves_per_eu(1,1) unlocks full VGPR budget so
// the 128 packed weights stay register-resident. 3-stage static pipeline.
// ---------------------------------------------------------------------------
struct GS {
    int nid;
    float tn0, tn1, tn2, pv, e0, sk, t;
};

__global__ void __launch_bounds__(64) __attribute__((amdgpu_waves_per_eu(1, 1)))
gru1_kernel(const int* __restrict__ nidsL, const int* __restrict__ eidsL,
            const float* __restrict__ timesL, const int* __restrict__ curL,
            const int* __restrict__ nidsQ, const int* __restrict__ eidsQ,
            const float* __restrict__ timesQ, const int* __restrict__ curQ,
            const float* __restrict__ node_raw, const float* __restrict__ edge_raw,
            const float* __restrict__ proj_node,
            const float* __restrict__ TnL, const float* __restrict__ TnQ,
            const float* __restrict__ cstL, const float* __restrict__ cstQ,
            const unsigned* __restrict__ whpL, const unsigned* __restrict__ whpQ,
            const unsigned* __restrict__ tpkL, const unsigned* __restrict__ tpkQ,
            const unsigned* __restrict__ wtpk,
            const float* __restrict__ bhhL, const float* __restrict__ bhhQ,
            const float* __restrict__ Wedge, const float* __restrict__ bedge,
            const float* __restrict__ Wtime, const float* __restrict__ btime,
            const float* __restrict__ Wstruct, const float* __restrict__ bstruct,
            float* __restrict__ embL, float* __restrict__ embQ)
{
    const int blk = blockIdx.x;
    const int g = blk >> 9, s = blk & 511;
    const int d = threadIdx.x;

    const int*      nids  = g ? nidsQ : nidsL;
    const int*      eids  = g ? eidsQ : eidsL;
    const float*    times = g ? timesQ : timesL;
    const int*      curp  = g ? curQ : curL;
    const float*    Tn    = g ? TnQ : TnL;
    const float*    cst   = g ? cstQ : cstL;
    const unsigned* whp   = g ? whpQ : whpL;
    const unsigned* tpk   = g ? tpkQ : tpkL;
    const float*    bhh   = g ? bhhQ : bhhL;
    float*          emb   = g ? embQ : embL;

    // ---- packed Whh rows: 96 u32 in VGPRs
    unsigned w0[32], w1[32], w2[32];
    {
        const unsigned* p0 = whp + (size_t)d * 32;
        const unsigned* p1 = whp + (size_t)(64 + d) * 32;
        const unsigned* p2 = whp + (size_t)(128 + d) * 32;
#pragma unroll
        for (int q4 = 0; q4 < 8; ++q4) {
            uint4 a = *(const uint4*)(p0 + 4 * q4);
            w0[4*q4] = a.x; w0[4*q4+1] = a.y; w0[4*q4+2] = a.z; w0[4*q4+3] = a.w;
            uint4 b = *(const uint4*)(p1 + 4 * q4);
            w1[4*q4] = b.x; w1[4*q4+1] = b.y; w1[4*q4+2] = b.z; w1[4*q4+3] = b.w;
            uint4 c = *(const uint4*)(p2 + 4 * q4);
            w2[4*q4] = c.x; w2[4*q4+1] = c.y; w2[4*q4+2] = c.z; w2[4*q4+3] = c.w;
        }
    }
#pragma unroll
    for (int i = 0; i < 32; ++i) {
        asm volatile("" : "+v"(w0[i]));
        asm volatile("" : "+v"(w1[i]));
        asm volatile("" : "+v"(w2[i]));
    }
    // packed cos-dot weights (pre-packed by consts_kernel)
    unsigned tp0[8], tp1[8], tp2[8], wtp[8];
#pragma unroll
    for (int q4 = 0; q4 < 2; ++q4) {
        uint4 a = *(const uint4*)(tpk + (size_t)(0 * 64 + d) * 8 + 4 * q4);
        tp0[4*q4] = a.x; tp0[4*q4+1] = a.y; tp0[4*q4+2] = a.z; tp0[4*q4+3] = a.w;
        uint4 b = *(const uint4*)(tpk + (size_t)(1 * 64 + d) * 8 + 4 * q4);
        tp1[4*q4] = b.x; tp1[4*q4+1] = b.y; tp1[4*q4+2] = b.z; tp1[4*q4+3] = b.w;
        uint4 c = *(const uint4*)(tpk + (size_t)(2 * 64 + d) * 8 + 4 * q4);
        tp2[4*q4] = c.x; tp2[4*q4+1] = c.y; tp2[4*q4+2] = c.z; tp2[4*q4+3] = c.w;
        uint4 e = *(const uint4*)(wtpk + (size_t)d * 8 + 4 * q4);
        wtp[4*q4] = e.x; wtp[4*q4+1] = e.y; wtp[4*q4+2] = e.z; wtp[4*q4+3] = e.w;
    }
#pragma unroll
    for (int i = 0; i < 8; ++i) {
        asm volatile("" : "+v"(tp0[i]));
        asm volatile("" : "+v"(tp1[i]));
        asm volatile("" : "+v"(tp2[i]));
        asm volatile("" : "+v"(wtp[i]));
    }
    const float TE0 = cst[0*192 + d], TE1 = cst[0*192 + 64 + d], TE2 = cst[0*192 + 128 + d];
    const float TW0 = cst[1*192 + d], TW1 = cst[1*192 + 64 + d], TW2 = cst[1*192 + 128 + d];
    const float T10 = cst[2*192 + d], T11 = cst[2*192 + 64 + d], T12 = cst[2*192 + 128 + d];
    const float TB0 = cst[3*192 + d], TB1 = cst[3*192 + 64 + d], TB2 = cst[3*192 + 128 + d];
    const float CC0 = cst[4*192 + d] + bhh[d];
    const float CC1 = cst[4*192 + 64 + d] + bhh[64 + d];
    const float CC2 = cst[4*192 + 128 + d];
    const float BH2 = bhh[128 + d];
    const float we_l = Wedge[d];
    const float ws_l = Wstruct[d];
    const float b0_l = bedge[d] + btime[d] + 2.f * bstruct[d];
    const float tfl  = TFREQ[d & 15];

    const int cur = curp[s];
    const int csk = (int)node_raw[(size_t)cur * FF];
    const int* nrow = nids + s * LHH;
    const int* erow = eids + s * LHH;
    const float* trow = times + s * LHH;

    float h = 0.f;

    auto GATH = [&](GS& G, int nid, int eid, int lpos) {
        G.nid = nid;
        const float* tb = Tn + (size_t)nid * 192;
        G.tn0 = tb[d];
        G.tn1 = tb[64 + d];
        G.tn2 = tb[128 + d];
        G.pv  = proj_node[(size_t)nid * DD + d];
        G.e0  = edge_raw[(size_t)eid * 4];
        G.sk  = node_raw[(size_t)nid * FF];
        G.t   = trow[lpos];
    };

    auto PREP = [&](const GS& G, float& g0, float& g1, float& g2) {
        float cv = __cosf(G.t * tfl);
        float cx = dpp_xor1(cv);
        unsigned cp = pkrtz_u(cv, cx);
        unsigned s0 = rlu(cp, 0),  s1 = rlu(cp, 2),  s2 = rlu(cp, 4),  s3 = rlu(cp, 6);
        unsigned s4 = rlu(cp, 8),  s5 = rlu(cp, 10), s6 = rlu(cp, 12), s7 = rlu(cp, 14);
        float tf = fd2(wtp[7], s7, fd2(wtp[6], s6, fd2(wtp[5], s5, fd2(wtp[4], s4, 0.f))));
        tf = fd2(wtp[3], s3, fd2(wtp[2], s2, fd2(wtp[1], s1, fd2(wtp[0], s0, tf))));
        float flg = ((G.nid == cur) ? 1.f : 0.f) + (((int)G.sk == csk) ? 1.f : 0.f);
        float f = G.pv + G.e0 * we_l + flg * ws_l + b0_l + tf;
        float mu = f;
#pragma unroll
        for (int off = 32; off; off >>= 1) mu += __shfl_xor(mu, off);
        mu *= (1.f / 64.f);
        float dv = f - mu, var = dv * dv;
#pragma unroll
        for (int off = 32; off; off >>= 1) var += __shfl_xor(var, off);
        float rs = rsqrtf(var * (1.f / 64.f) + 1e-5f);
        float c0 = fd2(tp0[7], s7, fd2(tp0[6], s6, fd2(tp0[5], s5, fd2(tp0[4], s4, 0.f))));
        c0 = fd2(tp0[3], s3, fd2(tp0[2], s2, fd2(tp0[1], s1, fd2(tp0[0], s0, c0))));
        float c1 = fd2(tp1[7], s7, fd2(tp1[6], s6, fd2(tp1[5], s5, fd2(tp1[4], s4, 0.f))));
        c1 = fd2(tp1[3], s3, fd2(tp1[2], s2, fd2(tp1[1], s1, fd2(tp1[0], s0, c1))));
        float c2 = fd2(tp2[7], s7, fd2(tp2[6], s6, fd2(tp2[5], s5, fd2(tp2[4], s4, 0.f))));
        c2 = fd2(tp2[3], s3, fd2(tp2[2], s2, fd2(tp2[1], s1, fd2(tp2[0], s0, c2))));
        g0 = (c0 + G.tn0 + G.e0 * TE0 + flg * TW0 + TB0 - mu * T10) * rs + CC0;
        g1 = (c1 + G.tn1 + G.e0 * TE1 + flg * TW1 + TB1 - mu * T11) * rs + CC1;
        g2 = (c2 + G.tn2 + G.e0 * TE2 + flg * TW2 + TB2 - mu * T12) * rs + CC2;
    };

    auto COMPUTE = [&](float g0, float g1, float g2) {
        float hx = dpp_xor1(h);
        unsigned hpu = pkrtz_u(h, hx);
        float a0 = 0.f, a1 = 0.f, a2 = 0.f, e0 = 0.f, e1 = 0.f, e2 = 0.f;
#pragma unroll
        for (int q = 0; q < 32; q += 2) {
            unsigned sa = rlu(hpu, 2 * q);
            unsigned sb = rlu(hpu, 2 * q + 2);
            a0 = fd2(w0[q], sa, a0);
            a1 = fd2(w1[q], sa, a1);
            a2 = fd2(w2[q], sa, a2);
            e0 = fd2(w0[q+1], sb, e0);
            e1 = fd2(w1[q+1], sb, e1);
            e2 = fd2(w2[q+1], sb, e2);
        }
        float mv0 = a0 + e0, mv1 = a1 + e1, mv2 = a2 + e2;
        float r = sigm(g0 + mv0);
        float z = sigm(g1 + mv1);
        float n = tanh_f(g2 + r * (mv2 + BH2));
        h = (1.f - z) * n + z * h;
    };

    // ---- prologue
    int in0, in1, in2, in3, ie0, ie1, ie2, ie3;
    GS G0, G1, G2, G3;
    float gA0, gA1, gA2, gB0, gB1, gB2;
    {
        int pn[10], pe[10];
#pragma unroll
        for (int i = 0; i < 10; ++i) { pn[i] = nrow[i]; pe[i] = erow[i]; }
        GS Gp0, Gp1;
        GATH(Gp0, pn[0], pe[0], 0);
        GATH(Gp1, pn[1], pe[1], 1);
        GATH(G0, pn[2], pe[2], 2);
        GATH(G1, pn[3], pe[3], 3);
        GATH(G2, pn[4], pe[4], 4);
        GATH(G3, pn[5], pe[5], 5);
        in0 = pn[6]; in1 = pn[7]; in2 = pn[8]; in3 = pn[9];
        ie0 = pe[6]; ie1 = pe[7]; ie2 = pe[8]; ie3 = pe[9];
        PREP(Gp0, gA0, gA1, gA2);
        PREP(Gp1, gB0, gB1, gB2);
    }

    // ---- main loop: 4 steps / iteration
    for (int l = 0; l < LHH; l += 4) {
        int i10 = (l + 10 < LHH) ? l + 10 : LHH - 1;
        int i11 = (l + 11 < LHH) ? l + 11 : LHH - 1;
        int i12 = (l + 12 < LHH) ? l + 12 : LHH - 1;
        int i13 = (l + 13 < LHH) ? l + 13 : LHH - 1;
        int nn0 = nrow[i10], nn1 = nrow[i11], nn2 = nrow[i12], nn3 = nrow[i13];
        int ne0 = erow[i10], ne1 = erow[i11], ne2 = erow[i12], ne3 = erow[i13];
        int p6 = (l + 6 < LHH) ? l + 6 : LHH - 1;
        int p7 = (l + 7 < LHH) ? l + 7 : LHH - 1;
        int p8 = (l + 8 < LHH) ? l + 8 : LHH - 1;
        int p9 = (l + 9 < LHH) ? l + 9 : LHH - 1;
        GS N0, N1, N2, N3;
        GATH(N0, in0, ie0, p6);
        GATH(N1, in1, ie1, p7);
        GATH(N2, in2, ie2, p8);
        GATH(N3, in3, ie3, p9);
        float gC0, gC1, gC2, gD0, gD1, gD2, gE0, gE1, gE2, gF0, gF1, gF2;
        PREP(G0, gC0, gC1, gC2);
        PREP(G1, gD0, gD1, gD2);
        PREP(G2, gE0, gE1, gE2);
        PREP(G3, gF0, gF1, gF2);
        COMPUTE(gA0, gA1, gA2);
        COMPUTE(gB0, gB1, gB2);
        COMPUTE(gC0, gC1, gC2);
        COMPUTE(gD0, gD1, gD2);
        gA0 = gE0; gA1 = gE1; gA2 = gE2;
        gB0 = gF0; gB1 = gF1; gB2 = gF2;
        G0 = N0; G1 = N1; G2 = N2; G3 = N3;
        in0 = nn0; in1 = nn1; in2 = nn2; in3 = nn3;
        ie0 = ne0; ie1 = ne1; ie2 = ne2; ie3 = ne3;
    }
    emb[(size_t)s * DD + d] = h;
}

// ---------------------------------------------------------------------------
// K3: graph_emb — hash-dedup'd GCNConv + mean pool. 512 thr (8 waves)/block.
// ---------------------------------------------------------------------------
__device__ __forceinline__ int hlookup(const unsigned* hkey, const int* hslot, unsigned id)
{
    unsigned p = (id * 2654435761u) & (GE_HASH - 1);
    while (hkey[p] != id) p = (p + 1) & (GE_HASH - 1);
    return hslot[p];
}

__global__ void __launch_bounds__(512)
graph_emb_kernel(const int* __restrict__ retrieved, const int* __restrict__ pool_nodes,
                 const float* __restrict__ hgcn, const float* __restrict__ gcn_b,
                 float* __restrict__ glob)
{
    __shared__ float agg[400 * 64];
    __shared__ unsigned hkey[GE_HASH];
    __shared__ int hslot[GE_HASH];
    __shared__ unsigned ekey[GE_HASH];
    __shared__ int slot_id[400];
    __shared__ unsigned deg[400];
    __shared__ float dis[400];
    __shared__ unsigned elist[400];
    __shared__ int ids[400];
    __shared__ int pids[8];
    __shared__ int cntU, cntE;
    __shared__ float gcnb_s[64];
    __shared__ float red[8][64];

    const int b = blockIdx.x;
    const int tid = threadIdx.x;
    const int lane = tid & 63, wid = tid >> 6;

    if (tid < 8)  pids[tid] = retrieved[b * 8 + tid];
    if (tid < 64) gcnb_s[tid] = gcn_b[tid];
    if (tid == 0) { cntU = 0; cntE = 0; }
    for (int i = tid; i < GE_HASH; i += 512) { hkey[i] = 0u; ekey[i] = 0u; }
    if (tid < 400) deg[tid] = 0u;
    __syncthreads();

    if (tid < 400) {
        int k = tid / 50, p = tid % 50;
        ids[tid] = pool_nodes[(size_t)pids[k] * 50 + p];
    }
    __syncthreads();

    if (tid < 400) {
        int idi = ids[tid];
        if (idi > 0) {
            unsigned id = (unsigned)idi;
            unsigned p = (id * 2654435761u) & (GE_HASH - 1);
            while (true) {
                unsigned old = atomicCAS(&hkey[p], 0u, id);
                if (old == 0u) {
                    int s = atomicAdd(&cntU, 1);
                    hslot[p] = s; slot_id[s] = idi;
                    break;
                }
                if (old == id) break;
                p = (p + 1) & (GE_HASH - 1);
            }
        }
    }
    __syncthreads();

    if (tid < 8 * 49) {
        int k = tid / 49, p = tid % 49;
        int u = ids[k * 50 + p], v = ids[k * 50 + p + 1];
        if (u > 0 && v > 0) {
            unsigned a = (unsigned)min(u, v), bb = (unsigned)max(u, v);
            unsigned key = a * 40000u + bb;
            unsigned p2 = (key * 2654435761u) & (GE_HASH - 1);
            while (true) {
                unsigned old = atomicCAS(&ekey[p2], 0u, key);
                if (old == 0u) {
                    int su = hlookup(hkey, hslot, a);
                    int sv = hlookup(hkey, hslot, bb);
                    int e = atomicAdd(&cntE, 1);
                    elist[e] = ((unsigned)su << 16) | (unsigned)sv;
                    atomicAdd(&deg[su], 1u);
                    atomicAdd(&deg[sv], 1u);
                    break;
                }
                if (old == key) break;
                p2 = (p2 + 1) & (GE_HASH - 1);
            }
        }
    }
    __syncthreads();

    const int U = cntU, EC = cntE;
    if (tid < U) dis[tid] = rsqrtf((float)deg[tid] + 1.0f);
    __syncthreads();

    for (int s = wid; s < U; s += 8) {
        float d2 = dis[s] * dis[s];
        float hval = hgcn[(size_t)slot_id[s] * 64 + lane];
        agg[s * 64 + lane] = gcnb_s[lane] + d2 * hval;
    }
    __syncthreads();

    for (int e = wid; e < EC; e += 8) {
        unsigned pk = elist[e];
        int su = (int)(pk >> 16), sv = (int)(pk & 0xffffu);
        float nrm = dis[su] * dis[sv];
        float hu = hgcn[(size_t)slot_id[su] * 64 + lane];
        float hv = hgcn[(size_t)slot_id[sv] * 64 + lane];
        atomicAdd(&agg[sv * 64 + lane], nrm * hu);
        atomicAdd(&agg[su * 64 + lane], nrm * hv);
    }
    __syncthreads();

    float acc = 0.f;
    for (int s = wid; s < U; s += 8) acc += fmaxf(agg[s * 64 + lane], 0.f);
    red[wid][lane] = acc;
    __syncthreads();
    if (tid < 64) {
        float tot = 0.f;
#pragma unroll
        for (int q = 0; q < 8; ++q) tot += red[q][tid];
        glob[(size_t)b * 64 + tid] = tot / (float)max(U, 1);
    }
}

// ---------------------------------------------------------------------------
// K4: fusion + output heads.
// ---------------------------------------------------------------------------
__global__ void __launch_bounds__(64)
head_kernel(const float* __restrict__ local_emb, const float* __restrict__ glob,
            const float* __restrict__ q_emb,
            const float* __restrict__ fus_W, const float* __restrict__ fus_b,
            const float* __restrict__ out_W, const float* __restrict__ out_b,
            float* __restrict__ out)
{
    __shared__ float cat[128];
    __shared__ float fus[64];
    __shared__ float qv[64];
    const int b = blockIdx.x, d = threadIdx.x;
    cat[d]      = local_emb[(size_t)b * 64 + d];
    cat[64 + d] = glob[(size_t)b * 64 + d];
    qv[d]       = q_emb[(size_t)b * 64 + d];
    __syncthreads();
    float acc = fus_b[d];
    const float* fw = fus_W + (size_t)d * 128;
#pragma unroll 4
    for (int k = 0; k < 128; ++k) acc += cat[k] * fw[k];
    fus[d] = fmaxf(acc, 0.f);
    __syncthreads();
    float o0 = out_b[d], o1 = out_b[d];
    const float* ow = out_W + (size_t)d * 64;
#pragma unroll 4
    for (int k = 0; k < 64; ++k) { float ww = ow[k]; o0 += fus[k] * ww; o1 += qv[k] * ww; }
    out[(size_t)b * 64 + d] = o0;
    out[(size_t)BB * 64 + (size_t)b * 64 + d] = o1;
}

// ---------------------------------------------------------------------------
extern "C" void kernel_launch(void* const* d_in, const int* in_sizes, int n_in,
                              void* d_out, int out_size, void* d_ws, size_t ws_size,
                              hipStream_t stream)
{
    const int*   src_ids    = (const int*)d_in[0];
    const int*   dst_ids    = (const int*)d_in[1];
    const int*   l_nids     = (const int*)d_in[2];
    const int*   l_eids     = (const int*)d_in[3];
    const float* l_times    = (const float*)d_in[4];
    const int*   d_nids     = (const int*)d_in[5];
    const int*   d_eids     = (const int*)d_in[6];
    const float* d_times    = (const float*)d_in[7];
    const int*   retr       = (const int*)d_in[8];
    const float* node_raw   = (const float*)d_in[9];
    const float* edge_raw   = (const float*)d_in[10];
    const int*   pool_nodes = (const int*)d_in[11];
    const float* Wfeat  = (const float*)d_in[12];
    const float* bfeat  = (const float*)d_in[13];
    const float* Wedge  = (const float*)d_in[14];
    const float* bedge  = (const float*)d_in[15];
    const float* Wtime  = (const float*)d_in[16];
    const float* btime  = (const float*)d_in[17];
    const float* Wstruct= (const float*)d_in[18];
    const float* bstruct= (const float*)d_in[19];
    const float* ln_g   = (const float*)d_in[20];
    const float* ln_b   = (const float*)d_in[21];
    const float* gruL_Wih = (const float*)d_in[22];
    const float* gruL_Whh = (const float*)d_in[23];
    const float* gruL_bih = (const float*)d_in[24];
    const float* gruL_bhh = (const float*)d_in[25];
    const float* gruQ_Wih = (const float*)d_in[26];
    const float* gruQ_Whh = (const float*)d_in[27];
    const float* gruQ_bih = (const float*)d_in[28];
    const float* gruQ_bhh = (const float*)d_in[29];
    const float* gcn_W  = (const float*)d_in[30];
    const float* gcn_b  = (const float*)d_in[31];
    const float* fus_W  = (const float*)d_in[32];
    const float* fus_b  = (const float*)d_in[33];
    const float* out_W  = (const float*)d_in[34];
    const float* out_b  = (const float*)d_in[35];

    float* ws = (float*)d_ws;
    float* proj_node = ws;                              ws += (size_t)NN * DD;
    float* hgcn      = ws;                              ws += (size_t)NN * DD;
    float* TnL       = ws;                              ws += (size_t)NN * 192;
    float* TnQ       = ws;                              ws += (size_t)NN * 192;
    float* cstL      = ws;                              ws += 4096;
    float* cstQ      = ws;                              ws += 4096;
    unsigned* whpL   = (unsigned*)ws;                   ws += 192 * 32;
    unsigned* whpQ   = (unsigned*)ws;                   ws += 192 * 32;
    unsigned* tpkL   = (unsigned*)ws;                   ws += 192 * 8;
    unsigned* tpkQ   = (unsigned*)ws;                   ws += 192 * 8;
    unsigned* wtpk   = (unsigned*)ws;                   ws += 64 * 8;
    float* local_emb = ws;                              ws += (size_t)BB * DD;
    float* q_emb     = ws;                              ws += (size_t)BB * DD;
    float* glob      = ws;                              ws += (size_t)BB * DD;

    dim3 g1((NN + 127) / 128);
    gemm_nt_kernel<FF><<<g1, 256, 0, stream>>>(node_raw, Wfeat, bfeat, proj_node, NN);

    consts_kernel<<<2, 192, 0, stream>>>(gruL_Wih, gruL_bih, gruL_Whh, cstL, whpL, tpkL,
                                         gruQ_Wih, gruQ_bih, gruQ_Whh, cstQ, whpQ, tpkQ,
                                         wtpk, ln_g, ln_b, Wedge, bedge, Wtime, btime,
                                         Wstruct, bstruct);

    gemm_nt_kernel<DD><<<g1, 256, 0, stream>>>(proj_node, gcn_W, nullptr, hgcn, NN);

    tn_gemm_kernel<<<dim3(NN / 64, 2), 256, 0, stream>>>(proj_node, gruL_Wih, gruQ_Wih,
                                                         ln_g, TnL, TnQ);

    gru1_kernel<<<2 * BB, 64, 0, stream>>>(
        l_nids, l_eids, l_times, dst_ids,
        d_nids, d_eids, d_times, src_ids,
        node_raw, edge_raw, proj_node, TnL, TnQ, cstL, cstQ, whpL, whpQ,
        tpkL, tpkQ, wtpk,
        gruL_bhh, gruQ_bhh, Wedge, bedge, Wtime, btime, Wstruct, bstruct,
        local_emb, q_emb);

    graph_emb_kernel<<<BB, 512, 0, stream>>>(retr, pool_nodes, hgcn, gcn_b, glob);

    head_kernel<<<BB, 64, 0, stream>>>(local_emb, glob, q_emb,
        fus_W, fus_b, out_W, out_b, (float*)d_out);
}

// Round 9
// 380.334 us; speedup vs baseline: 1.9699x; 1.0105x over previous
//
#include <hip/hip_runtime.h>
#include <math.h>

#define NN 40000
#define FF 256
#define DD 64
#define LHH 200
#define BB 512
#define TDD 16
#define GE_HASH 1024

typedef _Float16 h2f __attribute__((ext_vector_type(2)));

__constant__ float TFREQ[16] = {
    1.0f,            0.48696753f,    0.23713737f,    0.115478195f,
    0.056234132f,    0.027384196f,   0.013335215f,   0.0064938162f,
    0.0031622776f,   0.0015399265f,  0.00074989421f, 0.00036517414f,
    0.00017782794f,  8.6596433e-05f, 4.2169650e-05f, 2.0535251e-05f
};

__device__ __forceinline__ float fd2(unsigned a, unsigned b, float c) {
    union { unsigned u; h2f h; } ua, ub;
    ua.u = a; ub.u = b;
    return __builtin_amdgcn_fdot2(ua.h, ub.h, c, false);
}
__device__ __forceinline__ unsigned packrn(float a, float b) {
    union { h2f h; unsigned u; } x;
    x.h.x = (_Float16)a; x.h.y = (_Float16)b;
    return x.u;
}
__device__ __forceinline__ unsigned short f16u(float a) {
    union { _Float16 h; unsigned short u; } x;
    x.h = (_Float16)a;
    return x.u;
}
__device__ __forceinline__ float h16f(unsigned short u) {
    union { unsigned short u; _Float16 h; } x;
    x.u = u;
    return (float)x.h;
}
__device__ __forceinline__ float f16lo(unsigned u) {
    union { unsigned u; h2f h; } x; x.u = u; return (float)x.h.x;
}
__device__ __forceinline__ float f16hi(unsigned u) {
    union { unsigned u; h2f h; } x; x.u = u; return (float)x.h.y;
}
__device__ __forceinline__ unsigned pkrtz_u(float a, float b) {
    auto pk = __builtin_amdgcn_cvt_pkrtz(a, b);
    union { decltype(pk) h; unsigned u; } x;
    x.h = pk;
    return x.u;
}
__device__ __forceinline__ float dpp_xor1(float v) {
    return __int_as_float(
        __builtin_amdgcn_mov_dpp(__float_as_int(v), 0xB1, 0xF, 0xF, true));
}
__device__ __forceinline__ unsigned rlu(unsigned v, int l) {
    return (unsigned)__builtin_amdgcn_readlane((int)v, l);
}
__device__ __forceinline__ float sigm(float x) {
    return __builtin_amdgcn_rcpf(1.f + __expf(-x));
}
__device__ __forceinline__ float tanh_f(float x) {
    float e = __expf(2.f * x);
    return 1.f - 2.f * __builtin_amdgcn_rcpf(e + 1.f);
}

// ---------------------------------------------------------------------------
// K1: C[n][0:64] = A[n][:] @ W[64][KDIM]^T + bias
// ---------------------------------------------------------------------------
template<int KDIM>
__global__ void __launch_bounds__(256)
gemm_nt_kernel(const float* __restrict__ A, const float* __restrict__ W,
               const float* __restrict__ bias, float* __restrict__ C, int Nrows)
{
    __shared__ __align__(16) float a_t[128][8];
    __shared__ __align__(16) float wt[8][64];
    const int tid = threadIdx.x;
    const int tx = tid & 15;
    const int ty = tid >> 4;
    const int n0 = blockIdx.x * 128;

    float4 acc[8];
#pragma unroll
    for (int r = 0; r < 8; ++r) acc[r] = make_float4(0.f, 0.f, 0.f, 0.f);

    for (int kc = 0; kc < KDIM; kc += 8) {
        __syncthreads();
        {
            int r = tid >> 1;
            int cc = (tid & 1) * 4;
            int n = n0 + r;
            float4 v = make_float4(0.f, 0.f, 0.f, 0.f);
            if (n < Nrows) v = *(const float4*)(A + (size_t)n * KDIM + kc + cc);
            *(float4*)&a_t[r][cc] = v;
        }
        {
            int m = tid >> 2;
            int f0 = (tid & 3) * 2;
            float2 v = *(const float2*)(W + (size_t)m * KDIM + kc + f0);
            wt[f0][m] = v.x; wt[f0 + 1][m] = v.y;
        }
        __syncthreads();
        float4 w4[8];
#pragma unroll
        for (int f = 0; f < 8; ++f) w4[f] = *(float4*)&wt[f][tx * 4];
#pragma unroll
        for (int rr = 0; rr < 8; ++rr) {
            int row = ty + rr * 16;
            float4 a0 = *(float4*)&a_t[row][0];
            float4 a1 = *(float4*)&a_t[row][4];
            float av[8] = {a0.x, a0.y, a0.z, a0.w, a1.x, a1.y, a1.z, a1.w};
#pragma unroll
            for (int f = 0; f < 8; ++f) {
                acc[rr].x += av[f] * w4[f].x;
                acc[rr].y += av[f] * w4[f].y;
                acc[rr].z += av[f] * w4[f].z;
                acc[rr].w += av[f] * w4[f].w;
            }
        }
    }
    float4 bv = make_float4(0.f, 0.f, 0.f, 0.f);
    if (bias) bv = *(const float4*)(bias + tx * 4);
#pragma unroll
    for (int rr = 0; rr < 8; ++rr) {
        int n = n0 + ty + rr * 16;
        if (n < Nrows) {
            float4 o = acc[rr];
            o.x += bv.x; o.y += bv.y; o.z += bv.z; o.w += bv.w;
            *(float4*)(C + (size_t)n * DD + tx * 4) = o;
        }
    }
}

// ---------------------------------------------------------------------------
// Tn16[n][j] = f16( sum_k proj[n][k] * Wih[j][k] * ln_g[k] ); grid.y = L/Q.
// ---------------------------------------------------------------------------
__global__ void __launch_bounds__(256)
tn_gemm_kernel(const float* __restrict__ proj,
               const float* __restrict__ WihL, const float* __restrict__ WihQ,
               const float* __restrict__ ln_g,
               unsigned short* __restrict__ TnL, unsigned short* __restrict__ TnQ)
{
    const float* Wih = blockIdx.y ? WihQ : WihL;
    unsigned short* Tn = blockIdx.y ? TnQ : TnL;
    __shared__ float wgT[64][193];
    __shared__ __align__(16) float4 at4[64][16];
    const int tid = threadIdx.x;
    const int n0 = blockIdx.x * 64;
    for (int i = tid; i < 192 * 64; i += 256) {
        int j = i >> 6, k = i & 63;
        wgT[k][j] = Wih[i] * ln_g[k];
    }
    for (int i = tid; i < 1024; i += 256) {
        int r = i >> 4, kc = i & 15;
        at4[r][kc] = ((const float4*)(proj + (size_t)(n0 + r) * DD))[kc];
    }
    __syncthreads();
    const int c = tid & 63, wv = tid >> 6;
    float acc0[16], acc1[16], acc2[16];
#pragma unroll
    for (int r = 0; r < 16; ++r) { acc0[r] = 0.f; acc1[r] = 0.f; acc2[r] = 0.f; }
    for (int kc = 0; kc < 16; ++kc) {
        float w0[4], w1[4], w2[4];
#pragma unroll
        for (int q = 0; q < 4; ++q) {
            w0[q] = wgT[kc * 4 + q][c];
            w1[q] = wgT[kc * 4 + q][64 + c];
            w2[q] = wgT[kc * 4 + q][128 + c];
        }
#pragma unroll
        for (int r = 0; r < 16; ++r) {
            float4 a = at4[wv * 16 + r][kc];
            acc0[r] += a.x * w0[0] + a.y * w0[1] + a.z * w0[2] + a.w * w0[3];
            acc1[r] += a.x * w1[0] + a.y * w1[1] + a.z * w1[2] + a.w * w1[3];
            acc2[r] += a.x * w2[0] + a.y * w2[1] + a.z * w2[2] + a.w * w2[3];
        }
    }
#pragma unroll
    for (int r = 0; r < 16; ++r) {
        size_t row = (size_t)(n0 + wv * 16 + r) * 192;
        Tn[row + c]       = f16u(acc0[r]);
        Tn[row + 64 + c]  = f16u(acc1[r]);
        Tn[row + 128 + c] = f16u(acc2[r]);
    }
}

// ---------------------------------------------------------------------------
// Per-gate-row constants out[21][192] + f16-packed Whh + packed time weights.
// ---------------------------------------------------------------------------
__global__ void __launch_bounds__(192)
consts_kernel(const float* __restrict__ WihL, const float* __restrict__ bihL,
              const float* __restrict__ WhhL, float* __restrict__ outL,
              unsigned* __restrict__ whpL, unsigned* __restrict__ tpkL,
              const float* __restrict__ WihQ, const float* __restrict__ bihQ,
              const float* __restrict__ WhhQ, float* __restrict__ outQ,
              unsigned* __restrict__ whpQ, unsigned* __restrict__ tpkQ,
              unsigned* __restrict__ wtpk,
              const float* __restrict__ ln_g, const float* __restrict__ ln_b,
              const float* __restrict__ Wedge, const float* __restrict__ bedge,
              const float* __restrict__ Wtime, const float* __restrict__ btime,
              const float* __restrict__ Wstruct, const float* __restrict__ bstruct)
{
    const float* Wih = blockIdx.x ? WihQ : WihL;
    const float* bih = blockIdx.x ? bihQ : bihL;
    const float* Whh = blockIdx.x ? WhhQ : WhhL;
    float* out = blockIdx.x ? outQ : outL;
    unsigned* whp = blockIdx.x ? whpQ : whpL;
    unsigned* tpk = blockIdx.x ? tpkQ : tpkL;
    const int j = threadIdx.x;
    float te = 0.f, tw = 0.f, t1 = 0.f, tb0 = 0.f, cc = 0.f;
    float tt[16];
#pragma unroll
    for (int t = 0; t < 16; ++t) tt[t] = 0.f;
    for (int k = 0; k < DD; ++k) {
        float wv = Wih[j * DD + k];
        float wg = wv * ln_g[k];
        te  += wg * Wedge[k];
        tw  += wg * Wstruct[k];
        t1  += wg;
        tb0 += wg * (bedge[k] + btime[k] + 2.f * bstruct[k]);
        cc  += wv * ln_b[k];
#pragma unroll
        for (int t = 0; t < 16; ++t) tt[t] += wg * Wtime[k * TDD + t];
    }
    out[0 * 192 + j] = te;
    out[1 * 192 + j] = tw;
    out[2 * 192 + j] = t1;
    out[3 * 192 + j] = tb0;
    out[4 * 192 + j] = cc + bih[j];
    for (int t = 0; t < 16; ++t) out[(5 + t) * 192 + j] = tt[t];
    for (int q = 0; q < 8; ++q)
        tpk[j * 8 + q] = packrn(tt[2 * q], tt[2 * q + 1]);
    if (blockIdx.x == 0 && j < 64)
        for (int q = 0; q < 8; ++q)
            wtpk[j * 8 + q] = packrn(Wtime[j * TDD + 2 * q], Wtime[j * TDD + 2 * q + 1]);
    for (int k2 = 0; k2 < 32; ++k2)
        whp[j * 32 + k2] = packrn(Whh[j * DD + 2 * k2], Whh[j * DD + 2 * k2 + 1]);
}

// ---------------------------------------------------------------------------
// PRE: compute folded gate pre-activations g0,g1,g2 for every (seq, l).
// Massively parallel: 4096 waves, 50 positions each, 2-stage pipeline.
// ---------------------------------------------------------------------------
struct PS {
    int nid;
    float tn0, tn1, tn2, pv, e0, sk, t;
};

__global__ void __launch_bounds__(64)
pre_kernel(const int* __restrict__ nidsL, const int* __restrict__ eidsL,
           const float* __restrict__ timesL, const int* __restrict__ curL,
           const int* __restrict__ nidsQ, const int* __restrict__ eidsQ,
           const float* __restrict__ timesQ, const int* __restrict__ curQ,
           const float* __restrict__ node_raw, const float* __restrict__ edge_raw,
           const float* __restrict__ proj_node,
           const unsigned short* __restrict__ TnL, const unsigned short* __restrict__ TnQ,
           const float* __restrict__ cstL, const float* __restrict__ cstQ,
           const unsigned* __restrict__ tpkL, const unsigned* __restrict__ tpkQ,
           const unsigned* __restrict__ wtpk,
           const float* __restrict__ bhhL, const float* __restrict__ bhhQ,
           const float* __restrict__ Wedge, const float* __restrict__ bedge,
           const float* __restrict__ Wtime, const float* __restrict__ btime,
           const float* __restrict__ Wstruct, const float* __restrict__ bstruct,
           unsigned* __restrict__ g01out, unsigned short* __restrict__ g2out)
{
    const int bq = blockIdx.x;
    const int blk = bq >> 2, qq = bq & 3;
    const int g = blk >> 9, s = blk & 511;
    const int d = threadIdx.x;

    const int*            nids  = g ? nidsQ : nidsL;
    const int*            eids  = g ? eidsQ : eidsL;
    const float*          times = g ? timesQ : timesL;
    const int*            curp  = g ? curQ : curL;
    const unsigned short* Tn    = g ? TnQ : TnL;
    const float*          cst   = g ? cstQ : cstL;
    const unsigned*       tpk   = g ? tpkQ : tpkL;
    const float*          bhh   = g ? bhhQ : bhhL;

    unsigned tp0[8], tp1[8], tp2[8], wtp[8];
#pragma unroll
    for (int q4 = 0; q4 < 2; ++q4) {
        uint4 a = *(const uint4*)(tpk + (size_t)(0 * 64 + d) * 8 + 4 * q4);
        tp0[4*q4] = a.x; tp0[4*q4+1] = a.y; tp0[4*q4+2] = a.z; tp0[4*q4+3] = a.w;
        uint4 b = *(const uint4*)(tpk + (size_t)(1 * 64 + d) * 8 + 4 * q4);
        tp1[4*q4] = b.x; tp1[4*q4+1] = b.y; tp1[4*q4+2] = b.z; tp1[4*q4+3] = b.w;
        uint4 c = *(const uint4*)(tpk + (size_t)(2 * 64 + d) * 8 + 4 * q4);
        tp2[4*q4] = c.x; tp2[4*q4+1] = c.y; tp2[4*q4+2] = c.z; tp2[4*q4+3] = c.w;
        uint4 e = *(const uint4*)(wtpk + (size_t)d * 8 + 4 * q4);
        wtp[4*q4] = e.x; wtp[4*q4+1] = e.y; wtp[4*q4+2] = e.z; wtp[4*q4+3] = e.w;
    }
    const float TE0 = cst[0*192 + d], TE1 = cst[0*192 + 64 + d], TE2 = cst[0*192 + 128 + d];
    const float TW0 = cst[1*192 + d], TW1 = cst[1*192 + 64 + d], TW2 = cst[1*192 + 128 + d];
    const float T10 = cst[2*192 + d], T11 = cst[2*192 + 64 + d], T12 = cst[2*192 + 128 + d];
    const float TB0 = cst[3*192 + d], TB1 = cst[3*192 + 64 + d], TB2 = cst[3*192 + 128 + d];
    const float CC0 = cst[4*192 + d] + bhh[d];
    const float CC1 = cst[4*192 + 64 + d] + bhh[64 + d];
    const float CC2 = cst[4*192 + 128 + d];
    const float we_l = Wedge[d];
    const float ws_l = Wstruct[d];
    const float b0_l = bedge[d] + btime[d] + 2.f * bstruct[d];
    const float tfl  = TFREQ[d & 15];

    const int cur = curp[s];
    const int csk = (int)node_raw[(size_t)cur * FF];
    const int* nrow = nids + s * LHH;
    const int* erow = eids + s * LHH;
    const float* trow = times + s * LHH;
    const int lbase = qq * 50;

    auto GATH = [&](PS& P, int i) {
        int l = lbase + i;
        int nid = nrow[l];
        int eid = erow[l];
        P.nid = nid;
        const unsigned short* tb = Tn + (size_t)nid * 192;
        P.tn0 = h16f(tb[d]);
        P.tn1 = h16f(tb[64 + d]);
        P.tn2 = h16f(tb[128 + d]);
        P.pv  = proj_node[(size_t)nid * DD + d];
        P.e0  = edge_raw[(size_t)eid * 4];
        P.sk  = node_raw[(size_t)nid * FF];
        P.t   = trow[l];
    };

    auto EMIT = [&](const PS& P, int i) {
        float cv = __cosf(P.t * tfl);
        float cx = dpp_xor1(cv);
        unsigned cp = pkrtz_u(cv, cx);
        unsigned s0 = rlu(cp, 0),  s1 = rlu(cp, 2),  s2 = rlu(cp, 4),  s3 = rlu(cp, 6);
        unsigned s4 = rlu(cp, 8),  s5 = rlu(cp, 10), s6 = rlu(cp, 12), s7 = rlu(cp, 14);
        float tf = fd2(wtp[7], s7, fd2(wtp[6], s6, fd2(wtp[5], s5, fd2(wtp[4], s4, 0.f))));
        tf = fd2(wtp[3], s3, fd2(wtp[2], s2, fd2(wtp[1], s1, fd2(wtp[0], s0, tf))));
        float flg = ((P.nid == cur) ? 1.f : 0.f) + (((int)P.sk == csk) ? 1.f : 0.f);
        float f = P.pv + P.e0 * we_l + flg * ws_l + b0_l + tf;
        float mu = f;
#pragma unroll
        for (int off = 32; off; off >>= 1) mu += __shfl_xor(mu, off);
        mu *= (1.f / 64.f);
        float dv = f - mu, var = dv * dv;
#pragma unroll
        for (int off = 32; off; off >>= 1) var += __shfl_xor(var, off);
        float rs = rsqrtf(var * (1.f / 64.f) + 1e-5f);
        float c0 = fd2(tp0[7], s7, fd2(tp0[6], s6, fd2(tp0[5], s5, fd2(tp0[4], s4, 0.f))));
        c0 = fd2(tp0[3], s3, fd2(tp0[2], s2, fd2(tp0[1], s1, fd2(tp0[0], s0, c0))));
        float c1 = fd2(tp1[7], s7, fd2(tp1[6], s6, fd2(tp1[5], s5, fd2(tp1[4], s4, 0.f))));
        c1 = fd2(tp1[3], s3, fd2(tp1[2], s2, fd2(tp1[1], s1, fd2(tp1[0], s0, c1))));
        float c2 = fd2(tp2[7], s7, fd2(tp2[6], s6, fd2(tp2[5], s5, fd2(tp2[4], s4, 0.f))));
        c2 = fd2(tp2[3], s3, fd2(tp2[2], s2, fd2(tp2[1], s1, fd2(tp2[0], s0, c2))));
        float g0 = (c0 + P.tn0 + P.e0 * TE0 + flg * TW0 + TB0 - mu * T10) * rs + CC0;
        float g1 = (c1 + P.tn1 + P.e0 * TE1 + flg * TW1 + TB1 - mu * T11) * rs + CC1;
        float g2 = (c2 + P.tn2 + P.e0 * TE2 + flg * TW2 + TB2 - mu * T12) * rs + CC2;
        size_t pos = ((size_t)blk * LHH + (lbase + i)) * 64 + d;
        g01out[pos] = packrn(g0, g1);
        g2out[pos] = f16u(g2);
    };

    PS Pc, Pn;
    GATH(Pc, 0);
    for (int i = 0; i < 50; ++i) {
        int inext = (i + 1 < 50) ? i + 1 : 49;
        GATH(Pn, inext);
        EMIT(Pc, i);
        Pc = Pn;
    }
}

// ---------------------------------------------------------------------------
// GRU-lite: ONE wave per sequence; only the h-recurrence. Streams folded
// gate pre-activations; weights (96 u32) register-resident.
// ---------------------------------------------------------------------------
__global__ void __launch_bounds__(64) __attribute__((amdgpu_waves_per_eu(1, 1)))
gru_lite_kernel(const unsigned* __restrict__ g01, const unsigned short* __restrict__ g2a,
                const unsigned* __restrict__ whpL, const unsigned* __restrict__ whpQ,
                const float* __restrict__ bhhL, const float* __restrict__ bhhQ,
                float* __restrict__ embL, float* __restrict__ embQ)
{
    const int blk = blockIdx.x;
    const int g = blk >> 9, s = blk & 511;
    const int d = threadIdx.x;

    const unsigned* whp = g ? whpQ : whpL;
    const float*    bhh = g ? bhhQ : bhhL;
    float*          emb = g ? embQ : embL;

    unsigned w0[32], w1[32], w2[32];
    {
        const unsigned* p0 = whp + (size_t)d * 32;
        const unsigned* p1 = whp + (size_t)(64 + d) * 32;
        const unsigned* p2 = whp + (size_t)(128 + d) * 32;
#pragma unroll
        for (int q4 = 0; q4 < 8; ++q4) {
            uint4 a = *(const uint4*)(p0 + 4 * q4);
            w0[4*q4] = a.x; w0[4*q4+1] = a.y; w0[4*q4+2] = a.z; w0[4*q4+3] = a.w;
            uint4 b = *(const uint4*)(p1 + 4 * q4);
            w1[4*q4] = b.x; w1[4*q4+1] = b.y; w1[4*q4+2] = b.z; w1[4*q4+3] = b.w;
            uint4 c = *(const uint4*)(p2 + 4 * q4);
            w2[4*q4] = c.x; w2[4*q4+1] = c.y; w2[4*q4+2] = c.z; w2[4*q4+3] = c.w;
        }
    }
#pragma unroll
    for (int i = 0; i < 32; ++i) {
        asm volatile("" : "+v"(w0[i]));
        asm volatile("" : "+v"(w1[i]));
        asm volatile("" : "+v"(w2[i]));
    }
    const float BH2 = bhh[128 + d];

    const unsigned* p01 = g01 + (size_t)blk * LHH * 64 + d;
    const unsigned short* p2 = g2a + (size_t)blk * LHH * 64 + d;

    float h = 0.f;

    auto COMPUTE = [&](unsigned pk01, unsigned pk2) {
        float g0 = f16lo(pk01), g1 = f16hi(pk01);
        float g2 = h16f((unsigned short)pk2);
        float hx = dpp_xor1(h);
        unsigned hpu = pkrtz_u(h, hx);
        float a0 = 0.f, a1 = 0.f, a2 = 0.f, e0 = 0.f, e1 = 0.f, e2 = 0.f;
#pragma unroll
        for (int q = 0; q < 32; q += 2) {
            unsigned sa = rlu(hpu, 2 * q);
            unsigned sb = rlu(hpu, 2 * q + 2);
            a0 = fd2(w0[q], sa, a0);
            a1 = fd2(w1[q], sa, a1);
            a2 = fd2(w2[q], sa, a2);
            e0 = fd2(w0[q+1], sb, e0);
            e1 = fd2(w1[q+1], sb, e1);
            e2 = fd2(w2[q+1], sb, e2);
        }
        float mv0 = a0 + e0, mv1 = a1 + e1, mv2 = a2 + e2;
        float r = sigm(g0 + mv0);
        float z = sigm(g1 + mv1);
        float n = tanh_f(g2 + r * (mv2 + BH2));
        h = (1.f - z) * n + z * h;
    };

    unsigned A01[4], A2[4], B01[4], B2[4];
#pragma unroll
    for (int i = 0; i < 4; ++i) {
        A01[i] = p01[(size_t)i * 64];
        A2[i]  = p2[(size_t)i * 64];
    }
    for (int l = 0; l < LHH; l += 8) {
#pragma unroll
        for (int i = 0; i < 4; ++i) {
            int ll = l + 4 + i;
            B01[i] = p01[(size_t)ll * 64];
            B2[i]  = p2[(size_t)ll * 64];
        }
#pragma unroll
        for (int i = 0; i < 4; ++i) COMPUTE(A01[i], A2[i]);
#pragma unroll
        for (int i = 0; i < 4; ++i) {
            int ll = l + 8 + i;
            if (ll > LHH - 1) ll = LHH - 1;
            A01[i] = p01[(size_t)ll * 64];
            A2[i]  = p2[(size_t)ll * 64];
        }
#pragma unroll
        for (int i = 0; i < 4; ++i) COMPUTE(B01[i], B2[i]);
    }
    emb[(size_t)s * DD + d] = h;
}

// ---------------------------------------------------------------------------
// K3: graph_emb — hash-dedup'd GCNConv + mean pool. 512 thr (8 waves)/block.
// ---------------------------------------------------------------------------
__device__ __forceinline__ int hlookup(const unsigned* hkey, const int* hslot, unsigned id)
{
    unsigned p = (id * 2654435761u) & (GE_HASH - 1);
    while (hkey[p] != id) p = (p + 1) & (GE_HASH - 1);
    return hslot[p];
}

__global__ void __launch_bounds__(512)
graph_emb_kernel(const int* __restrict__ retrieved, const int* __restrict__ pool_nodes,
                 const float* __restrict__ hgcn, const float* __restrict__ gcn_b,
                 float* __restrict__ glob)
{
    __shared__ float agg[400 * 64];
    __shared__ unsigned hkey[GE_HASH];
    __shared__ int hslot[GE_HASH];
    __shared__ unsigned ekey[GE_HASH];
    __shared__ int slot_id[400];
    __shared__ unsigned deg[400];
    __shared__ float dis[400];
    __shared__ unsigned elist[400];
    __shared__ int ids[400];
    __shared__ int pids[8];
    __shared__ int cntU, cntE;
    __shared__ float gcnb_s[64];
    __shared__ float red[8][64];

    const int b = blockIdx.x;
    const int tid = threadIdx.x;
    const int lane = tid & 63, wid = tid >> 6;

    if (tid < 8)  pids[tid] = retrieved[b * 8 + tid];
    if (tid < 64) gcnb_s[tid] = gcn_b[tid];
    if (tid == 0) { cntU = 0; cntE = 0; }
    for (int i = tid; i < GE_HASH; i += 512) { hkey[i] = 0u; ekey[i] = 0u; }
    if (tid < 400) deg[tid] = 0u;
    __syncthreads();

    if (tid < 400) {
        int k = tid / 50, p = tid % 50;
        ids[tid] = pool_nodes[(size_t)pids[k] * 50 + p];
    }
    __syncthreads();

    if (tid < 400) {
        int idi = ids[tid];
        if (idi > 0) {
            unsigned id = (unsigned)idi;
            unsigned p = (id * 2654435761u) & (GE_HASH - 1);
            while (true) {
                unsigned old = atomicCAS(&hkey[p], 0u, id);
                if (old == 0u) {
                    int s = atomicAdd(&cntU, 1);
                    hslot[p] = s; slot_id[s] = idi;
                    break;
                }
                if (old == id) break;
                p = (p + 1) & (GE_HASH - 1);
            }
        }
    }
    __syncthreads();

    if (tid < 8 * 49) {
        int k = tid / 49, p = tid % 49;
        int u = ids[k * 50 + p], v = ids[k * 50 + p + 1];
        if (u > 0 && v > 0) {
            unsigned a = (unsigned)min(u, v), bb = (unsigned)max(u, v);
            unsigned key = a * 40000u + bb;
            unsigned p2 = (key * 2654435761u) & (GE_HASH - 1);
            while (true) {
                unsigned old = atomicCAS(&ekey[p2], 0u, key);
                if (old == 0u) {
                    int su = hlookup(hkey, hslot, a);
                    int sv = hlookup(hkey, hslot, bb);
                    int e = atomicAdd(&cntE, 1);
                    elist[e] = ((unsigned)su << 16) | (unsigned)sv;
                    atomicAdd(&deg[su], 1u);
                    atomicAdd(&deg[sv], 1u);
                    break;
                }
                if (old == key) break;
                p2 = (p2 + 1) & (GE_HASH - 1);
            }
        }
    }
    __syncthreads();

    const int U = cntU, EC = cntE;
    if (tid < U) dis[tid] = rsqrtf((float)deg[tid] + 1.0f);
    __syncthreads();

    for (int s = wid; s < U; s += 8) {
        float d2 = dis[s] * dis[s];
        float hval = hgcn[(size_t)slot_id[s] * 64 + lane];
        agg[s * 64 + lane] = gcnb_s[lane] + d2 * hval;
    }
    __syncthreads();

    for (int e = wid; e < EC; e += 8) {
        unsigned pk = elist[e];
        int su = (int)(pk >> 16), sv = (int)(pk & 0xffffu);
        float nrm = dis[su] * dis[sv];
        float hu = hgcn[(size_t)slot_id[su] * 64 + lane];
        float hv = hgcn[(size_t)slot_id[sv] * 64 + lane];
        atomicAdd(&agg[sv * 64 + lane], nrm * hu);
        atomicAdd(&agg[su * 64 + lane], nrm * hv);
    }
    __syncthreads();

    float acc = 0.f;
    for (int s = wid; s < U; s += 8) acc += fmaxf(agg[s * 64 + lane], 0.f);
    red[wid][lane] = acc;
    __syncthreads();
    if (tid < 64) {
        float tot = 0.f;
#pragma unroll
        for (int q = 0; q < 8; ++q) tot += red[q][tid];
        glob[(size_t)b * 64 + tid] = tot / (float)max(U, 1);
    }
}

// ---------------------------------------------------------------------------
// K4: fusion + output heads.
// ---------------------------------------------------------------------------
__global__ void __launch_bounds__(64)
head_kernel(const float* __restrict__ local_emb, const float* __restrict__ glob,
            const float* __restrict__ q_emb,
            const float* __restrict__ fus_W, const float* __restrict__ fus_b,
            const float* __restrict__ out_W, const float* __restrict__ out_b,
            float* __restrict__ out)
{
    __shared__ float cat[128];
    __shared__ float fus[64];
    __shared__ float qv[64];
    const int b = blockIdx.x, d = threadIdx.x;
    cat[d]      = local_emb[(size_t)b * 64 + d];
    cat[64 + d] = glob[(size_t)b * 64 + d];
    qv[d]       = q_emb[(size_t)b * 64 + d];
    __syncthreads();
    float acc = fus_b[d];
    const float* fw = fus_W + (size_t)d * 128;
#pragma unroll 4
    for (int k = 0; k < 128; ++k) acc += cat[k] * fw[k];
    fus[d] = fmaxf(acc, 0.f);
    __syncthreads();
    float o0 = out_b[d], o1 = out_b[d];
    const float* ow = out_W + (size_t)d * 64;
#pragma unroll 4
    for (int k = 0; k < 64; ++k) { float ww = ow[k]; o0 += fus[k] * ww; o1 += qv[k] * ww; }
    out[(size_t)b * 64 + d] = o0;
    out[(size_t)BB * 64 + (size_t)b * 64 + d] = o1;
}

// ---------------------------------------------------------------------------
extern "C" void kernel_launch(void* const* d_in, const int* in_sizes, int n_in,
                              void* d_out, int out_size, void* d_ws, size_t ws_size,
                              hipStream_t stream)
{
    const int*   src_ids    = (const int*)d_in[0];
    const int*   dst_ids    = (const int*)d_in[1];
    const int*   l_nids     = (const int*)d_in[2];
    const int*   l_eids     = (const int*)d_in[3];
    const float* l_times    = (const float*)d_in[4];
    const int*   d_nids     = (const int*)d_in[5];
    const int*   d_eids     = (const int*)d_in[6];
    const float* d_times    = (const float*)d_in[7];
    const int*   retr       = (const int*)d_in[8];
    const float* node_raw   = (const float*)d_in[9];
    const float* edge_raw   = (const float*)d_in[10];
    const int*   pool_nodes = (const int*)d_in[11];
    const float* Wfeat  = (const float*)d_in[12];
    const float* bfeat  = (const float*)d_in[13];
    const float* Wedge  = (const float*)d_in[14];
    const float* bedge  = (const float*)d_in[15];
    const float* Wtime  = (const float*)d_in[16];
    const float* btime  = (const float*)d_in[17];
    const float* Wstruct= (const float*)d_in[18];
    const float* bstruct= (const float*)d_in[19];
    const float* ln_g   = (const float*)d_in[20];
    const float* ln_b   = (const float*)d_in[21];
    const float* gruL_Wih = (const float*)d_in[22];
    const float* gruL_Whh = (const float*)d_in[23];
    const float* gruL_bih = (const float*)d_in[24];
    const float* gruL_bhh = (const float*)d_in[25];
    const float* gruQ_Wih = (const float*)d_in[26];
    const float* gruQ_Whh = (const float*)d_in[27];
    const float* gruQ_bih = (const float*)d_in[28];
    const float* gruQ_bhh = (const float*)d_in[29];
    const float* gcn_W  = (const float*)d_in[30];
    const float* gcn_b  = (const float*)d_in[31];
    const float* fus_W  = (const float*)d_in[32];
    const float* fus_b  = (const float*)d_in[33];
    const float* out_W  = (const float*)d_in[34];
    const float* out_b  = (const float*)d_in[35];

    char* wsb = (char*)d_ws;
    auto alloc = [&](size_t bytes) -> void* {
        void* p = (void*)wsb;
        wsb += (bytes + 255) & ~(size_t)255;
        return p;
    };
    float*          proj_node = (float*)alloc((size_t)NN * DD * 4);
    float*          hgcn      = (float*)alloc((size_t)NN * DD * 4);
    unsigned short* TnL16     = (unsigned short*)alloc((size_t)NN * 192 * 2);
    unsigned short* TnQ16     = (unsigned short*)alloc((size_t)NN * 192 * 2);
    float*          cstL      = (float*)alloc(4096 * 4);
    float*          cstQ      = (float*)alloc(4096 * 4);
    unsigned*       whpL      = (unsigned*)alloc(192 * 32 * 4);
    unsigned*       whpQ      = (unsigned*)alloc(192 * 32 * 4);
    unsigned*       tpkL      = (unsigned*)alloc(192 * 8 * 4);
    unsigned*       tpkQ      = (unsigned*)alloc(192 * 8 * 4);
    unsigned*       wtpk      = (unsigned*)alloc(64 * 8 * 4);
    unsigned*       g01       = (unsigned*)alloc((size_t)2 * BB * LHH * 64 * 4);
    unsigned short* g2a       = (unsigned short*)alloc((size_t)2 * BB * LHH * 64 * 2);
    float*          local_emb = (float*)alloc((size_t)BB * DD * 4);
    float*          q_emb     = (float*)alloc((size_t)BB * DD * 4);
    float*          glob      = (float*)alloc((size_t)BB * DD * 4);

    dim3 g1((NN + 127) / 128);
    gemm_nt_kernel<FF><<<g1, 256, 0, stream>>>(node_raw, Wfeat, bfeat, proj_node, NN);

    consts_kernel<<<2, 192, 0, stream>>>(gruL_Wih, gruL_bih, gruL_Whh, cstL, whpL, tpkL,
                                         gruQ_Wih, gruQ_bih, gruQ_Whh, cstQ, whpQ, tpkQ,
                                         wtpk, ln_g, ln_b, Wedge, bedge, Wtime, btime,
                                         Wstruct, bstruct);

    tn_gemm_kernel<<<dim3(NN / 64, 2), 256, 0, stream>>>(proj_node, gruL_Wih, gruQ_Wih,
                                                         ln_g, TnL16, TnQ16);

    pre_kernel<<<2 * BB * 4, 64, 0, stream>>>(
        l_nids, l_eids, l_times, dst_ids,
        d_nids, d_eids, d_times, src_ids,
        node_raw, edge_raw, proj_node, TnL16, TnQ16, cstL, cstQ,
        tpkL, tpkQ, wtpk, gruL_bhh, gruQ_bhh,
        Wedge, bedge, Wtime, btime, Wstruct, bstruct,
        g01, g2a);

    gemm_nt_kernel<DD><<<g1, 256, 0, stream>>>(proj_node, gcn_W, nullptr, hgcn, NN);

    gru_lite_kernel<<<2 * BB, 64, 0, stream>>>(
        g01, g2a, whpL, whpQ, gruL_bhh, gruQ_bhh, local_emb, q_emb);

    graph_emb_kernel<<<BB, 512, 0, stream>>>(retr, pool_nodes, hgcn, gcn_b, glob);

    head_kernel<<<BB, 64, 0, stream>>>(local_emb, glob, q_emb,
        fus_W, fus_b, out_W, out_b, (float*)d_out);
}